// Round 4
// baseline (278.797 us; speedup 1.0000x reference)
//
#include <hip/hip_runtime.h>
#include <stdint.h>

// SimplifiedLinearAttention: B=8, N=3136 (56x56), C=512, 8 heads x 64
// Pipeline: cvt -> transpose weights -> GEMM(QKV,fused act) -> kvmat/ksum ->
//           conv_dw -> attn(z,out,+fmap) -> GEMM(proj,+bias) -> f32 out
// R4: GEMM main loop = 4-slot circular LDS pipeline (depth-3 lookahead),
//     counted vmcnt(8/4/0), ONE raw s_barrier per K-tile, explicit
//     lgkmcnt(0)+sched_barrier before each MFMA cluster (rule #18),
//     setprio(1) around MFMAs (T5). Epilogues identical to passing R3.
#define B_    8
#define N_    3136
#define C_    512
#define MTOT  25088   // B_*N_

typedef __attribute__((ext_vector_type(8))) short bf16x8;
typedef __attribute__((ext_vector_type(4))) float f32x4;

__device__ __forceinline__ float bf2f(short s){
  union { float f; uint32_t u; } cv; cv.u = ((uint32_t)(uint16_t)s) << 16; return cv.f;
}
__device__ __forceinline__ short f2bf(float f){
  union { float f; uint32_t u; } cv; cv.f = f;
  uint32_t r = cv.u + 0x7FFFu + ((cv.u >> 16) & 1u);
  return (short)(r >> 16);
}

typedef const __attribute__((address_space(1))) void* gas1_t;
typedef __attribute__((address_space(3))) void* las3_t;
__device__ __forceinline__ void gld16(const void* g, void* l){
  __builtin_amdgcn_global_load_lds((gas1_t)g, (las3_t)l, 16, 0, 0);
}

// ---------------- convert x to bf16 (vectorized) ----------------
__global__ __launch_bounds__(256) void cvt_x(const float* __restrict__ x,
                                             short* __restrict__ xb, int n8){
  int i = blockIdx.x * 256 + threadIdx.x;
  if (i >= n8) return;
  const float4* p = (const float4*)x;
  float4 a = p[i*2], b = p[i*2+1];
  short o[8] = { f2bf(a.x), f2bf(a.y), f2bf(a.z), f2bf(a.w),
                 f2bf(b.x), f2bf(b.y), f2bf(b.z), f2bf(b.w) };
  *(bf16x8*)(xb + i*8) = *(bf16x8*)o;
}

// -------- transpose+convert weights: dst[j*512 + k] = bf16(src[k*J + j]) ----
__global__ __launch_bounds__(256) void tconv(const float* __restrict__ src,
                                             short* __restrict__ dst, int J){
  __shared__ float tile[32][33];
  int jb = blockIdx.x * 32, kb = blockIdx.y * 32;
  int tx = threadIdx.x & 31, ty = threadIdx.x >> 5;   // ty 0..7
#pragma unroll
  for (int r = 0; r < 32; r += 8)
    tile[ty + r][tx] = src[(size_t)(kb + ty + r) * J + jb + tx];
  __syncthreads();
#pragma unroll
  for (int r = 0; r < 32; r += 8)
    dst[(size_t)(jb + ty + r) * 512 + kb + tx] = f2bf(tile[tx][ty + r]);
}

// ---------------- 128x128 bf16 MFMA GEMM, K=512, Bt is (N x K) ----------------
// 4-slot circular pipeline (16 KB/slot, 64 KB). Per K-tile kt:
//   s_waitcnt vmcnt(8)  -> tile kt landed (kt+1,kt+2 in flight)
//   s_barrier           -> all waves see kt landed; all kt-1 reads complete
//   sched_barrier(0)    -> nothing crosses
//   stage(kt+3)         -> slot (kt-1)&3, provably retired
//   ds_read tile kt     -> swizzled
//   lgkmcnt(0)+sched_barrier(0)  -> reads complete HERE (rule #18)
//   setprio(1); 16 MFMA; setprio(0)
// Swizzle: 16B-chunk phys = log ^ (row&3) ^ ((row>>2)&3) (involution), applied
// to the global SOURCE at stage time and to the ds_read address.
// MODE 0: QKV epilogue (relu q / relu(k+pos) / v, bf16 out, LDS-restaged)
// MODE 1: proj epilogue (+bias, f32 out, LDS-restaged in two row-halves)
template<int MODE, int GX>
__global__ __launch_bounds__(256)
void gemm_bf16(const short* __restrict__ A, const short* __restrict__ Bt,
               short* __restrict__ oQ, short* __restrict__ oK, short* __restrict__ oV,
               const float* __restrict__ posenc,
               float* __restrict__ oF, const float* __restrict__ bias)
{
  __shared__ __align__(16) char lds[65536];
  constexpr int NT = 16;                            // K/32
  const int t = threadIdx.x;
  const int wave = t >> 6, lane = t & 63;

  // bijective XCD swizzle: grid count divisible by 8 in both uses
  const int nwg  = GX * 196;
  const int orig = blockIdx.y * GX + blockIdx.x;
  const int swz  = (orig & 7) * (nwg >> 3) + (orig >> 3);
  const int rt = (swz / GX) * 128;
  const int ct = (swz % GX) * 128;

  const int wm = (wave >> 1) * 64, wn = (wave & 1) * 64;
  const int fr = lane & 15;

  // ---- staging addressing (global source pre-swizzled; LDS dest linear) ----
  const int row0 = t >> 2;                                     // 0..63
  const int s0   = ((t & 3) ^ (row0 & 3) ^ ((row0 >> 2) & 3)) << 3;  // shorts
  const short* aBase = A  + (size_t)(rt + row0) * 512 + s0;
  const short* bBase = Bt + (size_t)(ct + row0) * 512 + s0;
  char* dBase = lds + wave * 1024;    // wave-uniform; HW adds lane*16

  auto stage = [&](int kt2) {
    char* d = dBase + (kt2 & 3) * 16384;
    const short* a0 = aBase + kt2 * 32;
    const short* b0 = bBase + kt2 * 32;
    gld16(a0,         d);            // A rows 0-63
    gld16(a0 + 32768, d + 4096);     // A rows 64-127  (+64*512 shorts)
    gld16(b0,         d + 8192);     // B rows 0-63
    gld16(b0 + 32768, d + 12288);    // B rows 64-127
  };

  // ---- fragment ds_read offsets (bytes, swizzled; row&3 / (row>>2)&3 are
  //      invariant under +16*m so one offset per operand suffices) ----
  const int rowA = wm + fr;
  const int offA = rowA * 64 + (((lane >> 4) ^ (rowA & 3) ^ ((rowA >> 2) & 3)) << 4);
  const int rowB = wn + fr;
  const int offB = 8192 + rowB * 64 + (((lane >> 4) ^ (rowB & 3) ^ ((rowB >> 2) & 3)) << 4);

  f32x4 zv = {0.f, 0.f, 0.f, 0.f};
  f32x4 acc[4][4];
#pragma unroll
  for (int i = 0; i < 4; i++)
#pragma unroll
    for (int j = 0; j < 4; j++) acc[i][j] = zv;

  stage(0); stage(1); stage(2);      // prologue: 12 loads in flight

  auto body = [&](int kt) {
    __builtin_amdgcn_s_barrier();            // kt landed everywhere; all
    __builtin_amdgcn_sched_barrier(0);       // kt-1 reads complete
    if (kt + 3 < NT) stage(kt + 3);          // slot (kt-1)&3: retired
    const char* slb = lds + (kt & 3) * 16384;
    bf16x8 af[4], bfv[4];
#pragma unroll
    for (int i = 0; i < 4; i++) {
      af[i]  = *(const bf16x8*)(slb + offA + i * 1024);
      bfv[i] = *(const bf16x8*)(slb + offB + i * 1024);
    }
    asm volatile("s_waitcnt lgkmcnt(0)" ::: "memory");  // reads done HERE,
    __builtin_amdgcn_sched_barrier(0);                  // before next barrier
    __builtin_amdgcn_s_setprio(1);
#pragma unroll
    for (int i = 0; i < 4; i++)
#pragma unroll
      for (int j = 0; j < 4; j++)
        acc[i][j] = __builtin_amdgcn_mfma_f32_16x16x32_bf16(af[i], bfv[j], acc[i][j], 0, 0, 0);
    __builtin_amdgcn_s_setprio(0);
  };

  // main loop: own-tile wait; 8 = 2 newer tiles * 4 loads still in flight
  for (int kt = 0; kt < NT - 2; ++kt) {
    asm volatile("s_waitcnt vmcnt(8)" ::: "memory");
    body(kt);
  }
  asm volatile("s_waitcnt vmcnt(4)" ::: "memory");
  body(NT - 2);
  asm volatile("s_waitcnt vmcnt(0)" ::: "memory");
  body(NT - 1);

  __builtin_amdgcn_s_barrier();              // all tile-15 reads done ->
  __builtin_amdgcn_sched_barrier(0);         // LDS reusable for epilogue

  // ---- epilogue: restage C tile through LDS, vectorized coalesced stores ----
  const int rb = (lane >> 4) << 2;           // D layout: row=(lane>>4)*4+reg
  if (MODE == 0) {
    short* ov = (short*)lds;                 // [128][144] bf16 (36864 B)
    const int sel = ct >> 9;                 // 0:Q 1:K 2:V (uniform per block)
    const int cb  = ct - sel * 512;
#pragma unroll
    for (int i = 0; i < 4; i++)
#pragma unroll
      for (int j = 0; j < 4; j++)
#pragma unroll
        for (int r = 0; r < 4; r++) {
          int row = wm + i * 16 + rb + r;
          int col = wn + j * 16 + fr;
          float v = acc[i][j][r];
          if (sel == 0) v = fmaxf(v, 0.f);
          if (sel == 1) {
            int nr = (rt + row) % N_;
            v = fmaxf(v + posenc[nr * 512 + cb + col], 0.f);
          }
          ov[row * 144 + col] = f2bf(v);
        }
    __syncthreads();
    short* outp = sel == 0 ? oQ : (sel == 1 ? oK : oV);
#pragma unroll
    for (int pass = 0; pass < 8; ++pass) {
      int row  = (t >> 4) + pass * 16;
      int colb = (t & 15) * 8;
      bf16x8 vv = *(const bf16x8*)&ov[row * 144 + colb];
      *(bf16x8*)(outp + (size_t)(rt + row) * 512 + cb + colb) = vv;
    }
  } else {
    float* ovf = (float*)lds;                // [64][132] f32 (33792 B), 2 halves
#pragma unroll
    for (int half = 0; half < 2; ++half) {
      if (half) __syncthreads();             // protect prev half's reads
      if ((wave >> 1) == half) {             // waves owning rows half*64..+63
#pragma unroll
        for (int i = 0; i < 4; i++)
#pragma unroll
          for (int j = 0; j < 4; j++)
#pragma unroll
            for (int r = 0; r < 4; r++)
              ovf[(i * 16 + rb + r) * 132 + wn + j * 16 + fr] = acc[i][j][r];
      }
      __syncthreads();
#pragma unroll
      for (int pass = 0; pass < 4; ++pass) {
        int row  = (t >> 4) + pass * 16;   // 0..63
        int colb = (t & 15) * 8;
        f32x4 v0 = *(const f32x4*)&ovf[row * 132 + colb];
        f32x4 v1 = *(const f32x4*)&ovf[row * 132 + colb + 4];
        f32x4 b0 = *(const f32x4*)&bias[ct + colb];
        f32x4 b1 = *(const f32x4*)&bias[ct + colb + 4];
        v0 += b0; v1 += b1;
        float* op = oF + (size_t)(rt + half * 64 + row) * 512 + ct + colb;
        *(f32x4*)op       = v0;
        *(f32x4*)(op + 4) = v1;
      }
    }
  }
}

// ------------- per-head KtV (64x64) + ksum, f32 partials, N split 7 ----------
__global__ __launch_bounds__(256)
void kvmat_part(const short* __restrict__ kb, const short* __restrict__ vb,
                float* __restrict__ pKV, float* __restrict__ pKS)
{
  __shared__ __align__(16) float lk[64][64];
  __shared__ __align__(16) float lv[64][64];
  const int chunk = blockIdx.x, bh = blockIdx.y;
  const int b = bh >> 3, h = bh & 7;
  const int t = threadIdx.x;
  const int tc = t >> 4, td = t & 15;
  const int kc = t & 63, kr = (t >> 6) * 16;
  float acc[4][4] = {};
  float ksacc = 0.f;

  for (int tile = 0; tile < 7; ++tile) {
    const int r0 = chunk * 448 + tile * 64;
    __syncthreads();
#pragma unroll
    for (int i = 0; i < 2; i++) {
      int idx = t + i * 256;
      int r = idx >> 3, c8 = (idx & 7) << 3;
      size_t g = (size_t)(b * N_ + r0 + r) * 512 + h * 64 + c8;
      bf16x8 kk = *(const bf16x8*)(kb + g);
      bf16x8 vv = *(const bf16x8*)(vb + g);
#pragma unroll
      for (int e = 0; e < 8; e++) { lk[r][c8 + e] = bf2f(kk[e]); lv[r][c8 + e] = bf2f(vv[e]); }
    }
    __syncthreads();
#pragma unroll 4
    for (int r = 0; r < 64; r++) {
      f32x4 k4 = *(const f32x4*)&lk[r][tc * 4];
      f32x4 v4 = *(const f32x4*)&lv[r][td * 4];
#pragma unroll
      for (int i = 0; i < 4; i++)
#pragma unroll
        for (int j = 0; j < 4; j++) acc[i][j] += k4[i] * v4[j];
    }
#pragma unroll 4
    for (int rr = 0; rr < 16; rr++) ksacc += lk[kr + rr][kc];
  }

  const int pbase = (bh * 7 + chunk) * 4096;
#pragma unroll
  for (int i = 0; i < 4; i++)
#pragma unroll
    for (int j = 0; j < 4; j++)
      pKV[pbase + (tc * 4 + i) * 64 + td * 4 + j] = acc[i][j];
  __syncthreads();
  float* red = &lk[0][0];
  red[t] = ksacc;
  __syncthreads();
  if (t < 64)
    pKS[(bh * 7 + chunk) * 64 + t] = red[t] + red[t + 64] + red[t + 128] + red[t + 192];
}

__global__ __launch_bounds__(256)
void kv_reduce(const float* __restrict__ pKV, const float* __restrict__ pKS,
               float* __restrict__ kvm, float* __restrict__ ksum)
{
  int bh = blockIdx.x, t = threadIdx.x;
#pragma unroll
  for (int i = 0; i < 16; i++) {
    int idx = t + i * 256;
    float s = 0.f;
#pragma unroll
    for (int c = 0; c < 7; c++) s += pKV[(bh * 7 + c) * 4096 + idx];
    kvm[bh * 4096 + idx] = s;
  }
  if (t < 64) {
    float s = 0.f;
#pragma unroll
    for (int c = 0; c < 7; c++) s += pKS[(bh * 7 + c) * 64 + t];
    ksum[bh * 64 + t] = s;
  }
}

// ------------- depthwise 5x5 conv on v, +bias -> pre (bf16) -------------
__global__ __launch_bounds__(256)
void conv_dw(const short* __restrict__ vb, const float* __restrict__ w,
             const float* __restrict__ bias, short* __restrict__ pre)
{
  __shared__ __align__(16) short lsv[5 * 56 * 64];
  __shared__ float lw[1600];
  __shared__ float lb[64];
  const int y = blockIdx.x, bh = blockIdx.y;
  const int b = bh >> 3, h = bh & 7;
  const int t = threadIdx.x;
  for (int i = t; i < 1600; i += 256) lw[i] = w[i];
  if (t < 64) lb[t] = bias[t];
  for (int i = t; i < 2240; i += 256) {
    int row = i / 448, rem = i - row * 448;
    int xx = rem >> 3, c8 = (rem & 7) << 3;
    int gy = y + row - 2;
    bf16x8 val = {0, 0, 0, 0, 0, 0, 0, 0};
    if ((unsigned)gy < 56u)
      val = *(const bf16x8*)(vb + (size_t)(b * N_ + gy * 56 + xx) * 512 + h * 64 + c8);
    int byt = ((row * 56 + xx) * 64 + c8) * 2;
    byt ^= (xx & 7) << 4;                 // bank-conflict swizzle
    *(bf16x8*)((char*)lsv + byt) = val;
  }
  __syncthreads();
  const int x = t >> 2, dq = t & 3;
  if (x >= 56) return;
  float acc[16];
#pragma unroll
  for (int i = 0; i < 16; i++) acc[i] = lb[dq * 16 + i];
#pragma unroll
  for (int dy = 0; dy < 5; ++dy) {
#pragma unroll
    for (int dx = 0; dx < 5; ++dx) {
      int xx = x + dx - 2;
      if ((unsigned)xx < 56u) {
        int byt = ((dy * 56 + xx) * 64 + dq * 16) * 2;
        byt ^= (xx & 7) << 4;
        bf16x8 v0 = *(const bf16x8*)((const char*)lsv + byt);
        bf16x8 v1 = *(const bf16x8*)((const char*)lsv + (byt ^ 16));
#pragma unroll
        for (int e = 0; e < 8; e++) {
          acc[e]     += bf2f(v0[e]) * lw[(dq * 16 + e) * 25 + dy * 5 + dx];
          acc[e + 8] += bf2f(v1[e]) * lw[(dq * 16 + e + 8) * 25 + dy * 5 + dx];
        }
      }
    }
  }
  size_t base = (size_t)(b * N_ + y * 56 + x) * 512 + h * 64 + dq * 16;
  short o[16];
#pragma unroll
  for (int i = 0; i < 16; i++) o[i] = f2bf(acc[i]);
  *(bf16x8*)(pre + base)     = *(bf16x8*)&o[0];
  *(bf16x8*)(pre + base + 8) = *(bf16x8*)&o[8];
}

// ------- attn: out = (q . kvmat) * z + fmap, in-place on pre (bf16) -------
__global__ __launch_bounds__(256)
void attn_comb(const short* __restrict__ qb, const float* __restrict__ kvm,
               const float* __restrict__ ksum, short* __restrict__ pre)
{
  __shared__ __align__(16) float lkv[4096];
  __shared__ __align__(16) float lq[4096];   // [c][p] transposed
  __shared__ float lks[64];
  const int pt = blockIdx.x, bh = blockIdx.y;
  const int b = bh >> 3, h = bh & 7;
  const int t = threadIdx.x;
  for (int i = t; i < 4096; i += 256) lkv[i] = kvm[bh * 4096 + i];
  if (t < 64) lks[t] = ksum[bh * 64 + t];
  {
    const int p = t & 63, cg = t >> 6;
    size_t g = (size_t)(b * N_ + pt * 64 + p) * 512 + h * 64 + cg * 16;
    bf16x8 qa = *(const bf16x8*)(qb + g);
    bf16x8 qc = *(const bf16x8*)(qb + g + 8);
#pragma unroll
    for (int e = 0; e < 8; e++) {
      lq[(cg * 16 + e) * 64 + p]     = bf2f(qa[e]);
      lq[(cg * 16 + 8 + e) * 64 + p] = bf2f(qc[e]);
    }
  }
  __syncthreads();
  const int p = t & 63, d0 = (t >> 6) * 16;
  float acc[16] = {};
  float zd = 0.f;
#pragma unroll 4
  for (int c = 0; c < 64; c++) {
    float qv = lq[c * 64 + p];
    zd += qv * lks[c];
    const f32x4* row = (const f32x4*)&lkv[c * 64 + d0];
    f32x4 m0 = row[0], m1 = row[1], m2 = row[2], m3 = row[3];
#pragma unroll
    for (int e = 0; e < 4; e++) {
      acc[e]      += qv * m0[e];
      acc[4 + e]  += qv * m1[e];
      acc[8 + e]  += qv * m2[e];
      acc[12 + e] += qv * m3[e];
    }
  }
  float z = 1.f / (zd + 1e-6f);
  size_t base = (size_t)(b * N_ + pt * 64 + p) * 512 + h * 64 + d0;
  bf16x8 f0 = *(const bf16x8*)(pre + base);
  bf16x8 f1 = *(const bf16x8*)(pre + base + 8);
  short o[16];
#pragma unroll
  for (int e = 0; e < 8; e++) {
    o[e]     = f2bf(acc[e] * z + bf2f(f0[e]));
    o[e + 8] = f2bf(acc[e + 8] * z + bf2f(f1[e]));
  }
  *(bf16x8*)(pre + base)     = *(bf16x8*)&o[0];
  *(bf16x8*)(pre + base + 8) = *(bf16x8*)&o[8];
}

// ---------------------------------------------------------------------------
extern "C" void kernel_launch(void* const* d_in, const int* in_sizes, int n_in,
                              void* d_out, int out_size, void* d_ws, size_t ws_size,
                              hipStream_t stream)
{
  const float* x     = (const float*)d_in[0];
  const float* Wq    = (const float*)d_in[3];
  const float* Wkv   = (const float*)d_in[4];
  const float* pos   = (const float*)d_in[5];
  const float* dwcw  = (const float*)d_in[6];
  const float* dwcb  = (const float*)d_in[7];
  const float* Wproj = (const float*)d_in[8];
  const float* bproj = (const float*)d_in[9];
  float* out = (float*)d_out;

  char* ws = (char*)d_ws;
  size_t off = 0;
  auto alloc = [&](size_t bytes) -> void* {
    void* p = ws + off;
    off = (off + bytes + 255) & ~(size_t)255;
    return p;
  };
  short* xb     = (short*)alloc((size_t)MTOT * 512 * 2);
  short* wqkvT  = (short*)alloc((size_t)1536 * 512 * 2);
  short* wprojT = (short*)alloc((size_t)512 * 512 * 2);
  short* qb     = (short*)alloc((size_t)MTOT * 512 * 2);
  short* kbuf   = (short*)alloc((size_t)MTOT * 512 * 2);
  short* vbuf   = (short*)alloc((size_t)MTOT * 512 * 2);
  float* pKV    = (float*)alloc((size_t)64 * 7 * 4096 * 4);
  float* pKS    = (float*)alloc((size_t)64 * 7 * 64 * 4);
  float* kvm    = (float*)alloc((size_t)64 * 4096 * 4);
  float* ksumB  = (float*)alloc((size_t)64 * 64 * 4);
  short* pre    = (short*)alloc((size_t)MTOT * 512 * 2);
  if (ws_size < off) return;   // workspace too small: leave output zeroed (visible failure)

  // 1. convert x
  cvt_x<<<dim3((MTOT * 512 / 8 + 255) / 256), dim3(256), 0, stream>>>(x, xb, MTOT * 512 / 8);
  // 2. transpose weights -> (N x K) bf16
  tconv<<<dim3(16, 16), dim3(256), 0, stream>>>(Wq,    wqkvT,              512);
  tconv<<<dim3(32, 16), dim3(256), 0, stream>>>(Wkv,   wqkvT + 512 * 512, 1024);
  tconv<<<dim3(16, 16), dim3(256), 0, stream>>>(Wproj, wprojT,             512);
  // 3. QKV GEMM, fused activations
  gemm_bf16<0, 12><<<dim3(12, 196), dim3(256), 0, stream>>>(xb, wqkvT, qb, kbuf, vbuf, pos,
                                                            nullptr, nullptr);
  // 4. per-head KtV + ksum
  kvmat_part<<<dim3(7, 64), dim3(256), 0, stream>>>(kbuf, vbuf, pKV, pKS);
  kv_reduce<<<dim3(64), dim3(256), 0, stream>>>(pKV, pKS, kvm, ksumB);
  // 5. depthwise conv -> pre
  conv_dw<<<dim3(56, 64), dim3(256), 0, stream>>>(vbuf, dwcw, dwcb, pre);
  // 6. attention output + fmap (in-place on pre)
  attn_comb<<<dim3(49, 64), dim3(256), 0, stream>>>(qb, kvm, ksumB, pre);
  // 7. projection GEMM -> f32 out
  gemm_bf16<1, 4><<<dim3(4, 196), dim3(256), 0, stream>>>(pre, wprojT, nullptr, nullptr, nullptr,
                                                          nullptr, out, bproj);
}

// Round 5
// 251.144 us; speedup vs baseline: 1.1101x; 1.1101x over previous
//
#include <hip/hip_runtime.h>
#include <stdint.h>

// SimplifiedLinearAttention: B=8, N=3136 (56x56), C=512, 8 heads x 64
// Pipeline: cvt -> transpose weights -> GEMM(QKV,fused act) -> kvmat/ksum ->
//           conv_dw -> attn(z,out,+fmap) -> GEMM(proj,+bias) -> f32 out
// R5: GEMM geometry change. BM=256, 512 threads (8 waves), BK=32, proven R3
//     drain-loop sync. QKV: BN=256 (588 blocks, wave-tile 128x64, 12 reads /
//     32 MFMA). proj: BN=128 (392 blocks). Quarter-restaged epilogues with
//     conflict-free strides; activations applied at store time. m204
//     bijective XCD swizzle.
#define B_    8
#define N_    3136
#define C_    512
#define MTOT  25088   // B_*N_

typedef __attribute__((ext_vector_type(8))) short bf16x8;
typedef __attribute__((ext_vector_type(4))) float f32x4;

__device__ __forceinline__ float bf2f(short s){
  union { float f; uint32_t u; } cv; cv.u = ((uint32_t)(uint16_t)s) << 16; return cv.f;
}
__device__ __forceinline__ short f2bf(float f){
  union { float f; uint32_t u; } cv; cv.f = f;
  uint32_t r = cv.u + 0x7FFFu + ((cv.u >> 16) & 1u);
  return (short)(r >> 16);
}

typedef const __attribute__((address_space(1))) void* gas1_t;
typedef __attribute__((address_space(3))) void* las3_t;
__device__ __forceinline__ void gld16(const void* g, void* l){
  __builtin_amdgcn_global_load_lds((gas1_t)g, (las3_t)l, 16, 0, 0);
}

// ---------------- convert x to bf16 (vectorized) ----------------
__global__ __launch_bounds__(256) void cvt_x(const float* __restrict__ x,
                                             short* __restrict__ xb, int n8){
  int i = blockIdx.x * 256 + threadIdx.x;
  if (i >= n8) return;
  const float4* p = (const float4*)x;
  float4 a = p[i*2], b = p[i*2+1];
  short o[8] = { f2bf(a.x), f2bf(a.y), f2bf(a.z), f2bf(a.w),
                 f2bf(b.x), f2bf(b.y), f2bf(b.z), f2bf(b.w) };
  *(bf16x8*)(xb + i*8) = *(bf16x8*)o;
}

// -------- transpose+convert weights: dst[j*512 + k] = bf16(src[k*J + j]) ----
__global__ __launch_bounds__(256) void tconv(const float* __restrict__ src,
                                             short* __restrict__ dst, int J){
  __shared__ float tile[32][33];
  int jb = blockIdx.x * 32, kb = blockIdx.y * 32;
  int tx = threadIdx.x & 31, ty = threadIdx.x >> 5;   // ty 0..7
#pragma unroll
  for (int r = 0; r < 32; r += 8)
    tile[ty + r][tx] = src[(size_t)(kb + ty + r) * J + jb + tx];
  __syncthreads();
#pragma unroll
  for (int r = 0; r < 32; r += 8)
    dst[(size_t)(jb + ty + r) * 512 + kb + tx] = f2bf(tile[tx][ty + r]);
}

// -------------- 256-row bf16 MFMA GEMM, K=512, Bt is (N x K) ----------------
// BM=256, BK=32, 512 threads (8 waves: 2Mx4N).
// MODE 0: BN=256, wave-tile 128x64, acc[8][4]. QKV epilogue (relu q /
//         relu(k+pos) / v), bf16 out, quarter-restaged (stride 264 shorts).
// MODE 1: BN=128, wave-tile 128x32, acc[8][2]. proj epilogue (+bias), f32
//         out, quarter-restaged (stride 132 floats).
// Loop: stage(kt+1) -> ds_read/MFMA tile kt -> __syncthreads (proven R3 sync).
// Swizzle: 16B-chunk phys = log ^ (row&3) ^ ((row>>2)&3), both sides.
template<int MODE, int NCT>
__global__ __launch_bounds__(512, 2)
void gemm_bf16(const short* __restrict__ A, const short* __restrict__ Bt,
               short* __restrict__ oQ, short* __restrict__ oK, short* __restrict__ oV,
               const float* __restrict__ posenc,
               float* __restrict__ oF, const float* __restrict__ bias)
{
  constexpr int BN   = MODE ? 128 : 256;
  constexpr int NJ   = MODE ? 2 : 4;        // B frags per wave
  constexpr int WNW  = MODE ? 32 : 64;      // wave N width
  constexpr int SLOT = MODE ? 24576 : 32768;
  constexpr int BOFF = 16384;
  __shared__ __align__(16) char lds[MODE ? 49152 : 65536];
  constexpr int NT = 16;                    // K/32
  const int t = threadIdx.x;
  const int wave = t >> 6, lane = t & 63;

  // m204 bijective XCD swizzle
  constexpr int nwg = 98 * NCT;
  constexpr int q8 = nwg / 8, r8 = nwg % 8;
  const int orig = blockIdx.x;
  const int xcd = orig & 7, lid = orig >> 3;
  const int swz = (xcd < r8 ? xcd * (q8 + 1) : r8 * (q8 + 1) + (xcd - r8) * q8) + lid;
  const int rt = (swz / NCT) * 256;
  const int ct = (swz % NCT) * BN;

  const int wm = (wave >> 2) * 128;
  const int wn = (wave & 3) * WNW;
  const int fr = lane & 15;

  // ---- staging addressing (global source pre-swizzled; LDS dest linear) ----
  const int row0 = t >> 2;                                     // 0..127
  const int s0   = ((t & 3) ^ (row0 & 3) ^ ((row0 >> 2) & 3)) << 3;  // shorts
  const short* aBase = A  + (size_t)(rt + row0) * 512 + s0;
  const short* bBase = Bt + (size_t)(ct + row0) * 512 + s0;
  char* dBase = lds + wave * 1024;    // wave-uniform; HW adds lane*16

  auto stage = [&](int kt2) {
    char* d = dBase + (kt2 & 1) * SLOT;
    const short* a0 = aBase + kt2 * 32;
    gld16(a0,         d);            // A rows 0-127
    gld16(a0 + 65536, d + 8192);     // A rows 128-255 (+128*512 shorts)
    const short* b0 = bBase + kt2 * 32;
    gld16(b0,         d + BOFF);     // B rows 0-127
    if (MODE == 0)
      gld16(b0 + 65536, d + BOFF + 8192);  // B rows 128-255
  };

  // ---- fragment ds_read offsets (bytes, swizzled; (row&3)/((row>>2)&3) are
  //      invariant under +16*i and wave offsets) ----
  const int phys = ((lane >> 4) ^ (fr & 3) ^ ((fr >> 2) & 3)) << 4;
  const int offA = (wm + fr) * 64 + phys;
  const int offB = BOFF + (wn + fr) * 64 + phys;

  f32x4 zv = {0.f, 0.f, 0.f, 0.f};
  f32x4 acc[8][NJ];
#pragma unroll
  for (int i = 0; i < 8; i++)
#pragma unroll
    for (int j = 0; j < NJ; j++) acc[i][j] = zv;

  stage(0);
  __syncthreads();                       // tile 0 landed (full drain)

  for (int kt = 0; kt < NT; ++kt) {
    if (kt + 1 < NT) stage(kt + 1);      // other slot; its readers finished
                                         // before the barrier that ended kt-1
    const char* slb = lds + (kt & 1) * SLOT;
    bf16x8 af[8], bfv[NJ];
#pragma unroll
    for (int i = 0; i < 8; i++) af[i] = *(const bf16x8*)(slb + offA + i * 1024);
#pragma unroll
    for (int j = 0; j < NJ; j++) bfv[j] = *(const bf16x8*)(slb + offB + j * 1024);
#pragma unroll
    for (int i = 0; i < 8; i++)
#pragma unroll
      for (int j = 0; j < NJ; j++)
        acc[i][j] = __builtin_amdgcn_mfma_f32_16x16x32_bf16(af[i], bfv[j], acc[i][j], 0, 0, 0);
    __syncthreads();                     // drains stage(kt+1); retires reads
  }

  // ---- epilogue: quarter-restage (64 rows) through LDS, coalesced stores ----
  const int rb = (lane >> 4) << 2;       // D layout: row=(lane>>4)*4+reg
  if (MODE == 0) {
    short* ov = (short*)lds;             // [64][264] bf16 (33792 B)
    const int sel = ct >> 9;             // 0:Q 1:K 2:V (uniform per block)
    const int cb  = ct - sel * 512;
    short* outp = sel == 0 ? oQ : (sel == 1 ? oK : oV);
#pragma unroll
    for (int q = 0; q < 4; ++q) {
      if (q) __syncthreads();            // protect prev quarter's reads
      if ((wave >> 2) == (q >> 1)) {
        const int ib = (q & 1) * 4;
#pragma unroll
        for (int ii = 0; ii < 4; ii++)
#pragma unroll
          for (int j = 0; j < 4; j++)
#pragma unroll
            for (int r = 0; r < 4; r++)
              ov[(ii * 16 + rb + r) * 264 + wn + j * 16 + fr] = f2bf(acc[ib + ii][j][r]);
      }
      __syncthreads();
#pragma unroll
      for (int p = 0; p < 4; ++p) {
        int id = t + 512 * p;
        int row = id >> 5, cc = (id & 31) * 8;
        bf16x8 vv = *(const bf16x8*)&ov[row * 264 + cc];
        int grow = rt + q * 64 + row;
        short o[8];
        if (sel == 0) {
#pragma unroll
          for (int e = 0; e < 8; e++) o[e] = f2bf(fmaxf(bf2f(vv[e]), 0.f));
        } else if (sel == 1) {
          int nr = grow % N_;
          const float* pp = posenc + (size_t)nr * 512 + cb + cc;
          f32x4 p0 = *(const f32x4*)pp;
          f32x4 p1 = *(const f32x4*)(pp + 4);
#pragma unroll
          for (int e = 0; e < 4; e++) {
            o[e]     = f2bf(fmaxf(bf2f(vv[e]) + p0[e], 0.f));
            o[e + 4] = f2bf(fmaxf(bf2f(vv[e + 4]) + p1[e], 0.f));
          }
        } else {
#pragma unroll
          for (int e = 0; e < 8; e++) o[e] = vv[e];
        }
        *(bf16x8*)(outp + (size_t)grow * 512 + cb + cc) = *(bf16x8*)o;
      }
    }
  } else {
    float* ovf = (float*)lds;            // [64][132] f32 (33792 B)
#pragma unroll
    for (int q = 0; q < 4; ++q) {
      if (q) __syncthreads();
      if ((wave >> 2) == (q >> 1)) {
        const int ib = (q & 1) * 4;
#pragma unroll
        for (int ii = 0; ii < 4; ii++)
#pragma unroll
          for (int j = 0; j < 2; j++)
#pragma unroll
            for (int r = 0; r < 4; r++)
              ovf[(ii * 16 + rb + r) * 132 + wn + j * 16 + fr] = acc[ib + ii][j][r];
      }
      __syncthreads();
#pragma unroll
      for (int p = 0; p < 2; ++p) {
        int id = t + 512 * p;
        int row = id >> 4, cc = (id & 15) * 8;
        f32x4 v0 = *(const f32x4*)&ovf[row * 132 + cc];
        f32x4 v1 = *(const f32x4*)&ovf[row * 132 + cc + 4];
        v0 += *(const f32x4*)&bias[ct + cc];
        v1 += *(const f32x4*)&bias[ct + cc + 4];
        float* op = oF + (size_t)(rt + q * 64 + row) * 512 + ct + cc;
        *(f32x4*)op       = v0;
        *(f32x4*)(op + 4) = v1;
      }
    }
  }
}

// ------------- per-head KtV (64x64) + ksum, f32 partials, N split 7 ----------
__global__ __launch_bounds__(256)
void kvmat_part(const short* __restrict__ kb, const short* __restrict__ vb,
                float* __restrict__ pKV, float* __restrict__ pKS)
{
  __shared__ __align__(16) float lk[64][64];
  __shared__ __align__(16) float lv[64][64];
  const int chunk = blockIdx.x, bh = blockIdx.y;
  const int b = bh >> 3, h = bh & 7;
  const int t = threadIdx.x;
  const int tc = t >> 4, td = t & 15;
  const int kc = t & 63, kr = (t >> 6) * 16;
  float acc[4][4] = {};
  float ksacc = 0.f;

  for (int tile = 0; tile < 7; ++tile) {
    const int r0 = chunk * 448 + tile * 64;
    __syncthreads();
#pragma unroll
    for (int i = 0; i < 2; i++) {
      int idx = t + i * 256;
      int r = idx >> 3, c8 = (idx & 7) << 3;
      size_t g = (size_t)(b * N_ + r0 + r) * 512 + h * 64 + c8;
      bf16x8 kk = *(const bf16x8*)(kb + g);
      bf16x8 vv = *(const bf16x8*)(vb + g);
#pragma unroll
      for (int e = 0; e < 8; e++) { lk[r][c8 + e] = bf2f(kk[e]); lv[r][c8 + e] = bf2f(vv[e]); }
    }
    __syncthreads();
#pragma unroll 4
    for (int r = 0; r < 64; r++) {
      f32x4 k4 = *(const f32x4*)&lk[r][tc * 4];
      f32x4 v4 = *(const f32x4*)&lv[r][td * 4];
#pragma unroll
      for (int i = 0; i < 4; i++)
#pragma unroll
        for (int j = 0; j < 4; j++) acc[i][j] += k4[i] * v4[j];
    }
#pragma unroll 4
    for (int rr = 0; rr < 16; rr++) ksacc += lk[kr + rr][kc];
  }

  const int pbase = (bh * 7 + chunk) * 4096;
#pragma unroll
  for (int i = 0; i < 4; i++)
#pragma unroll
    for (int j = 0; j < 4; j++)
      pKV[pbase + (tc * 4 + i) * 64 + td * 4 + j] = acc[i][j];
  __syncthreads();
  float* red = &lk[0][0];
  red[t] = ksacc;
  __syncthreads();
  if (t < 64)
    pKS[(bh * 7 + chunk) * 64 + t] = red[t] + red[t + 64] + red[t + 128] + red[t + 192];
}

__global__ __launch_bounds__(256)
void kv_reduce(const float* __restrict__ pKV, const float* __restrict__ pKS,
               float* __restrict__ kvm, float* __restrict__ ksum)
{
  int bh = blockIdx.x, t = threadIdx.x;
#pragma unroll
  for (int i = 0; i < 16; i++) {
    int idx = t + i * 256;
    float s = 0.f;
#pragma unroll
    for (int c = 0; c < 7; c++) s += pKV[(bh * 7 + c) * 4096 + idx];
    kvm[bh * 4096 + idx] = s;
  }
  if (t < 64) {
    float s = 0.f;
#pragma unroll
    for (int c = 0; c < 7; c++) s += pKS[(bh * 7 + c) * 64 + t];
    ksum[bh * 64 + t] = s;
  }
}

// ------------- depthwise 5x5 conv on v, +bias -> pre (bf16) -------------
__global__ __launch_bounds__(256)
void conv_dw(const short* __restrict__ vb, const float* __restrict__ w,
             const float* __restrict__ bias, short* __restrict__ pre)
{
  __shared__ __align__(16) short lsv[5 * 56 * 64];
  __shared__ float lw[1600];
  __shared__ float lb[64];
  const int y = blockIdx.x, bh = blockIdx.y;
  const int b = bh >> 3, h = bh & 7;
  const int t = threadIdx.x;
  for (int i = t; i < 1600; i += 256) lw[i] = w[i];
  if (t < 64) lb[t] = bias[t];
  for (int i = t; i < 2240; i += 256) {
    int row = i / 448, rem = i - row * 448;
    int xx = rem >> 3, c8 = (rem & 7) << 3;
    int gy = y + row - 2;
    bf16x8 val = {0, 0, 0, 0, 0, 0, 0, 0};
    if ((unsigned)gy < 56u)
      val = *(const bf16x8*)(vb + (size_t)(b * N_ + gy * 56 + xx) * 512 + h * 64 + c8);
    int byt = ((row * 56 + xx) * 64 + c8) * 2;
    byt ^= (xx & 7) << 4;                 // bank-conflict swizzle
    *(bf16x8*)((char*)lsv + byt) = val;
  }
  __syncthreads();
  const int x = t >> 2, dq = t & 3;
  if (x >= 56) return;
  float acc[16];
#pragma unroll
  for (int i = 0; i < 16; i++) acc[i] = lb[dq * 16 + i];
#pragma unroll
  for (int dy = 0; dy < 5; ++dy) {
#pragma unroll
    for (int dx = 0; dx < 5; ++dx) {
      int xx = x + dx - 2;
      if ((unsigned)xx < 56u) {
        int byt = ((dy * 56 + xx) * 64 + dq * 16) * 2;
        byt ^= (xx & 7) << 4;
        bf16x8 v0 = *(const bf16x8*)((const char*)lsv + byt);
        bf16x8 v1 = *(const bf16x8*)((const char*)lsv + (byt ^ 16));
#pragma unroll
        for (int e = 0; e < 8; e++) {
          acc[e]     += bf2f(v0[e]) * lw[(dq * 16 + e) * 25 + dy * 5 + dx];
          acc[e + 8] += bf2f(v1[e]) * lw[(dq * 16 + e + 8) * 25 + dy * 5 + dx];
        }
      }
    }
  }
  size_t base = (size_t)(b * N_ + y * 56 + x) * 512 + h * 64 + dq * 16;
  short o[16];
#pragma unroll
  for (int i = 0; i < 16; i++) o[i] = f2bf(acc[i]);
  *(bf16x8*)(pre + base)     = *(bf16x8*)&o[0];
  *(bf16x8*)(pre + base + 8) = *(bf16x8*)&o[8];
}

// ------- attn: out = (q . kvmat) * z + fmap, in-place on pre (bf16) -------
__global__ __launch_bounds__(256)
void attn_comb(const short* __restrict__ qb, const float* __restrict__ kvm,
               const float* __restrict__ ksum, short* __restrict__ pre)
{
  __shared__ __align__(16) float lkv[4096];
  __shared__ __align__(16) float lq[4096];   // [c][p] transposed
  __shared__ float lks[64];
  const int pt = blockIdx.x, bh = blockIdx.y;
  const int b = bh >> 3, h = bh & 7;
  const int t = threadIdx.x;
  for (int i = t; i < 4096; i += 256) lkv[i] = kvm[bh * 4096 + i];
  if (t < 64) lks[t] = ksum[bh * 64 + t];
  {
    const int p = t & 63, cg = t >> 6;
    size_t g = (size_t)(b * N_ + pt * 64 + p) * 512 + h * 64 + cg * 16;
    bf16x8 qa = *(const bf16x8*)(qb + g);
    bf16x8 qc = *(const bf16x8*)(qb + g + 8);
#pragma unroll
    for (int e = 0; e < 8; e++) {
      lq[(cg * 16 + e) * 64 + p]     = bf2f(qa[e]);
      lq[(cg * 16 + 8 + e) * 64 + p] = bf2f(qc[e]);
    }
  }
  __syncthreads();
  const int p = t & 63, d0 = (t >> 6) * 16;
  float acc[16] = {};
  float zd = 0.f;
#pragma unroll 4
  for (int c = 0; c < 64; c++) {
    float qv = lq[c * 64 + p];
    zd += qv * lks[c];
    const f32x4* row = (const f32x4*)&lkv[c * 64 + d0];
    f32x4 m0 = row[0], m1 = row[1], m2 = row[2], m3 = row[3];
#pragma unroll
    for (int e = 0; e < 4; e++) {
      acc[e]      += qv * m0[e];
      acc[4 + e]  += qv * m1[e];
      acc[8 + e]  += qv * m2[e];
      acc[12 + e] += qv * m3[e];
    }
  }
  float z = 1.f / (zd + 1e-6f);
  size_t base = (size_t)(b * N_ + pt * 64 + p) * 512 + h * 64 + d0;
  bf16x8 f0 = *(const bf16x8*)(pre + base);
  bf16x8 f1 = *(const bf16x8*)(pre + base + 8);
  short o[16];
#pragma unroll
  for (int e = 0; e < 8; e++) {
    o[e]     = f2bf(acc[e] * z + bf2f(f0[e]));
    o[e + 8] = f2bf(acc[e + 8] * z + bf2f(f1[e]));
  }
  *(bf16x8*)(pre + base)     = *(bf16x8*)&o[0];
  *(bf16x8*)(pre + base + 8) = *(bf16x8*)&o[8];
}

// ---------------------------------------------------------------------------
extern "C" void kernel_launch(void* const* d_in, const int* in_sizes, int n_in,
                              void* d_out, int out_size, void* d_ws, size_t ws_size,
                              hipStream_t stream)
{
  const float* x     = (const float*)d_in[0];
  const float* Wq    = (const float*)d_in[3];
  const float* Wkv   = (const float*)d_in[4];
  const float* pos   = (const float*)d_in[5];
  const float* dwcw  = (const float*)d_in[6];
  const float* dwcb  = (const float*)d_in[7];
  const float* Wproj = (const float*)d_in[8];
  const float* bproj = (const float*)d_in[9];
  float* out = (float*)d_out;

  char* ws = (char*)d_ws;
  size_t off = 0;
  auto alloc = [&](size_t bytes) -> void* {
    void* p = ws + off;
    off = (off + bytes + 255) & ~(size_t)255;
    return p;
  };
  short* xb     = (short*)alloc((size_t)MTOT * 512 * 2);
  short* wqkvT  = (short*)alloc((size_t)1536 * 512 * 2);
  short* wprojT = (short*)alloc((size_t)512 * 512 * 2);
  short* qb     = (short*)alloc((size_t)MTOT * 512 * 2);
  short* kbuf   = (short*)alloc((size_t)MTOT * 512 * 2);
  short* vbuf   = (short*)alloc((size_t)MTOT * 512 * 2);
  float* pKV    = (float*)alloc((size_t)64 * 7 * 4096 * 4);
  float* pKS    = (float*)alloc((size_t)64 * 7 * 64 * 4);
  float* kvm    = (float*)alloc((size_t)64 * 4096 * 4);
  float* ksumB  = (float*)alloc((size_t)64 * 64 * 4);
  short* pre    = (short*)alloc((size_t)MTOT * 512 * 2);
  if (ws_size < off) return;   // workspace too small: leave output zeroed (visible failure)

  // 1. convert x
  cvt_x<<<dim3((MTOT * 512 / 8 + 255) / 256), dim3(256), 0, stream>>>(x, xb, MTOT * 512 / 8);
  // 2. transpose weights -> (N x K) bf16
  tconv<<<dim3(16, 16), dim3(256), 0, stream>>>(Wq,    wqkvT,              512);
  tconv<<<dim3(32, 16), dim3(256), 0, stream>>>(Wkv,   wqkvT + 512 * 512, 1024);
  tconv<<<dim3(16, 16), dim3(256), 0, stream>>>(Wproj, wprojT,             512);
  // 3. QKV GEMM, fused activations (256x256 tiles, 98*6=588 blocks)
  gemm_bf16<0, 6><<<dim3(588), dim3(512), 0, stream>>>(xb, wqkvT, qb, kbuf, vbuf, pos,
                                                       nullptr, nullptr);
  // 4. per-head KtV + ksum
  kvmat_part<<<dim3(7, 64), dim3(256), 0, stream>>>(kbuf, vbuf, pKV, pKS);
  kv_reduce<<<dim3(64), dim3(256), 0, stream>>>(pKV, pKS, kvm, ksumB);
  // 5. depthwise conv -> pre
  conv_dw<<<dim3(56, 64), dim3(256), 0, stream>>>(vbuf, dwcw, dwcb, pre);
  // 6. attention output + fmap (in-place on pre)
  attn_comb<<<dim3(49, 64), dim3(256), 0, stream>>>(qb, kvm, ksumB, pre);
  // 7. projection GEMM -> f32 out (256x128 tiles, 98*4=392 blocks)
  gemm_bf16<1, 4><<<dim3(392), dim3(512), 0, stream>>>(pre, wprojT, nullptr, nullptr, nullptr,
                                                       nullptr, out, bproj);
}

// Round 6
// 248.872 us; speedup vs baseline: 1.1202x; 1.0091x over previous
//
#include <hip/hip_runtime.h>
#include <stdint.h>

// SimplifiedLinearAttention: B=8, N=3136 (56x56), C=512, 8 heads x 64
// Pipeline: cvt -> transpose weights -> GEMM(QKV,fused act) -> kvmat/ksum ->
//           conv_dw -> attn(z,out,+fmap) -> GEMM(proj,+bias) -> f32 out
// R6: GEMM = 4-phase/K-tile counted-vmcnt pipeline (T3+T4) at BM=BN=256,
//     BK=64, 8 waves, 128KB dynamic LDS (2 K-tile buffers). Per phase:
//     stage 1 chunk of tile t+1 -> [vmcnt(6) at ks-entry phases] -> barrier
//     -> ds_read -> lgkmcnt(0)+sched_barrier -> setprio{16 MFMA} -> barrier.
//     vmcnt(0) only once (last tile). Epilogue strides fixed to 260.
#define B_    8
#define N_    3136
#define C_    512
#define MTOT  25088   // B_*N_

typedef __attribute__((ext_vector_type(8))) short bf16x8;
typedef __attribute__((ext_vector_type(4))) float f32x4;

__device__ __forceinline__ float bf2f(short s){
  union { float f; uint32_t u; } cv; cv.u = ((uint32_t)(uint16_t)s) << 16; return cv.f;
}
__device__ __forceinline__ short f2bf(float f){
  union { float f; uint32_t u; } cv; cv.f = f;
  uint32_t r = cv.u + 0x7FFFu + ((cv.u >> 16) & 1u);
  return (short)(r >> 16);
}

typedef const __attribute__((address_space(1))) void* gas1_t;
typedef __attribute__((address_space(3))) void* las3_t;
__device__ __forceinline__ void gld16(const void* g, void* l){
  __builtin_amdgcn_global_load_lds((gas1_t)g, (las3_t)l, 16, 0, 0);
}

#define BARR  __builtin_amdgcn_s_barrier()
#define SCHB  __builtin_amdgcn_sched_barrier(0)
#define LGKM0 asm volatile("s_waitcnt lgkmcnt(0)" ::: "memory")
#define VMC6  asm volatile("s_waitcnt vmcnt(6)" ::: "memory")
#define VMC0  asm volatile("s_waitcnt vmcnt(0)" ::: "memory")

// ---------------- convert x to bf16 (vectorized) ----------------
__global__ __launch_bounds__(256) void cvt_x(const float* __restrict__ x,
                                             short* __restrict__ xb, int n8){
  int i = blockIdx.x * 256 + threadIdx.x;
  if (i >= n8) return;
  const float4* p = (const float4*)x;
  float4 a = p[i*2], b = p[i*2+1];
  short o[8] = { f2bf(a.x), f2bf(a.y), f2bf(a.z), f2bf(a.w),
                 f2bf(b.x), f2bf(b.y), f2bf(b.z), f2bf(b.w) };
  *(bf16x8*)(xb + i*8) = *(bf16x8*)o;
}

// -------- transpose+convert weights: dst[j*512 + k] = bf16(src[k*J + j]) ----
__global__ __launch_bounds__(256) void tconv(const float* __restrict__ src,
                                             short* __restrict__ dst, int J){
  __shared__ float tile[32][33];
  int jb = blockIdx.x * 32, kb = blockIdx.y * 32;
  int tx = threadIdx.x & 31, ty = threadIdx.x >> 5;   // ty 0..7
#pragma unroll
  for (int r = 0; r < 32; r += 8)
    tile[ty + r][tx] = src[(size_t)(kb + ty + r) * J + jb + tx];
  __syncthreads();
#pragma unroll
  for (int r = 0; r < 32; r += 8)
    dst[(size_t)(jb + ty + r) * 512 + kb + tx] = f2bf(tile[tx][ty + r]);
}

// ---------------- 256x256 bf16 MFMA GEMM, K=512, Bt is (N x K) ----------------
// 8 waves (2M x 4N), wave-tile 128x64, acc[8][4]. BK=64 in 2 k-slices of 32.
// LDS (dynamic 128KB): buf b at b*64KB: A at [ks*16KB + row*64B], B at +32KB.
// Chunk g of tile t staged during phase g of tile t-1 (order A0,B0,A1,B1);
// steady-state in-flight = 3 chunks = 6 loads -> vmcnt(6) at phases (0,0),(1,0).
// Swizzle (involution both sides): 16B-chunk phys = log ^ ((row>>1)&3).
// MODE 0: QKV epilogue (relu q / relu(k+pos) / v, bf16). MODE 1: +bias, f32.
template<int MODE, int NCT>
__global__ __launch_bounds__(512, 2)
void gemm_bf16(const short* __restrict__ A, const short* __restrict__ Bt,
               short* __restrict__ oQ, short* __restrict__ oK, short* __restrict__ oV,
               const float* __restrict__ posenc,
               float* __restrict__ oF, const float* __restrict__ bias)
{
  extern __shared__ __align__(16) char lds[];
  const int tid = threadIdx.x;
  const int wave = tid >> 6, lane = tid & 63;
  const int fr = lane & 15;

  // m204 bijective XCD swizzle
  constexpr int nwg = 98 * NCT;
  constexpr int q8 = nwg / 8, r8 = nwg % 8;
  const int orig = blockIdx.x;
  const int xcd = orig & 7, lid = orig >> 3;
  const int swz = (xcd < r8 ? xcd * (q8 + 1) : r8 * (q8 + 1) + (xcd - r8) * q8) + lid;
  const int rt = (swz / NCT) * 256;
  const int ct = (swz % NCT) * 256;

  const int wm = (wave >> 2) * 128;
  const int wn = (wave & 3) * 64;

  // ---- staging: per-lane source (pre-swizzled), wave-uniform LDS dest ----
  const int srow = lane >> 2;                                  // 0..15
  const int csrc = ((lane & 3) ^ ((lane >> 3) & 3)) << 3;      // shorts
  const short* srcA = A  + (size_t)(rt + wave * 32 + srow) * 512 + csrc;
  const short* srcB = Bt + (size_t)(ct + wave * 32 + srow) * 512 + csrc;
  char* dA = lds + wave * 2048;
  char* dB = lds + 32768 + wave * 2048;

  auto stage = [&](int sb, int isB, int ks, int tt) {
    const short* s = (isB ? srcB : srcA) + tt * 64 + ks * 32;
    char* d = (isB ? dB : dA) + sb * 65536 + ks * 16384;
    gld16(s,        d);          // rows w*32 .. +15
    gld16(s + 8192, d + 1024);   // rows w*32+16 .. +31
  };

  // ---- fragment ds_read offsets (swizzled; (row>>1)&3 == (fr>>1)&3) ----
  const int cR   = (((lane >> 4) ^ ((fr >> 1) & 3)) << 4);
  const int offA = (wm + fr) * 64 + cR;
  const int offB = 32768 + (wn + fr) * 64 + cR;

  bf16x8 af[8], bfr[4];
  auto readA8 = [&](int buf, int ks) {
    const char* p = lds + buf * 65536 + ks * 16384 + offA;
#pragma unroll
    for (int i = 0; i < 8; i++) af[i] = *(const bf16x8*)(p + i * 1024);
  };
  auto readB2 = [&](int buf, int ks, int j0) {
    const char* p = lds + buf * 65536 + ks * 16384 + offB;
    bfr[j0]     = *(const bf16x8*)(p + j0 * 1024);
    bfr[j0 + 1] = *(const bf16x8*)(p + (j0 + 1) * 1024);
  };

  f32x4 zv = {0.f, 0.f, 0.f, 0.f};
  f32x4 acc[8][4];
#pragma unroll
  for (int i = 0; i < 8; i++)
#pragma unroll
    for (int j = 0; j < 4; j++) acc[i][j] = zv;

  auto mfma16 = [&](int ch) {
    __builtin_amdgcn_s_setprio(1);
#pragma unroll
    for (int i = 0; i < 8; i++) {
      acc[i][2*ch]   = __builtin_amdgcn_mfma_f32_16x16x32_bf16(af[i], bfr[2*ch],   acc[i][2*ch],   0, 0, 0);
      acc[i][2*ch+1] = __builtin_amdgcn_mfma_f32_16x16x32_bf16(af[i], bfr[2*ch+1], acc[i][2*ch+1], 0, 0, 0);
    }
    __builtin_amdgcn_s_setprio(0);
  };

  // prologue: tile 0 -> buf 0, chunk order A0,B0,A1,B1 (matches vmcnt math)
  stage(0, 0, 0, 0); stage(0, 1, 0, 0); stage(0, 0, 1, 0); stage(0, 1, 1, 0);

  for (int t = 0; t < 7; ++t) {
    const int buf = t & 1, sb = buf ^ 1, tt = t + 1;
    // phase (ks0, colhalf0)
    stage(sb, 0, 0, tt);
    VMC6; BARR; SCHB;
    readA8(buf, 0); readB2(buf, 0, 0);
    LGKM0; SCHB;
    mfma16(0);
    BARR; SCHB;
    // phase (ks0, colhalf1)
    stage(sb, 1, 0, tt);
    BARR; SCHB;
    readB2(buf, 0, 2);
    LGKM0; SCHB;
    mfma16(1);
    BARR; SCHB;
    // phase (ks1, colhalf0)
    stage(sb, 0, 1, tt);
    VMC6; BARR; SCHB;
    readA8(buf, 1); readB2(buf, 1, 0);
    LGKM0; SCHB;
    mfma16(0);
    BARR; SCHB;
    // phase (ks1, colhalf1)
    stage(sb, 1, 1, tt);
    BARR; SCHB;
    readB2(buf, 1, 2);
    LGKM0; SCHB;
    mfma16(1);
    BARR; SCHB;
  }
  // t = 7 (buf = 1), no staging; vmcnt(0) before the final k-slice
  {
    VMC6; BARR; SCHB;
    readA8(1, 0); readB2(1, 0, 0); LGKM0; SCHB; mfma16(0); BARR; SCHB;
    BARR; SCHB;
    readB2(1, 0, 2); LGKM0; SCHB; mfma16(1); BARR; SCHB;
    VMC0; BARR; SCHB;
    readA8(1, 1); readB2(1, 1, 0); LGKM0; SCHB; mfma16(0); BARR; SCHB;
    BARR; SCHB;
    readB2(1, 1, 2); LGKM0; SCHB; mfma16(1); BARR; SCHB;
  }

  // ---- epilogue: quarter-restage (64 rows) through LDS, coalesced stores ----
  const int rb = (lane >> 4) << 2;       // D layout: row=(lane>>4)*4+reg
  if (MODE == 0) {
    short* ov = (short*)lds;             // [64][260] bf16 (33280 B)
    const int sel = ct >> 9;             // 0:Q 1:K 2:V (uniform per block)
    const int cb  = ct - sel * 512;
    short* outp = sel == 0 ? oQ : (sel == 1 ? oK : oV);
#pragma unroll
    for (int q4 = 0; q4 < 4; ++q4) {
      if (q4) __syncthreads();           // protect prev quarter's reads
      if ((wave >> 2) == (q4 >> 1)) {    // waves owning rows q4*64..+63
        const int ib = (q4 & 1) * 4;
#pragma unroll
        for (int ii = 0; ii < 4; ii++)
#pragma unroll
          for (int j = 0; j < 4; j++)
#pragma unroll
            for (int r = 0; r < 4; r++)
              ov[(ii * 16 + rb + r) * 260 + wn + j * 16 + fr] = f2bf(acc[ib + ii][j][r]);
      }
      __syncthreads();
#pragma unroll
      for (int p = 0; p < 4; ++p) {
        int id = tid + 512 * p;
        int row = id >> 5, cc = (id & 31) * 8;
        bf16x8 vv = *(const bf16x8*)&ov[row * 260 + cc];
        int grow = rt + q4 * 64 + row;
        short o[8];
        if (sel == 0) {
#pragma unroll
          for (int e = 0; e < 8; e++) o[e] = f2bf(fmaxf(bf2f(vv[e]), 0.f));
        } else if (sel == 1) {
          int nr = grow % N_;
          const float* pp = posenc + (size_t)nr * 512 + cb + cc;
          f32x4 p0 = *(const f32x4*)pp;
          f32x4 p1 = *(const f32x4*)(pp + 4);
#pragma unroll
          for (int e = 0; e < 4; e++) {
            o[e]     = f2bf(fmaxf(bf2f(vv[e]) + p0[e], 0.f));
            o[e + 4] = f2bf(fmaxf(bf2f(vv[e + 4]) + p1[e], 0.f));
          }
        } else {
#pragma unroll
          for (int e = 0; e < 8; e++) o[e] = vv[e];
        }
        *(bf16x8*)(outp + (size_t)grow * 512 + cb + cc) = *(bf16x8*)o;
      }
    }
  } else {
    float* ovf = (float*)lds;            // [64][260] f32 (66560 B)
#pragma unroll
    for (int q4 = 0; q4 < 4; ++q4) {
      if (q4) __syncthreads();
      if ((wave >> 2) == (q4 >> 1)) {
        const int ib = (q4 & 1) * 4;
#pragma unroll
        for (int ii = 0; ii < 4; ii++)
#pragma unroll
          for (int j = 0; j < 4; j++)
#pragma unroll
            for (int r = 0; r < 4; r++)
              ovf[(ii * 16 + rb + r) * 260 + wn + j * 16 + fr] = acc[ib + ii][j][r];
      }
      __syncthreads();
#pragma unroll
      for (int p = 0; p < 4; ++p) {
        int id = tid + 512 * p;
        int row = id >> 5, cc = (id & 31) * 8;
        f32x4 v0 = *(const f32x4*)&ovf[row * 260 + cc];
        f32x4 v1 = *(const f32x4*)&ovf[row * 260 + cc + 4];
        v0 += *(const f32x4*)&bias[ct + cc];
        v1 += *(const f32x4*)&bias[ct + cc + 4];
        float* op = oF + (size_t)(rt + q4 * 64 + row) * 512 + ct + cc;
        *(f32x4*)op       = v0;
        *(f32x4*)(op + 4) = v1;
      }
    }
  }
}

// ------------- per-head KtV (64x64) + ksum, f32 partials, N split 7 ----------
__global__ __launch_bounds__(256)
void kvmat_part(const short* __restrict__ kb, const short* __restrict__ vb,
                float* __restrict__ pKV, float* __restrict__ pKS)
{
  __shared__ __align__(16) float lk[64][64];
  __shared__ __align__(16) float lv[64][64];
  const int chunk = blockIdx.x, bh = blockIdx.y;
  const int b = bh >> 3, h = bh & 7;
  const int t = threadIdx.x;
  const int tc = t >> 4, td = t & 15;
  const int kc = t & 63, kr = (t >> 6) * 16;
  float acc[4][4] = {};
  float ksacc = 0.f;

  for (int tile = 0; tile < 7; ++tile) {
    const int r0 = chunk * 448 + tile * 64;
    __syncthreads();
#pragma unroll
    for (int i = 0; i < 2; i++) {
      int idx = t + i * 256;
      int r = idx >> 3, c8 = (idx & 7) << 3;
      size_t g = (size_t)(b * N_ + r0 + r) * 512 + h * 64 + c8;
      bf16x8 kk = *(const bf16x8*)(kb + g);
      bf16x8 vv = *(const bf16x8*)(vb + g);
#pragma unroll
      for (int e = 0; e < 8; e++) { lk[r][c8 + e] = bf2f(kk[e]); lv[r][c8 + e] = bf2f(vv[e]); }
    }
    __syncthreads();
#pragma unroll 4
    for (int r = 0; r < 64; r++) {
      f32x4 k4 = *(const f32x4*)&lk[r][tc * 4];
      f32x4 v4 = *(const f32x4*)&lv[r][td * 4];
#pragma unroll
      for (int i = 0; i < 4; i++)
#pragma unroll
        for (int j = 0; j < 4; j++) acc[i][j] += k4[i] * v4[j];
    }
#pragma unroll 4
    for (int rr = 0; rr < 16; rr++) ksacc += lk[kr + rr][kc];
  }

  const int pbase = (bh * 7 + chunk) * 4096;
#pragma unroll
  for (int i = 0; i < 4; i++)
#pragma unroll
    for (int j = 0; j < 4; j++)
      pKV[pbase + (tc * 4 + i) * 64 + td * 4 + j] = acc[i][j];
  __syncthreads();
  float* red = &lk[0][0];
  red[t] = ksacc;
  __syncthreads();
  if (t < 64)
    pKS[(bh * 7 + chunk) * 64 + t] = red[t] + red[t + 64] + red[t + 128] + red[t + 192];
}

__global__ __launch_bounds__(256)
void kv_reduce(const float* __restrict__ pKV, const float* __restrict__ pKS,
               float* __restrict__ kvm, float* __restrict__ ksum)
{
  int bh = blockIdx.x, t = threadIdx.x;
#pragma unroll
  for (int i = 0; i < 16; i++) {
    int idx = t + i * 256;
    float s = 0.f;
#pragma unroll
    for (int c = 0; c < 7; c++) s += pKV[(bh * 7 + c) * 4096 + idx];
    kvm[bh * 4096 + idx] = s;
  }
  if (t < 64) {
    float s = 0.f;
#pragma unroll
    for (int c = 0; c < 7; c++) s += pKS[(bh * 7 + c) * 64 + t];
    ksum[bh * 64 + t] = s;
  }
}

// ------------- depthwise 5x5 conv on v, +bias -> pre (bf16) -------------
__global__ __launch_bounds__(256)
void conv_dw(const short* __restrict__ vb, const float* __restrict__ w,
             const float* __restrict__ bias, short* __restrict__ pre)
{
  __shared__ __align__(16) short lsv[5 * 56 * 64];
  __shared__ float lw[1600];
  __shared__ float lb[64];
  const int y = blockIdx.x, bh = blockIdx.y;
  const int b = bh >> 3, h = bh & 7;
  const int t = threadIdx.x;
  for (int i = t; i < 1600; i += 256) lw[i] = w[i];
  if (t < 64) lb[t] = bias[t];
  for (int i = t; i < 2240; i += 256) {
    int row = i / 448, rem = i - row * 448;
    int xx = rem >> 3, c8 = (rem & 7) << 3;
    int gy = y + row - 2;
    bf16x8 val = {0, 0, 0, 0, 0, 0, 0, 0};
    if ((unsigned)gy < 56u)
      val = *(const bf16x8*)(vb + (size_t)(b * N_ + gy * 56 + xx) * 512 + h * 64 + c8);
    int byt = ((row * 56 + xx) * 64 + c8) * 2;
    byt ^= (xx & 7) << 4;                 // bank-conflict swizzle
    *(bf16x8*)((char*)lsv + byt) = val;
  }
  __syncthreads();
  const int x = t >> 2, dq = t & 3;
  if (x >= 56) return;
  float acc[16];
#pragma unroll
  for (int i = 0; i < 16; i++) acc[i] = lb[dq * 16 + i];
#pragma unroll
  for (int dy = 0; dy < 5; ++dy) {
#pragma unroll
    for (int dx = 0; dx < 5; ++dx) {
      int xx = x + dx - 2;
      if ((unsigned)xx < 56u) {
        int byt = ((dy * 56 + xx) * 64 + dq * 16) * 2;
        byt ^= (xx & 7) << 4;
        bf16x8 v0 = *(const bf16x8*)((const char*)lsv + byt);
        bf16x8 v1 = *(const bf16x8*)((const char*)lsv + (byt ^ 16));
#pragma unroll
        for (int e = 0; e < 8; e++) {
          acc[e]     += bf2f(v0[e]) * lw[(dq * 16 + e) * 25 + dy * 5 + dx];
          acc[e + 8] += bf2f(v1[e]) * lw[(dq * 16 + e + 8) * 25 + dy * 5 + dx];
        }
      }
    }
  }
  size_t base = (size_t)(b * N_ + y * 56 + x) * 512 + h * 64 + dq * 16;
  short o[16];
#pragma unroll
  for (int i = 0; i < 16; i++) o[i] = f2bf(acc[i]);
  *(bf16x8*)(pre + base)     = *(bf16x8*)&o[0];
  *(bf16x8*)(pre + base + 8) = *(bf16x8*)&o[8];
}

// ------- attn: out = (q . kvmat) * z + fmap, in-place on pre (bf16) -------
__global__ __launch_bounds__(256)
void attn_comb(const short* __restrict__ qb, const float* __restrict__ kvm,
               const float* __restrict__ ksum, short* __restrict__ pre)
{
  __shared__ __align__(16) float lkv[4096];
  __shared__ __align__(16) float lq[4096];   // [c][p] transposed
  __shared__ float lks[64];
  const int pt = blockIdx.x, bh = blockIdx.y;
  const int b = bh >> 3, h = bh & 7;
  const int t = threadIdx.x;
  for (int i = t; i < 4096; i += 256) lkv[i] = kvm[bh * 4096 + i];
  if (t < 64) lks[t] = ksum[bh * 64 + t];
  {
    const int p = t & 63, cg = t >> 6;
    size_t g = (size_t)(b * N_ + pt * 64 + p) * 512 + h * 64 + cg * 16;
    bf16x8 qa = *(const bf16x8*)(qb + g);
    bf16x8 qc = *(const bf16x8*)(qb + g + 8);
#pragma unroll
    for (int e = 0; e < 8; e++) {
      lq[(cg * 16 + e) * 64 + p]     = bf2f(qa[e]);
      lq[(cg * 16 + 8 + e) * 64 + p] = bf2f(qc[e]);
    }
  }
  __syncthreads();
  const int p = t & 63, d0 = (t >> 6) * 16;
  float acc[16] = {};
  float zd = 0.f;
#pragma unroll 4
  for (int c = 0; c < 64; c++) {
    float qv = lq[c * 64 + p];
    zd += qv * lks[c];
    const f32x4* row = (const f32x4*)&lkv[c * 64 + d0];
    f32x4 m0 = row[0], m1 = row[1], m2 = row[2], m3 = row[3];
#pragma unroll
    for (int e = 0; e < 4; e++) {
      acc[e]      += qv * m0[e];
      acc[4 + e]  += qv * m1[e];
      acc[8 + e]  += qv * m2[e];
      acc[12 + e] += qv * m3[e];
    }
  }
  float z = 1.f / (zd + 1e-6f);
  size_t base = (size_t)(b * N_ + pt * 64 + p) * 512 + h * 64 + d0;
  bf16x8 f0 = *(const bf16x8*)(pre + base);
  bf16x8 f1 = *(const bf16x8*)(pre + base + 8);
  short o[16];
#pragma unroll
  for (int e = 0; e < 8; e++) {
    o[e]     = f2bf(acc[e] * z + bf2f(f0[e]));
    o[e + 8] = f2bf(acc[e + 8] * z + bf2f(f1[e]));
  }
  *(bf16x8*)(pre + base)     = *(bf16x8*)&o[0];
  *(bf16x8*)(pre + base + 8) = *(bf16x8*)&o[8];
}

// ---------------------------------------------------------------------------
extern "C" void kernel_launch(void* const* d_in, const int* in_sizes, int n_in,
                              void* d_out, int out_size, void* d_ws, size_t ws_size,
                              hipStream_t stream)
{
  const float* x     = (const float*)d_in[0];
  const float* Wq    = (const float*)d_in[3];
  const float* Wkv   = (const float*)d_in[4];
  const float* pos   = (const float*)d_in[5];
  const float* dwcw  = (const float*)d_in[6];
  const float* dwcb  = (const float*)d_in[7];
  const float* Wproj = (const float*)d_in[8];
  const float* bproj = (const float*)d_in[9];
  float* out = (float*)d_out;

  char* ws = (char*)d_ws;
  size_t off = 0;
  auto alloc = [&](size_t bytes) -> void* {
    void* p = ws + off;
    off = (off + bytes + 255) & ~(size_t)255;
    return p;
  };
  short* xb     = (short*)alloc((size_t)MTOT * 512 * 2);
  short* wqkvT  = (short*)alloc((size_t)1536 * 512 * 2);
  short* wprojT = (short*)alloc((size_t)512 * 512 * 2);
  short* qb     = (short*)alloc((size_t)MTOT * 512 * 2);
  short* kbuf   = (short*)alloc((size_t)MTOT * 512 * 2);
  short* vbuf   = (short*)alloc((size_t)MTOT * 512 * 2);
  float* pKV    = (float*)alloc((size_t)64 * 7 * 4096 * 4);
  float* pKS    = (float*)alloc((size_t)64 * 7 * 64 * 4);
  float* kvm    = (float*)alloc((size_t)64 * 4096 * 4);
  float* ksumB  = (float*)alloc((size_t)64 * 64 * 4);
  short* pre    = (short*)alloc((size_t)MTOT * 512 * 2);
  if (ws_size < off) return;   // workspace too small: leave output zeroed (visible failure)

  // allow 128KB dynamic LDS for the GEMMs (host-side attr, graph-safe)
  {
    auto k0 = gemm_bf16<0, 6>;
    auto k1 = gemm_bf16<1, 2>;
    hipFuncSetAttribute(reinterpret_cast<const void*>(k0),
                        hipFuncAttributeMaxDynamicSharedMemorySize, 131072);
    hipFuncSetAttribute(reinterpret_cast<const void*>(k1),
                        hipFuncAttributeMaxDynamicSharedMemorySize, 131072);
  }

  // 1. convert x
  cvt_x<<<dim3((MTOT * 512 / 8 + 255) / 256), dim3(256), 0, stream>>>(x, xb, MTOT * 512 / 8);
  // 2. transpose weights -> (N x K) bf16
  tconv<<<dim3(16, 16), dim3(256), 0, stream>>>(Wq,    wqkvT,              512);
  tconv<<<dim3(32, 16), dim3(256), 0, stream>>>(Wkv,   wqkvT + 512 * 512, 1024);
  tconv<<<dim3(16, 16), dim3(256), 0, stream>>>(Wproj, wprojT,             512);
  // 3. QKV GEMM, fused activations (256x256 tiles, 98*6=588 blocks)
  gemm_bf16<0, 6><<<dim3(588), dim3(512), 131072, stream>>>(xb, wqkvT, qb, kbuf, vbuf, pos,
                                                            nullptr, nullptr);
  // 4. per-head KtV + ksum
  kvmat_part<<<dim3(7, 64), dim3(256), 0, stream>>>(kbuf, vbuf, pKV, pKS);
  kv_reduce<<<dim3(64), dim3(256), 0, stream>>>(pKV, pKS, kvm, ksumB);
  // 5. depthwise conv -> pre
  conv_dw<<<dim3(56, 64), dim3(256), 0, stream>>>(vbuf, dwcw, dwcb, pre);
  // 6. attention output + fmap (in-place on pre)
  attn_comb<<<dim3(49, 64), dim3(256), 0, stream>>>(qb, kvm, ksumB, pre);
  // 7. projection GEMM -> f32 out (256x256 tiles, 98*2=196 blocks)
  gemm_bf16<1, 2><<<dim3(196), dim3(512), 131072, stream>>>(pre, wprojT, nullptr, nullptr, nullptr,
                                                            nullptr, out, bproj);
}

// Round 7
// 247.268 us; speedup vs baseline: 1.1275x; 1.0065x over previous
//
#include <hip/hip_runtime.h>
#include <stdint.h>

// SimplifiedLinearAttention: B=8, N=3136 (56x56), C=512, 8 heads x 64
// Pipeline: cvt -> transpose weights -> GEMM(QKV,fused act) -> kvmat/ksum ->
//           conv_dw -> attn(z,out,+fmap) -> GEMM(proj,+bias) -> f32 out
// R7: GEMM schedule rebuilt as 1-phase-lookahead register pipeline (m196/m201
//     lever): ds_reads for phase p+1 issue BEFORE MFMA of phase p (double reg
//     sets afU/afV, bX/bY), counted lgkmcnt(2/10) instead of lgkmcnt(0), ONE
//     barrier per phase, per-phase vmcnt [6,4,6,4]. Addressing, swizzle,
//     staging and epilogues byte-identical to R6 (passed, 0 bank conflicts).
#define B_    8
#define N_    3136
#define C_    512
#define MTOT  25088   // B_*N_

typedef __attribute__((ext_vector_type(8))) short bf16x8;
typedef __attribute__((ext_vector_type(4))) float f32x4;

__device__ __forceinline__ float bf2f(short s){
  union { float f; uint32_t u; } cv; cv.u = ((uint32_t)(uint16_t)s) << 16; return cv.f;
}
__device__ __forceinline__ short f2bf(float f){
  union { float f; uint32_t u; } cv; cv.f = f;
  uint32_t r = cv.u + 0x7FFFu + ((cv.u >> 16) & 1u);
  return (short)(r >> 16);
}

typedef const __attribute__((address_space(1))) void* gas1_t;
typedef __attribute__((address_space(3))) void* las3_t;
__device__ __forceinline__ void gld16(const void* g, void* l){
  __builtin_amdgcn_global_load_lds((gas1_t)g, (las3_t)l, 16, 0, 0);
}

#define BARR  __builtin_amdgcn_s_barrier()
#define SCHB  __builtin_amdgcn_sched_barrier(0)
#define VMC0  asm volatile("s_waitcnt vmcnt(0)" ::: "memory")
#define VMC4  asm volatile("s_waitcnt vmcnt(4)" ::: "memory")
#define VMC6  asm volatile("s_waitcnt vmcnt(6)" ::: "memory")
#define LGKM0  asm volatile("s_waitcnt lgkmcnt(0)" ::: "memory")
#define LGKM2  asm volatile("s_waitcnt lgkmcnt(2)" ::: "memory")
#define LGKM10 asm volatile("s_waitcnt lgkmcnt(10)" ::: "memory")

// ---------------- convert x to bf16 (vectorized) ----------------
__global__ __launch_bounds__(256) void cvt_x(const float* __restrict__ x,
                                             short* __restrict__ xb, int n8){
  int i = blockIdx.x * 256 + threadIdx.x;
  if (i >= n8) return;
  const float4* p = (const float4*)x;
  float4 a = p[i*2], b = p[i*2+1];
  short o[8] = { f2bf(a.x), f2bf(a.y), f2bf(a.z), f2bf(a.w),
                 f2bf(b.x), f2bf(b.y), f2bf(b.z), f2bf(b.w) };
  *(bf16x8*)(xb + i*8) = *(bf16x8*)o;
}

// -------- transpose+convert weights: dst[j*512 + k] = bf16(src[k*J + j]) ----
__global__ __launch_bounds__(256) void tconv(const float* __restrict__ src,
                                             short* __restrict__ dst, int J){
  __shared__ float tile[32][33];
  int jb = blockIdx.x * 32, kb = blockIdx.y * 32;
  int tx = threadIdx.x & 31, ty = threadIdx.x >> 5;   // ty 0..7
#pragma unroll
  for (int r = 0; r < 32; r += 8)
    tile[ty + r][tx] = src[(size_t)(kb + ty + r) * J + jb + tx];
  __syncthreads();
#pragma unroll
  for (int r = 0; r < 32; r += 8)
    dst[(size_t)(jb + ty + r) * 512 + kb + tx] = f2bf(tile[tx][ty + r]);
}

// ---------------- 256x256 bf16 MFMA GEMM, K=512, Bt is (N x K) ----------------
// 8 waves (2M x 4N), wave-tile 128x64, acc[8][4]. BK=64 in 2 k-slices of 32.
// LDS (dynamic 128KB): buf b at b*64KB: A at [ks*16KB + row*64B], B at +32KB.
// Chunk order per tile: g0=(A,ks0)@P0, g1=(B,ks0)@P1, g2=(A,ks1)@P2,
// g3=(B,ks1)@P3 (staged one tile ahead). Per phase (1-lookahead pipeline):
//   stage(g_i of t+1) ; vmcnt(N_i) ; s_barrier ; ds_read set for phase i+1 ;
//   lgkmcnt(R_{i+1}) [retires set_i, DS in-order] ; setprio{16 MFMA set_i}.
// vmcnt per phase: [6,4,6,4]. Swizzle identical to R6 (0 bank conflicts).
// MODE 0: QKV epilogue (relu q / relu(k+pos) / v, bf16). MODE 1: +bias, f32.
template<int MODE, int NCT>
__global__ __launch_bounds__(512, 2)
void gemm_bf16(const short* __restrict__ A, const short* __restrict__ Bt,
               short* __restrict__ oQ, short* __restrict__ oK, short* __restrict__ oV,
               const float* __restrict__ posenc,
               float* __restrict__ oF, const float* __restrict__ bias)
{
  extern __shared__ __align__(16) char lds[];
  const int tid = threadIdx.x;
  const int wave = tid >> 6, lane = tid & 63;
  const int fr = lane & 15;

  // m204 bijective XCD swizzle
  constexpr int nwg = 98 * NCT;
  constexpr int q8 = nwg / 8, r8 = nwg % 8;
  const int orig = blockIdx.x;
  const int xcd = orig & 7, lid = orig >> 3;
  const int swz = (xcd < r8 ? xcd * (q8 + 1) : r8 * (q8 + 1) + (xcd - r8) * q8) + lid;
  const int rt = (swz / NCT) * 256;
  const int ct = (swz % NCT) * 256;

  const int wm = (wave >> 2) * 128;
  const int wn = (wave & 3) * 64;

  // ---- staging: per-lane source (pre-swizzled), wave-uniform LDS dest ----
  const int srow = lane >> 2;                                  // 0..15
  const int csrc = ((lane & 3) ^ ((lane >> 3) & 3)) << 3;      // shorts
  const short* srcA = A  + (size_t)(rt + wave * 32 + srow) * 512 + csrc;
  const short* srcB = Bt + (size_t)(ct + wave * 32 + srow) * 512 + csrc;
  char* dA = lds + wave * 2048;
  char* dB = lds + 32768 + wave * 2048;

  auto stage = [&](int sbb, int isB, int ks, int tt) {
    const short* s = (isB ? srcB : srcA) + tt * 64 + ks * 32;
    char* d = (isB ? dB : dA) + sbb + ks * 16384;
    gld16(s,        d);          // rows w*32 .. +15
    gld16(s + 8192, d + 1024);   // rows w*32+16 .. +31
  };

  // ---- fragment ds_read offsets (swizzled; (row>>1)&3 == (fr>>1)&3) ----
  const int cR   = (((lane >> 4) ^ ((fr >> 1) & 3)) << 4);
  const int offA = (wm + fr) * 64 + cR;
  const int offB = 32768 + (wn + fr) * 64 + cR;

#define READ_A(dst, bufb, ks) do { \
    const char* _p = lds + (bufb) + (ks) * 16384 + offA; \
    _Pragma("unroll") \
    for (int _i = 0; _i < 8; _i++) dst[_i] = *(const bf16x8*)(_p + _i * 1024); \
  } while (0)
#define READ_B2(dst, bufb, ks, j0) do { \
    const char* _p = lds + (bufb) + (ks) * 16384 + offB + (j0) * 1024; \
    dst[0] = *(const bf16x8*)(_p); \
    dst[1] = *(const bf16x8*)(_p + 1024); \
  } while (0)
#define MFMA16(afv, bv, jb) do { \
    __builtin_amdgcn_s_setprio(1); \
    _Pragma("unroll") \
    for (int _i = 0; _i < 8; _i++) { \
      acc[_i][jb]     = __builtin_amdgcn_mfma_f32_16x16x32_bf16(afv[_i], bv[0], acc[_i][jb],     0, 0, 0); \
      acc[_i][jb + 1] = __builtin_amdgcn_mfma_f32_16x16x32_bf16(afv[_i], bv[1], acc[_i][jb + 1], 0, 0, 0); \
    } \
    __builtin_amdgcn_s_setprio(0); \
  } while (0)

  f32x4 zv = {0.f, 0.f, 0.f, 0.f};
  f32x4 acc[8][4];
#pragma unroll
  for (int i = 0; i < 8; i++)
#pragma unroll
    for (int j = 0; j < 4; j++) acc[i][j] = zv;

  bf16x8 afU[8], afV[8], bX[2], bY[2];

  // prologue: tile 0 -> buf 0 (g0..g3), then pre-read P0-set
  stage(0, 0, 0, 0); stage(0, 1, 0, 0); stage(0, 0, 1, 0); stage(0, 1, 1, 0);
  VMC4; BARR; SCHB;               // g0,g1 landed (g2,g3 may fly)
  READ_A(afU, 0, 0);
  READ_B2(bX, 0, 0, 0);

  for (int t = 0; t < 7; ++t) {
    const int bufb = (t & 1) * 65536, sbb = bufb ^ 65536;
    // P0: MFMA(afU,bX ks0c0); read bY(ks0c1); stage g0'(A ks0, t+1)
    stage(sbb, 0, 0, t + 1);
    VMC6; BARR; SCHB;             // g1(t) landed
    READ_B2(bY, bufb, 0, 2);
    LGKM2; SCHB;                  // P0-set (afU,bX) complete
    MFMA16(afU, bX, 0);
    // P1: MFMA(afU,bY ks0c1); read afV,bX(ks1); stage g1'(B ks0)
    stage(sbb, 1, 0, t + 1);
    VMC4; BARR; SCHB;             // g2(t),g3(t) landed
    READ_A(afV, bufb, 1);
    READ_B2(bX, bufb, 1, 0);
    LGKM10; SCHB;                 // bY complete
    MFMA16(afU, bY, 2);
    // P2: MFMA(afV,bX ks1c0); read bY(ks1c1); stage g2'(A ks1)
    stage(sbb, 0, 1, t + 1);
    VMC6; BARR; SCHB;
    READ_B2(bY, bufb, 1, 2);
    LGKM2; SCHB;                  // afV,bX complete
    MFMA16(afV, bX, 0);
    // P3: MFMA(afV,bY ks1c1); read afU,bX(t+1 ks0); stage g3'(B ks1)
    stage(sbb, 1, 1, t + 1);
    VMC4; BARR; SCHB;             // g0',g1' landed
    READ_A(afU, sbb, 0);
    READ_B2(bX, sbb, 0, 0);
    LGKM10; SCHB;                 // bY complete
    MFMA16(afV, bY, 2);
  }
  {
    const int bufb = 65536;       // t = 7, no staging
    // P0
    VMC4; BARR; SCHB;
    READ_B2(bY, bufb, 0, 2);
    LGKM2; SCHB;
    MFMA16(afU, bX, 0);
    // P1
    VMC0; BARR; SCHB;             // g2,g3 of tile 7 landed
    READ_A(afV, bufb, 1);
    READ_B2(bX, bufb, 1, 0);
    LGKM10; SCHB;
    MFMA16(afU, bY, 2);
    // P2 (no barrier needed: data visibility established at P1)
    READ_B2(bY, bufb, 1, 2);
    LGKM2; SCHB;
    MFMA16(afV, bX, 0);
    // P3
    LGKM0; SCHB;
    MFMA16(afV, bY, 2);
  }

  BARR; SCHB;                     // all LDS reads done -> reusable

  // ---- epilogue: quarter-restage (64 rows) through LDS, coalesced stores ----
  const int rb = (lane >> 4) << 2;       // D layout: row=(lane>>4)*4+reg
  if (MODE == 0) {
    short* ov = (short*)lds;             // [64][260] bf16 (33280 B)
    const int sel = ct >> 9;             // 0:Q 1:K 2:V (uniform per block)
    const int cb  = ct - sel * 512;
    short* outp = sel == 0 ? oQ : (sel == 1 ? oK : oV);
#pragma unroll
    for (int q4 = 0; q4 < 4; ++q4) {
      if (q4) __syncthreads();           // protect prev quarter's reads
      if ((wave >> 2) == (q4 >> 1)) {    // waves owning rows q4*64..+63
        const int ib = (q4 & 1) * 4;
#pragma unroll
        for (int ii = 0; ii < 4; ii++)
#pragma unroll
          for (int j = 0; j < 4; j++)
#pragma unroll
            for (int r = 0; r < 4; r++)
              ov[(ii * 16 + rb + r) * 260 + wn + j * 16 + fr] = f2bf(acc[ib + ii][j][r]);
      }
      __syncthreads();
#pragma unroll
      for (int p = 0; p < 4; ++p) {
        int id = tid + 512 * p;
        int row = id >> 5, cc = (id & 31) * 8;
        bf16x8 vv = *(const bf16x8*)&ov[row * 260 + cc];
        int grow = rt + q4 * 64 + row;
        short o[8];
        if (sel == 0) {
#pragma unroll
          for (int e = 0; e < 8; e++) o[e] = f2bf(fmaxf(bf2f(vv[e]), 0.f));
        } else if (sel == 1) {
          int nr = grow % N_;
          const float* pp = posenc + (size_t)nr * 512 + cb + cc;
          f32x4 p0 = *(const f32x4*)pp;
          f32x4 p1 = *(const f32x4*)(pp + 4);
#pragma unroll
          for (int e = 0; e < 4; e++) {
            o[e]     = f2bf(fmaxf(bf2f(vv[e]) + p0[e], 0.f));
            o[e + 4] = f2bf(fmaxf(bf2f(vv[e + 4]) + p1[e], 0.f));
          }
        } else {
#pragma unroll
          for (int e = 0; e < 8; e++) o[e] = vv[e];
        }
        *(bf16x8*)(outp + (size_t)grow * 512 + cb + cc) = *(bf16x8*)o;
      }
    }
  } else {
    float* ovf = (float*)lds;            // [64][260] f32 (66560 B)
#pragma unroll
    for (int q4 = 0; q4 < 4; ++q4) {
      if (q4) __syncthreads();
      if ((wave >> 2) == (q4 >> 1)) {
        const int ib = (q4 & 1) * 4;
#pragma unroll
        for (int ii = 0; ii < 4; ii++)
#pragma unroll
          for (int j = 0; j < 4; j++)
#pragma unroll
            for (int r = 0; r < 4; r++)
              ovf[(ii * 16 + rb + r) * 260 + wn + j * 16 + fr] = acc[ib + ii][j][r];
      }
      __syncthreads();
#pragma unroll
      for (int p = 0; p < 4; ++p) {
        int id = tid + 512 * p;
        int row = id >> 5, cc = (id & 31) * 8;
        f32x4 v0 = *(const f32x4*)&ovf[row * 260 + cc];
        f32x4 v1 = *(const f32x4*)&ovf[row * 260 + cc + 4];
        v0 += *(const f32x4*)&bias[ct + cc];
        v1 += *(const f32x4*)&bias[ct + cc + 4];
        float* op = oF + (size_t)(rt + q4 * 64 + row) * 512 + ct + cc;
        *(f32x4*)op       = v0;
        *(f32x4*)(op + 4) = v1;
      }
    }
  }
#undef READ_A
#undef READ_B2
#undef MFMA16
}

// ------------- per-head KtV (64x64) + ksum, f32 partials, N split 7 ----------
__global__ __launch_bounds__(256)
void kvmat_part(const short* __restrict__ kb, const short* __restrict__ vb,
                float* __restrict__ pKV, float* __restrict__ pKS)
{
  __shared__ __align__(16) float lk[64][64];
  __shared__ __align__(16) float lv[64][64];
  const int chunk = blockIdx.x, bh = blockIdx.y;
  const int b = bh >> 3, h = bh & 7;
  const int t = threadIdx.x;
  const int tc = t >> 4, td = t & 15;
  const int kc = t & 63, kr = (t >> 6) * 16;
  float acc[4][4] = {};
  float ksacc = 0.f;

  for (int tile = 0; tile < 7; ++tile) {
    const int r0 = chunk * 448 + tile * 64;
    __syncthreads();
#pragma unroll
    for (int i = 0; i < 2; i++) {
      int idx = t + i * 256;
      int r = idx >> 3, c8 = (idx & 7) << 3;
      size_t g = (size_t)(b * N_ + r0 + r) * 512 + h * 64 + c8;
      bf16x8 kk = *(const bf16x8*)(kb + g);
      bf16x8 vv = *(const bf16x8*)(vb + g);
#pragma unroll
      for (int e = 0; e < 8; e++) { lk[r][c8 + e] = bf2f(kk[e]); lv[r][c8 + e] = bf2f(vv[e]); }
    }
    __syncthreads();
#pragma unroll 4
    for (int r = 0; r < 64; r++) {
      f32x4 k4 = *(const f32x4*)&lk[r][tc * 4];
      f32x4 v4 = *(const f32x4*)&lv[r][td * 4];
#pragma unroll
      for (int i = 0; i < 4; i++)
#pragma unroll
        for (int j = 0; j < 4; j++) acc[i][j] += k4[i] * v4[j];
    }
#pragma unroll 4
    for (int rr = 0; rr < 16; rr++) ksacc += lk[kr + rr][kc];
  }

  const int pbase = (bh * 7 + chunk) * 4096;
#pragma unroll
  for (int i = 0; i < 4; i++)
#pragma unroll
    for (int j = 0; j < 4; j++)
      pKV[pbase + (tc * 4 + i) * 64 + td * 4 + j] = acc[i][j];
  __syncthreads();
  float* red = &lk[0][0];
  red[t] = ksacc;
  __syncthreads();
  if (t < 64)
    pKS[(bh * 7 + chunk) * 64 + t] = red[t] + red[t + 64] + red[t + 128] + red[t + 192];
}

__global__ __launch_bounds__(256)
void kv_reduce(const float* __restrict__ pKV, const float* __restrict__ pKS,
               float* __restrict__ kvm, float* __restrict__ ksum)
{
  int bh = blockIdx.x, t = threadIdx.x;
#pragma unroll
  for (int i = 0; i < 16; i++) {
    int idx = t + i * 256;
    float s = 0.f;
#pragma unroll
    for (int c = 0; c < 7; c++) s += pKV[(bh * 7 + c) * 4096 + idx];
    kvm[bh * 4096 + idx] = s;
  }
  if (t < 64) {
    float s = 0.f;
#pragma unroll
    for (int c = 0; c < 7; c++) s += pKS[(bh * 7 + c) * 64 + t];
    ksum[bh * 64 + t] = s;
  }
}

// ------------- depthwise 5x5 conv on v, +bias -> pre (bf16) -------------
__global__ __launch_bounds__(256)
void conv_dw(const short* __restrict__ vb, const float* __restrict__ w,
             const float* __restrict__ bias, short* __restrict__ pre)
{
  __shared__ __align__(16) short lsv[5 * 56 * 64];
  __shared__ float lw[1600];
  __shared__ float lb[64];
  const int y = blockIdx.x, bh = blockIdx.y;
  const int b = bh >> 3, h = bh & 7;
  const int t = threadIdx.x;
  for (int i = t; i < 1600; i += 256) lw[i] = w[i];
  if (t < 64) lb[t] = bias[t];
  for (int i = t; i < 2240; i += 256) {
    int row = i / 448, rem = i - row * 448;
    int xx = rem >> 3, c8 = (rem & 7) << 3;
    int gy = y + row - 2;
    bf16x8 val = {0, 0, 0, 0, 0, 0, 0, 0};
    if ((unsigned)gy < 56u)
      val = *(const bf16x8*)(vb + (size_t)(b * N_ + gy * 56 + xx) * 512 + h * 64 + c8);
    int byt = ((row * 56 + xx) * 64 + c8) * 2;
    byt ^= (xx & 7) << 4;                 // bank-conflict swizzle
    *(bf16x8*)((char*)lsv + byt) = val;
  }
  __syncthreads();
  const int x = t >> 2, dq = t & 3;
  if (x >= 56) return;
  float acc[16];
#pragma unroll
  for (int i = 0; i < 16; i++) acc[i] = lb[dq * 16 + i];
#pragma unroll
  for (int dy = 0; dy < 5; ++dy) {
#pragma unroll
    for (int dx = 0; dx < 5; ++dx) {
      int xx = x + dx - 2;
      if ((unsigned)xx < 56u) {
        int byt = ((dy * 56 + xx) * 64 + dq * 16) * 2;
        byt ^= (xx & 7) << 4;
        bf16x8 v0 = *(const bf16x8*)((const char*)lsv + byt);
        bf16x8 v1 = *(const bf16x8*)((const char*)lsv + (byt ^ 16));
#pragma unroll
        for (int e = 0; e < 8; e++) {
          acc[e]     += bf2f(v0[e]) * lw[(dq * 16 + e) * 25 + dy * 5 + dx];
          acc[e + 8] += bf2f(v1[e]) * lw[(dq * 16 + e + 8) * 25 + dy * 5 + dx];
        }
      }
    }
  }
  size_t base = (size_t)(b * N_ + y * 56 + x) * 512 + h * 64 + dq * 16;
  short o[16];
#pragma unroll
  for (int i = 0; i < 16; i++) o[i] = f2bf(acc[i]);
  *(bf16x8*)(pre + base)     = *(bf16x8*)&o[0];
  *(bf16x8*)(pre + base + 8) = *(bf16x8*)&o[8];
}

// ------- attn: out = (q . kvmat) * z + fmap, in-place on pre (bf16) -------
__global__ __launch_bounds__(256)
void attn_comb(const short* __restrict__ qb, const float* __restrict__ kvm,
               const float* __restrict__ ksum, short* __restrict__ pre)
{
  __shared__ __align__(16) float lkv[4096];
  __shared__ __align__(16) float lq[4096];   // [c][p] transposed
  __shared__ float lks[64];
  const int pt = blockIdx.x, bh = blockIdx.y;
  const int b = bh >> 3, h = bh & 7;
  const int t = threadIdx.x;
  for (int i = t; i < 4096; i += 256) lkv[i] = kvm[bh * 4096 + i];
  if (t < 64) lks[t] = ksum[bh * 64 + t];
  {
    const int p = t & 63, cg = t >> 6;
    size_t g = (size_t)(b * N_ + pt * 64 + p) * 512 + h * 64 + cg * 16;
    bf16x8 qa = *(const bf16x8*)(qb + g);
    bf16x8 qc = *(const bf16x8*)(qb + g + 8);
#pragma unroll
    for (int e = 0; e < 8; e++) {
      lq[(cg * 16 + e) * 64 + p]     = bf2f(qa[e]);
      lq[(cg * 16 + 8 + e) * 64 + p] = bf2f(qc[e]);
    }
  }
  __syncthreads();
  const int p = t & 63, d0 = (t >> 6) * 16;
  float acc[16] = {};
  float zd = 0.f;
#pragma unroll 4
  for (int c = 0; c < 64; c++) {
    float qv = lq[c * 64 + p];
    zd += qv * lks[c];
    const f32x4* row = (const f32x4*)&lkv[c * 64 + d0];
    f32x4 m0 = row[0], m1 = row[1], m2 = row[2], m3 = row[3];
#pragma unroll
    for (int e = 0; e < 4; e++) {
      acc[e]      += qv * m0[e];
      acc[4 + e]  += qv * m1[e];
      acc[8 + e]  += qv * m2[e];
      acc[12 + e] += qv * m3[e];
    }
  }
  float z = 1.f / (zd + 1e-6f);
  size_t base = (size_t)(b * N_ + pt * 64 + p) * 512 + h * 64 + d0;
  bf16x8 f0 = *(const bf16x8*)(pre + base);
  bf16x8 f1 = *(const bf16x8*)(pre + base + 8);
  short o[16];
#pragma unroll
  for (int e = 0; e < 8; e++) {
    o[e]     = f2bf(acc[e] * z + bf2f(f0[e]));
    o[e + 8] = f2bf(acc[e + 8] * z + bf2f(f1[e]));
  }
  *(bf16x8*)(pre + base)     = *(bf16x8*)&o[0];
  *(bf16x8*)(pre + base + 8) = *(bf16x8*)&o[8];
}

// ---------------------------------------------------------------------------
extern "C" void kernel_launch(void* const* d_in, const int* in_sizes, int n_in,
                              void* d_out, int out_size, void* d_ws, size_t ws_size,
                              hipStream_t stream)
{
  const float* x     = (const float*)d_in[0];
  const float* Wq    = (const float*)d_in[3];
  const float* Wkv   = (const float*)d_in[4];
  const float* pos   = (const float*)d_in[5];
  const float* dwcw  = (const float*)d_in[6];
  const float* dwcb  = (const float*)d_in[7];
  const float* Wproj = (const float*)d_in[8];
  const float* bproj = (const float*)d_in[9];
  float* out = (float*)d_out;

  char* ws = (char*)d_ws;
  size_t off = 0;
  auto alloc = [&](size_t bytes) -> void* {
    void* p = ws + off;
    off = (off + bytes + 255) & ~(size_t)255;
    return p;
  };
  short* xb     = (short*)alloc((size_t)MTOT * 512 * 2);
  short* wqkvT  = (short*)alloc((size_t)1536 * 512 * 2);
  short* wprojT = (short*)alloc((size_t)512 * 512 * 2);
  short* qb     = (short*)alloc((size_t)MTOT * 512 * 2);
  short* kbuf   = (short*)alloc((size_t)MTOT * 512 * 2);
  short* vbuf   = (short*)alloc((size_t)MTOT * 512 * 2);
  float* pKV    = (float*)alloc((size_t)64 * 7 * 4096 * 4);
  float* pKS    = (float*)alloc((size_t)64 * 7 * 64 * 4);
  float* kvm    = (float*)alloc((size_t)64 * 4096 * 4);
  float* ksumB  = (float*)alloc((size_t)64 * 64 * 4);
  short* pre    = (short*)alloc((size_t)MTOT * 512 * 2);
  if (ws_size < off) return;   // workspace too small: leave output zeroed (visible failure)

  // allow 128KB dynamic LDS for the GEMMs (host-side attr, graph-safe)
  {
    auto k0 = gemm_bf16<0, 6>;
    auto k1 = gemm_bf16<1, 2>;
    hipFuncSetAttribute(reinterpret_cast<const void*>(k0),
                        hipFuncAttributeMaxDynamicSharedMemorySize, 131072);
    hipFuncSetAttribute(reinterpret_cast<const void*>(k1),
                        hipFuncAttributeMaxDynamicSharedMemorySize, 131072);
  }

  // 1. convert x
  cvt_x<<<dim3((MTOT * 512 / 8 + 255) / 256), dim3(256), 0, stream>>>(x, xb, MTOT * 512 / 8);
  // 2. transpose weights -> (N x K) bf16
  tconv<<<dim3(16, 16), dim3(256), 0, stream>>>(Wq,    wqkvT,              512);
  tconv<<<dim3(32, 16), dim3(256), 0, stream>>>(Wkv,   wqkvT + 512 * 512, 1024);
  tconv<<<dim3(16, 16), dim3(256), 0, stream>>>(Wproj, wprojT,             512);
  // 3. QKV GEMM, fused activations (256x256 tiles, 98*6=588 blocks)
  gemm_bf16<0, 6><<<dim3(588), dim3(512), 131072, stream>>>(xb, wqkvT, qb, kbuf, vbuf, pos,
                                                            nullptr, nullptr);
  // 4. per-head KtV + ksum
  kvmat_part<<<dim3(7, 64), dim3(256), 0, stream>>>(kbuf, vbuf, pKV, pKS);
  kv_reduce<<<dim3(64), dim3(256), 0, stream>>>(pKV, pKS, kvm, ksumB);
  // 5. depthwise conv -> pre
  conv_dw<<<dim3(56, 64), dim3(256), 0, stream>>>(vbuf, dwcw, dwcb, pre);
  // 6. attention output + fmap (in-place on pre)
  attn_comb<<<dim3(49, 64), dim3(256), 0, stream>>>(qb, kvm, ksumB, pre);
  // 7. projection GEMM -> f32 out (256x256 tiles, 98*2=196 blocks)
  gemm_bf16<1, 2><<<dim3(196), dim3(512), 131072, stream>>>(pre, wprojT, nullptr, nullptr, nullptr,
                                                            nullptr, out, bproj);
}

// Round 8
// 234.070 us; speedup vs baseline: 1.1911x; 1.0564x over previous
//
#include <hip/hip_runtime.h>
#include <stdint.h>

// SimplifiedLinearAttention: B=8, N=3136 (56x56), C=512, 8 heads x 64
// Pipeline: cvt -> transpose weights -> GEMM(QKV,fused act) -> kvmat/ksum ->
//           conv_dw -> attn(z,out,+fmap) -> GEMM(proj,+bias) -> f32 out
// R8: conv_dw rewritten (was 70us = QKV-sized): lane-contiguous LDS reads
//     (16B/lane consecutive -> conflict-free), weights pre-transposed to
//     [tap][ch] (broadcast b128 reads, one global load), zero-pad at stage
//     time. GEMMs (R7 pipeline) and all other kernels byte-identical.
#define B_    8
#define N_    3136
#define C_    512
#define MTOT  25088   // B_*N_

typedef __attribute__((ext_vector_type(8))) short bf16x8;
typedef __attribute__((ext_vector_type(4))) float f32x4;

__device__ __forceinline__ float bf2f(short s){
  union { float f; uint32_t u; } cv; cv.u = ((uint32_t)(uint16_t)s) << 16; return cv.f;
}
__device__ __forceinline__ short f2bf(float f){
  union { float f; uint32_t u; } cv; cv.f = f;
  uint32_t r = cv.u + 0x7FFFu + ((cv.u >> 16) & 1u);
  return (short)(r >> 16);
}

typedef const __attribute__((address_space(1))) void* gas1_t;
typedef __attribute__((address_space(3))) void* las3_t;
__device__ __forceinline__ void gld16(const void* g, void* l){
  __builtin_amdgcn_global_load_lds((gas1_t)g, (las3_t)l, 16, 0, 0);
}

#define BARR  __builtin_amdgcn_s_barrier()
#define SCHB  __builtin_amdgcn_sched_barrier(0)
#define VMC0  asm volatile("s_waitcnt vmcnt(0)" ::: "memory")
#define VMC4  asm volatile("s_waitcnt vmcnt(4)" ::: "memory")
#define VMC6  asm volatile("s_waitcnt vmcnt(6)" ::: "memory")
#define LGKM0  asm volatile("s_waitcnt lgkmcnt(0)" ::: "memory")
#define LGKM2  asm volatile("s_waitcnt lgkmcnt(2)" ::: "memory")
#define LGKM10 asm volatile("s_waitcnt lgkmcnt(10)" ::: "memory")

// ---------------- convert x to bf16 (vectorized) ----------------
__global__ __launch_bounds__(256) void cvt_x(const float* __restrict__ x,
                                             short* __restrict__ xb, int n8){
  int i = blockIdx.x * 256 + threadIdx.x;
  if (i >= n8) return;
  const float4* p = (const float4*)x;
  float4 a = p[i*2], b = p[i*2+1];
  short o[8] = { f2bf(a.x), f2bf(a.y), f2bf(a.z), f2bf(a.w),
                 f2bf(b.x), f2bf(b.y), f2bf(b.z), f2bf(b.w) };
  *(bf16x8*)(xb + i*8) = *(bf16x8*)o;
}

// -------- transpose+convert weights: dst[j*512 + k] = bf16(src[k*J + j]) ----
__global__ __launch_bounds__(256) void tconv(const float* __restrict__ src,
                                             short* __restrict__ dst, int J){
  __shared__ float tile[32][33];
  int jb = blockIdx.x * 32, kb = blockIdx.y * 32;
  int tx = threadIdx.x & 31, ty = threadIdx.x >> 5;   // ty 0..7
#pragma unroll
  for (int r = 0; r < 32; r += 8)
    tile[ty + r][tx] = src[(size_t)(kb + ty + r) * J + jb + tx];
  __syncthreads();
#pragma unroll
  for (int r = 0; r < 32; r += 8)
    dst[(size_t)(jb + ty + r) * 512 + kb + tx] = f2bf(tile[tx][ty + r]);
}

// -------- conv weight transpose: wt[tap*64 + c] = w[c*25 + tap] ------------
__global__ __launch_bounds__(256) void conv_wT(const float* __restrict__ w,
                                               float* __restrict__ wt){
  int i = blockIdx.x * 256 + threadIdx.x;
  if (i < 1600) { int c = i / 25, tap = i - c * 25; wt[tap * 64 + c] = w[i]; }
}

// ---------------- 256x256 bf16 MFMA GEMM, K=512, Bt is (N x K) ----------------
// (R7 pipeline, unchanged — passed, 0 bank conflicts.)
template<int MODE, int NCT>
__global__ __launch_bounds__(512, 2)
void gemm_bf16(const short* __restrict__ A, const short* __restrict__ Bt,
               short* __restrict__ oQ, short* __restrict__ oK, short* __restrict__ oV,
               const float* __restrict__ posenc,
               float* __restrict__ oF, const float* __restrict__ bias)
{
  extern __shared__ __align__(16) char lds[];
  const int tid = threadIdx.x;
  const int wave = tid >> 6, lane = tid & 63;
  const int fr = lane & 15;

  // m204 bijective XCD swizzle
  constexpr int nwg = 98 * NCT;
  constexpr int q8 = nwg / 8, r8 = nwg % 8;
  const int orig = blockIdx.x;
  const int xcd = orig & 7, lid = orig >> 3;
  const int swz = (xcd < r8 ? xcd * (q8 + 1) : r8 * (q8 + 1) + (xcd - r8) * q8) + lid;
  const int rt = (swz / NCT) * 256;
  const int ct = (swz % NCT) * 256;

  const int wm = (wave >> 2) * 128;
  const int wn = (wave & 3) * 64;

  // ---- staging: per-lane source (pre-swizzled), wave-uniform LDS dest ----
  const int srow = lane >> 2;                                  // 0..15
  const int csrc = ((lane & 3) ^ ((lane >> 3) & 3)) << 3;      // shorts
  const short* srcA = A  + (size_t)(rt + wave * 32 + srow) * 512 + csrc;
  const short* srcB = Bt + (size_t)(ct + wave * 32 + srow) * 512 + csrc;
  char* dA = lds + wave * 2048;
  char* dB = lds + 32768 + wave * 2048;

  auto stage = [&](int sbb, int isB, int ks, int tt) {
    const short* s = (isB ? srcB : srcA) + tt * 64 + ks * 32;
    char* d = (isB ? dB : dA) + sbb + ks * 16384;
    gld16(s,        d);          // rows w*32 .. +15
    gld16(s + 8192, d + 1024);   // rows w*32+16 .. +31
  };

  // ---- fragment ds_read offsets (swizzled; (row>>1)&3 == (fr>>1)&3) ----
  const int cR   = (((lane >> 4) ^ ((fr >> 1) & 3)) << 4);
  const int offA = (wm + fr) * 64 + cR;
  const int offB = 32768 + (wn + fr) * 64 + cR;

#define READ_A(dst, bufb, ks) do { \
    const char* _p = lds + (bufb) + (ks) * 16384 + offA; \
    _Pragma("unroll") \
    for (int _i = 0; _i < 8; _i++) dst[_i] = *(const bf16x8*)(_p + _i * 1024); \
  } while (0)
#define READ_B2(dst, bufb, ks, j0) do { \
    const char* _p = lds + (bufb) + (ks) * 16384 + offB + (j0) * 1024; \
    dst[0] = *(const bf16x8*)(_p); \
    dst[1] = *(const bf16x8*)(_p + 1024); \
  } while (0)
#define MFMA16(afv, bv, jb) do { \
    __builtin_amdgcn_s_setprio(1); \
    _Pragma("unroll") \
    for (int _i = 0; _i < 8; _i++) { \
      acc[_i][jb]     = __builtin_amdgcn_mfma_f32_16x16x32_bf16(afv[_i], bv[0], acc[_i][jb],     0, 0, 0); \
      acc[_i][jb + 1] = __builtin_amdgcn_mfma_f32_16x16x32_bf16(afv[_i], bv[1], acc[_i][jb + 1], 0, 0, 0); \
    } \
    __builtin_amdgcn_s_setprio(0); \
  } while (0)

  f32x4 zv = {0.f, 0.f, 0.f, 0.f};
  f32x4 acc[8][4];
#pragma unroll
  for (int i = 0; i < 8; i++)
#pragma unroll
    for (int j = 0; j < 4; j++) acc[i][j] = zv;

  bf16x8 afU[8], afV[8], bX[2], bY[2];

  // prologue: tile 0 -> buf 0 (g0..g3), then pre-read P0-set
  stage(0, 0, 0, 0); stage(0, 1, 0, 0); stage(0, 0, 1, 0); stage(0, 1, 1, 0);
  VMC4; BARR; SCHB;               // g0,g1 landed (g2,g3 may fly)
  READ_A(afU, 0, 0);
  READ_B2(bX, 0, 0, 0);

  for (int t = 0; t < 7; ++t) {
    const int bufb = (t & 1) * 65536, sbb = bufb ^ 65536;
    // P0: MFMA(afU,bX ks0c0); read bY(ks0c1); stage g0'(A ks0, t+1)
    stage(sbb, 0, 0, t + 1);
    VMC6; BARR; SCHB;             // g1(t) landed
    READ_B2(bY, bufb, 0, 2);
    LGKM2; SCHB;                  // P0-set (afU,bX) complete
    MFMA16(afU, bX, 0);
    // P1: MFMA(afU,bY ks0c1); read afV,bX(ks1); stage g1'(B ks0)
    stage(sbb, 1, 0, t + 1);
    VMC4; BARR; SCHB;             // g2(t),g3(t) landed
    READ_A(afV, bufb, 1);
    READ_B2(bX, bufb, 1, 0);
    LGKM10; SCHB;                 // bY complete
    MFMA16(afU, bY, 2);
    // P2: MFMA(afV,bX ks1c0); read bY(ks1c1); stage g2'(A ks1)
    stage(sbb, 0, 1, t + 1);
    VMC6; BARR; SCHB;
    READ_B2(bY, bufb, 1, 2);
    LGKM2; SCHB;                  // afV,bX complete
    MFMA16(afV, bX, 0);
    // P3: MFMA(afV,bY ks1c1); read afU,bX(t+1 ks0); stage g3'(B ks1)
    stage(sbb, 1, 1, t + 1);
    VMC4; BARR; SCHB;             // g0',g1' landed
    READ_A(afU, sbb, 0);
    READ_B2(bX, sbb, 0, 0);
    LGKM10; SCHB;                 // bY complete
    MFMA16(afV, bY, 2);
  }
  {
    const int bufb = 65536;       // t = 7, no staging
    // P0
    VMC4; BARR; SCHB;
    READ_B2(bY, bufb, 0, 2);
    LGKM2; SCHB;
    MFMA16(afU, bX, 0);
    // P1
    VMC0; BARR; SCHB;             // g2,g3 of tile 7 landed
    READ_A(afV, bufb, 1);
    READ_B2(bX, bufb, 1, 0);
    LGKM10; SCHB;
    MFMA16(afU, bY, 2);
    // P2 (no barrier needed: data visibility established at P1)
    READ_B2(bY, bufb, 1, 2);
    LGKM2; SCHB;
    MFMA16(afV, bX, 0);
    // P3
    LGKM0; SCHB;
    MFMA16(afV, bY, 2);
  }

  BARR; SCHB;                     // all LDS reads done -> reusable

  // ---- epilogue: quarter-restage (64 rows) through LDS, coalesced stores ----
  const int rb = (lane >> 4) << 2;       // D layout: row=(lane>>4)*4+reg
  if (MODE == 0) {
    short* ov = (short*)lds;             // [64][260] bf16 (33280 B)
    const int sel = ct >> 9;             // 0:Q 1:K 2:V (uniform per block)
    const int cb  = ct - sel * 512;
    short* outp = sel == 0 ? oQ : (sel == 1 ? oK : oV);
#pragma unroll
    for (int q4 = 0; q4 < 4; ++q4) {
      if (q4) __syncthreads();           // protect prev quarter's reads
      if ((wave >> 2) == (q4 >> 1)) {    // waves owning rows q4*64..+63
        const int ib = (q4 & 1) * 4;
#pragma unroll
        for (int ii = 0; ii < 4; ii++)
#pragma unroll
          for (int j = 0; j < 4; j++)
#pragma unroll
            for (int r = 0; r < 4; r++)
              ov[(ii * 16 + rb + r) * 260 + wn + j * 16 + fr] = f2bf(acc[ib + ii][j][r]);
      }
      __syncthreads();
#pragma unroll
      for (int p = 0; p < 4; ++p) {
        int id = tid + 512 * p;
        int row = id >> 5, cc = (id & 31) * 8;
        bf16x8 vv = *(const bf16x8*)&ov[row * 260 + cc];
        int grow = rt + q4 * 64 + row;
        short o[8];
        if (sel == 0) {
#pragma unroll
          for (int e = 0; e < 8; e++) o[e] = f2bf(fmaxf(bf2f(vv[e]), 0.f));
        } else if (sel == 1) {
          int nr = grow % N_;
          const float* pp = posenc + (size_t)nr * 512 + cb + cc;
          f32x4 p0 = *(const f32x4*)pp;
          f32x4 p1 = *(const f32x4*)(pp + 4);
#pragma unroll
          for (int e = 0; e < 4; e++) {
            o[e]     = f2bf(fmaxf(bf2f(vv[e]) + p0[e], 0.f));
            o[e + 4] = f2bf(fmaxf(bf2f(vv[e + 4]) + p1[e], 0.f));
          }
        } else {
#pragma unroll
          for (int e = 0; e < 8; e++) o[e] = vv[e];
        }
        *(bf16x8*)(outp + (size_t)grow * 512 + cb + cc) = *(bf16x8*)o;
      }
    }
  } else {
    float* ovf = (float*)lds;            // [64][260] f32 (66560 B)
#pragma unroll
    for (int q4 = 0; q4 < 4; ++q4) {
      if (q4) __syncthreads();
      if ((wave >> 2) == (q4 >> 1)) {
        const int ib = (q4 & 1) * 4;
#pragma unroll
        for (int ii = 0; ii < 4; ii++)
#pragma unroll
          for (int j = 0; j < 4; j++)
#pragma unroll
            for (int r = 0; r < 4; r++)
              ovf[(ii * 16 + rb + r) * 260 + wn + j * 16 + fr] = acc[ib + ii][j][r];
      }
      __syncthreads();
#pragma unroll
      for (int p = 0; p < 4; ++p) {
        int id = tid + 512 * p;
        int row = id >> 5, cc = (id & 31) * 8;
        f32x4 v0 = *(const f32x4*)&ovf[row * 260 + cc];
        f32x4 v1 = *(const f32x4*)&ovf[row * 260 + cc + 4];
        v0 += *(const f32x4*)&bias[ct + cc];
        v1 += *(const f32x4*)&bias[ct + cc + 4];
        float* op = oF + (size_t)(rt + q4 * 64 + row) * 512 + ct + cc;
        *(f32x4*)op       = v0;
        *(f32x4*)(op + 4) = v1;
      }
    }
  }
#undef READ_A
#undef READ_B2
#undef MFMA16
}

// ------------- per-head KtV (64x64) + ksum, f32 partials, N split 7 ----------
__global__ __launch_bounds__(256)
void kvmat_part(const short* __restrict__ kb, const short* __restrict__ vb,
                float* __restrict__ pKV, float* __restrict__ pKS)
{
  __shared__ __align__(16) float lk[64][64];
  __shared__ __align__(16) float lv[64][64];
  const int chunk = blockIdx.x, bh = blockIdx.y;
  const int b = bh >> 3, h = bh & 7;
  const int t = threadIdx.x;
  const int tc = t >> 4, td = t & 15;
  const int kc = t & 63, kr = (t >> 6) * 16;
  float acc[4][4] = {};
  float ksacc = 0.f;

  for (int tile = 0; tile < 7; ++tile) {
    const int r0 = chunk * 448 + tile * 64;
    __syncthreads();
#pragma unroll
    for (int i = 0; i < 2; i++) {
      int idx = t + i * 256;
      int r = idx >> 3, c8 = (idx & 7) << 3;
      size_t g = (size_t)(b * N_ + r0 + r) * 512 + h * 64 + c8;
      bf16x8 kk = *(const bf16x8*)(kb + g);
      bf16x8 vv = *(const bf16x8*)(vb + g);
#pragma unroll
      for (int e = 0; e < 8; e++) { lk[r][c8 + e] = bf2f(kk[e]); lv[r][c8 + e] = bf2f(vv[e]); }
    }
    __syncthreads();
#pragma unroll 4
    for (int r = 0; r < 64; r++) {
      f32x4 k4 = *(const f32x4*)&lk[r][tc * 4];
      f32x4 v4 = *(const f32x4*)&lv[r][td * 4];
#pragma unroll
      for (int i = 0; i < 4; i++)
#pragma unroll
        for (int j = 0; j < 4; j++) acc[i][j] += k4[i] * v4[j];
    }
#pragma unroll 4
    for (int rr = 0; rr < 16; rr++) ksacc += lk[kr + rr][kc];
  }

  const int pbase = (bh * 7 + chunk) * 4096;
#pragma unroll
  for (int i = 0; i < 4; i++)
#pragma unroll
    for (int j = 0; j < 4; j++)
      pKV[pbase + (tc * 4 + i) * 64 + td * 4 + j] = acc[i][j];
  __syncthreads();
  float* red = &lk[0][0];
  red[t] = ksacc;
  __syncthreads();
  if (t < 64)
    pKS[(bh * 7 + chunk) * 64 + t] = red[t] + red[t + 64] + red[t + 128] + red[t + 192];
}

__global__ __launch_bounds__(256)
void kv_reduce(const float* __restrict__ pKV, const float* __restrict__ pKS,
               float* __restrict__ kvm, float* __restrict__ ksum)
{
  int bh = blockIdx.x, t = threadIdx.x;
#pragma unroll
  for (int i = 0; i < 16; i++) {
    int idx = t + i * 256;
    float s = 0.f;
#pragma unroll
    for (int c = 0; c < 7; c++) s += pKV[(bh * 7 + c) * 4096 + idx];
    kvm[bh * 4096 + idx] = s;
  }
  if (t < 64) {
    float s = 0.f;
#pragma unroll
    for (int c = 0; c < 7; c++) s += pKS[(bh * 7 + c) * 64 + t];
    ksum[bh * 64 + t] = s;
  }
}

// ------------- depthwise 5x5 conv on v, +bias -> pre (bf16) -------------
// R8: thread <-> (x = t>>3, c8 = t&7), two x-passes. Data ds_reads are
// 16B/lane consecutive (conflict-free); weights from wT[tap][64ch]
// (broadcast b128); zero-pad applied at stage time.
__global__ __launch_bounds__(256)
void conv_dw(const short* __restrict__ vb, const float* __restrict__ wT,
             const float* __restrict__ bias, short* __restrict__ pre)
{
  __shared__ __align__(16) short lsv[5 * 56 * 64];   // [row][x][64ch]
  __shared__ __align__(16) float lwT[25 * 64];       // [tap][64ch]
  const int y = blockIdx.x, bh = blockIdx.y;
  const int b = bh >> 3, h = bh & 7;
  const int t = threadIdx.x;
  for (int i = t; i < 1600; i += 256) lwT[i] = wT[i];
  for (int i = t; i < 2240; i += 256) {
    int row = i / 448, rem = i - row * 448;
    int xx = rem >> 3, c8i = rem & 7;
    int gy = y + row - 2;
    bf16x8 val = {0, 0, 0, 0, 0, 0, 0, 0};
    if ((unsigned)gy < 56u)
      val = *(const bf16x8*)(vb + (size_t)(b * N_ + gy * 56 + xx) * 512 + h * 64 + c8i * 8);
    *(bf16x8*)(lsv + i * 8) = val;     // linear: [(row*56+xx)*64 + c8*8]
  }
  __syncthreads();

  const int c8 = t & 7;                // 8-channel chunk within head
  const int x0 = t >> 3;               // 0..31; second pass covers x0+32
  float acc0[8], acc1[8];
  {
    f32x4 b0 = *(const f32x4*)&bias[c8 * 8];
    f32x4 b1 = *(const f32x4*)&bias[c8 * 8 + 4];
#pragma unroll
    for (int e = 0; e < 4; e++) { acc0[e] = b0[e]; acc0[e+4] = b1[e];
                                  acc1[e] = b0[e]; acc1[e+4] = b1[e]; }
  }
#pragma unroll
  for (int dy = 0; dy < 5; ++dy) {
#pragma unroll
    for (int dx = 0; dx < 5; ++dx) {
      float w8[8];
      {
        const float* wp = &lwT[(dy * 5 + dx) * 64 + c8 * 8];
        *(f32x4*)&w8[0] = *(const f32x4*)wp;
        *(f32x4*)&w8[4] = *(const f32x4*)(wp + 4);
      }
      const int base = dy * 56 * 64 + c8 * 8;
      int xxa = x0 + dx - 2;
      if ((unsigned)xxa < 56u) {
        bf16x8 v = *(const bf16x8*)(lsv + base + xxa * 64);
#pragma unroll
        for (int e = 0; e < 8; e++) acc0[e] += bf2f(v[e]) * w8[e];
      }
      int xxb = xxa + 32;
      if (xxb < 56) {
        bf16x8 v = *(const bf16x8*)(lsv + base + xxb * 64);
#pragma unroll
        for (int e = 0; e < 8; e++) acc1[e] += bf2f(v[e]) * w8[e];
      }
    }
  }
  size_t gbase = (size_t)(b * N_ + y * 56 + x0) * 512 + h * 64 + c8 * 8;
  short o[8];
#pragma unroll
  for (int e = 0; e < 8; e++) o[e] = f2bf(acc0[e]);
  *(bf16x8*)(pre + gbase) = *(bf16x8*)o;
  if (x0 + 32 < 56) {
#pragma unroll
    for (int e = 0; e < 8; e++) o[e] = f2bf(acc1[e]);
    *(bf16x8*)(pre + gbase + (size_t)32 * 512) = *(bf16x8*)o;
  }
}

// ------- attn: out = (q . kvmat) * z + fmap, in-place on pre (bf16) -------
__global__ __launch_bounds__(256)
void attn_comb(const short* __restrict__ qb, const float* __restrict__ kvm,
               const float* __restrict__ ksum, short* __restrict__ pre)
{
  __shared__ __align__(16) float lkv[4096];
  __shared__ __align__(16) float lq[4096];   // [c][p] transposed
  __shared__ float lks[64];
  const int pt = blockIdx.x, bh = blockIdx.y;
  const int b = bh >> 3, h = bh & 7;
  const int t = threadIdx.x;
  for (int i = t; i < 4096; i += 256) lkv[i] = kvm[bh * 4096 + i];
  if (t < 64) lks[t] = ksum[bh * 64 + t];
  {
    const int p = t & 63, cg = t >> 6;
    size_t g = (size_t)(b * N_ + pt * 64 + p) * 512 + h * 64 + cg * 16;
    bf16x8 qa = *(const bf16x8*)(qb + g);
    bf16x8 qc = *(const bf16x8*)(qb + g + 8);
#pragma unroll
    for (int e = 0; e < 8; e++) {
      lq[(cg * 16 + e) * 64 + p]     = bf2f(qa[e]);
      lq[(cg * 16 + 8 + e) * 64 + p] = bf2f(qc[e]);
    }
  }
  __syncthreads();
  const int p = t & 63, d0 = (t >> 6) * 16;
  float acc[16] = {};
  float zd = 0.f;
#pragma unroll 4
  for (int c = 0; c < 64; c++) {
    float qv = lq[c * 64 + p];
    zd += qv * lks[c];
    const f32x4* row = (const f32x4*)&lkv[c * 64 + d0];
    f32x4 m0 = row[0], m1 = row[1], m2 = row[2], m3 = row[3];
#pragma unroll
    for (int e = 0; e < 4; e++) {
      acc[e]      += qv * m0[e];
      acc[4 + e]  += qv * m1[e];
      acc[8 + e]  += qv * m2[e];
      acc[12 + e] += qv * m3[e];
    }
  }
  float z = 1.f / (zd + 1e-6f);
  size_t base = (size_t)(b * N_ + pt * 64 + p) * 512 + h * 64 + d0;
  bf16x8 f0 = *(const bf16x8*)(pre + base);
  bf16x8 f1 = *(const bf16x8*)(pre + base + 8);
  short o[16];
#pragma unroll
  for (int e = 0; e < 8; e++) {
    o[e]     = f2bf(acc[e] * z + bf2f(f0[e]));
    o[e + 8] = f2bf(acc[e + 8] * z + bf2f(f1[e]));
  }
  *(bf16x8*)(pre + base)     = *(bf16x8*)&o[0];
  *(bf16x8*)(pre + base + 8) = *(bf16x8*)&o[8];
}

// ---------------------------------------------------------------------------
extern "C" void kernel_launch(void* const* d_in, const int* in_sizes, int n_in,
                              void* d_out, int out_size, void* d_ws, size_t ws_size,
                              hipStream_t stream)
{
  const float* x     = (const float*)d_in[0];
  const float* Wq    = (const float*)d_in[3];
  const float* Wkv   = (const float*)d_in[4];
  const float* pos   = (const float*)d_in[5];
  const float* dwcw  = (const float*)d_in[6];
  const float* dwcb  = (const float*)d_in[7];
  const float* Wproj = (const float*)d_in[8];
  const float* bproj = (const float*)d_in[9];
  float* out = (float*)d_out;

  char* ws = (char*)d_ws;
  size_t off = 0;
  auto alloc = [&](size_t bytes) -> void* {
    void* p = ws + off;
    off = (off + bytes + 255) & ~(size_t)255;
    return p;
  };
  short* xb     = (short*)alloc((size_t)MTOT * 512 * 2);
  short* wqkvT  = (short*)alloc((size_t)1536 * 512 * 2);
  short* wprojT = (short*)alloc((size_t)512 * 512 * 2);
  float* wTc    = (float*)alloc((size_t)25 * 64 * 4);
  short* qb     = (short*)alloc((size_t)MTOT * 512 * 2);
  short* kbuf   = (short*)alloc((size_t)MTOT * 512 * 2);
  short* vbuf   = (short*)alloc((size_t)MTOT * 512 * 2);
  float* pKV    = (float*)alloc((size_t)64 * 7 * 4096 * 4);
  float* pKS    = (float*)alloc((size_t)64 * 7 * 64 * 4);
  float* kvm    = (float*)alloc((size_t)64 * 4096 * 4);
  float* ksumB  = (float*)alloc((size_t)64 * 64 * 4);
  short* pre    = (short*)alloc((size_t)MTOT * 512 * 2);
  if (ws_size < off) return;   // workspace too small: leave output zeroed (visible failure)

  // allow 128KB dynamic LDS for the GEMMs (host-side attr, graph-safe)
  {
    auto k0 = gemm_bf16<0, 6>;
    auto k1 = gemm_bf16<1, 2>;
    hipFuncSetAttribute(reinterpret_cast<const void*>(k0),
                        hipFuncAttributeMaxDynamicSharedMemorySize, 131072);
    hipFuncSetAttribute(reinterpret_cast<const void*>(k1),
                        hipFuncAttributeMaxDynamicSharedMemorySize, 131072);
  }

  // 1. convert x; transpose conv weights
  cvt_x<<<dim3((MTOT * 512 / 8 + 255) / 256), dim3(256), 0, stream>>>(x, xb, MTOT * 512 / 8);
  conv_wT<<<dim3(7), dim3(256), 0, stream>>>(dwcw, wTc);
  // 2. transpose weights -> (N x K) bf16
  tconv<<<dim3(16, 16), dim3(256), 0, stream>>>(Wq,    wqkvT,              512);
  tconv<<<dim3(32, 16), dim3(256), 0, stream>>>(Wkv,   wqkvT + 512 * 512, 1024);
  tconv<<<dim3(16, 16), dim3(256), 0, stream>>>(Wproj, wprojT,             512);
  // 3. QKV GEMM, fused activations (256x256 tiles, 98*6=588 blocks)
  gemm_bf16<0, 6><<<dim3(588), dim3(512), 131072, stream>>>(xb, wqkvT, qb, kbuf, vbuf, pos,
                                                            nullptr, nullptr);
  // 4. per-head KtV + ksum
  kvmat_part<<<dim3(7, 64), dim3(256), 0, stream>>>(kbuf, vbuf, pKV, pKS);
  kv_reduce<<<dim3(64), dim3(256), 0, stream>>>(pKV, pKS, kvm, ksumB);
  // 5. depthwise conv -> pre
  conv_dw<<<dim3(56, 64), dim3(256), 0, stream>>>(vbuf, wTc, dwcb, pre);
  // 6. attention output + fmap (in-place on pre)
  attn_comb<<<dim3(49, 64), dim3(256), 0, stream>>>(qb, kvm, ksumB, pre);
  // 7. projection GEMM -> f32 out (256x256 tiles, 98*2=196 blocks)
  gemm_bf16<1, 2><<<dim3(196), dim3(512), 131072, stream>>>(pre, wprojT, nullptr, nullptr, nullptr,
                                                            nullptr, out, bproj);
}

// Round 9
// 220.543 us; speedup vs baseline: 1.2641x; 1.0613x over previous
//
#include <hip/hip_runtime.h>
#include <stdint.h>

// SimplifiedLinearAttention: B=8, N=3136 (56x56), C=512, 8 heads x 64
// Pipeline: cvt -> transpose weights -> GEMM(QKV,fused act) -> kvmat/ksum ->
//           conv_dw -> attn(z,out,+fmap) -> GEMM(proj,+bias) -> f32 out
// R9: attn_comb -> attn_mfma: per-wave 64x64x64 MFMA micro-GEMM, fragments
//     loaded directly from global (full-cacheline tiling, no input LDS),
//     kvmat consumed as bf16 [d][c] (produced by kv_reduce), f32 z, LDS
//     restage epilogue with vectorized bf16 RMW on pre. All other kernels
//     byte-identical to R8 (passing).
#define B_    8
#define N_    3136
#define C_    512
#define MTOT  25088   // B_*N_

typedef __attribute__((ext_vector_type(8))) short bf16x8;
typedef __attribute__((ext_vector_type(4))) float f32x4;

__device__ __forceinline__ float bf2f(short s){
  union { float f; uint32_t u; } cv; cv.u = ((uint32_t)(uint16_t)s) << 16; return cv.f;
}
__device__ __forceinline__ short f2bf(float f){
  union { float f; uint32_t u; } cv; cv.f = f;
  uint32_t r = cv.u + 0x7FFFu + ((cv.u >> 16) & 1u);
  return (short)(r >> 16);
}

typedef const __attribute__((address_space(1))) void* gas1_t;
typedef __attribute__((address_space(3))) void* las3_t;
__device__ __forceinline__ void gld16(const void* g, void* l){
  __builtin_amdgcn_global_load_lds((gas1_t)g, (las3_t)l, 16, 0, 0);
}

#define BARR  __builtin_amdgcn_s_barrier()
#define SCHB  __builtin_amdgcn_sched_barrier(0)
#define VMC0  asm volatile("s_waitcnt vmcnt(0)" ::: "memory")
#define VMC4  asm volatile("s_waitcnt vmcnt(4)" ::: "memory")
#define VMC6  asm volatile("s_waitcnt vmcnt(6)" ::: "memory")
#define LGKM0  asm volatile("s_waitcnt lgkmcnt(0)" ::: "memory")
#define LGKM2  asm volatile("s_waitcnt lgkmcnt(2)" ::: "memory")
#define LGKM10 asm volatile("s_waitcnt lgkmcnt(10)" ::: "memory")

// ---------------- convert x to bf16 (vectorized) ----------------
__global__ __launch_bounds__(256) void cvt_x(const float* __restrict__ x,
                                             short* __restrict__ xb, int n8){
  int i = blockIdx.x * 256 + threadIdx.x;
  if (i >= n8) return;
  const float4* p = (const float4*)x;
  float4 a = p[i*2], b = p[i*2+1];
  short o[8] = { f2bf(a.x), f2bf(a.y), f2bf(a.z), f2bf(a.w),
                 f2bf(b.x), f2bf(b.y), f2bf(b.z), f2bf(b.w) };
  *(bf16x8*)(xb + i*8) = *(bf16x8*)o;
}

// -------- transpose+convert weights: dst[j*512 + k] = bf16(src[k*J + j]) ----
__global__ __launch_bounds__(256) void tconv(const float* __restrict__ src,
                                             short* __restrict__ dst, int J){
  __shared__ float tile[32][33];
  int jb = blockIdx.x * 32, kb = blockIdx.y * 32;
  int tx = threadIdx.x & 31, ty = threadIdx.x >> 5;   // ty 0..7
#pragma unroll
  for (int r = 0; r < 32; r += 8)
    tile[ty + r][tx] = src[(size_t)(kb + ty + r) * J + jb + tx];
  __syncthreads();
#pragma unroll
  for (int r = 0; r < 32; r += 8)
    dst[(size_t)(jb + ty + r) * 512 + kb + tx] = f2bf(tile[tx][ty + r]);
}

// -------- conv weight transpose: wt[tap*64 + c] = w[c*25 + tap] ------------
__global__ __launch_bounds__(256) void conv_wT(const float* __restrict__ w,
                                               float* __restrict__ wt){
  int i = blockIdx.x * 256 + threadIdx.x;
  if (i < 1600) { int c = i / 25, tap = i - c * 25; wt[tap * 64 + c] = w[i]; }
}

// ---------------- 256x256 bf16 MFMA GEMM, K=512, Bt is (N x K) ----------------
// (R7 pipeline, unchanged — passed, 0 bank conflicts.)
template<int MODE, int NCT>
__global__ __launch_bounds__(512, 2)
void gemm_bf16(const short* __restrict__ A, const short* __restrict__ Bt,
               short* __restrict__ oQ, short* __restrict__ oK, short* __restrict__ oV,
               const float* __restrict__ posenc,
               float* __restrict__ oF, const float* __restrict__ bias)
{
  extern __shared__ __align__(16) char lds[];
  const int tid = threadIdx.x;
  const int wave = tid >> 6, lane = tid & 63;
  const int fr = lane & 15;

  // m204 bijective XCD swizzle
  constexpr int nwg = 98 * NCT;
  constexpr int q8 = nwg / 8, r8 = nwg % 8;
  const int orig = blockIdx.x;
  const int xcd = orig & 7, lid = orig >> 3;
  const int swz = (xcd < r8 ? xcd * (q8 + 1) : r8 * (q8 + 1) + (xcd - r8) * q8) + lid;
  const int rt = (swz / NCT) * 256;
  const int ct = (swz % NCT) * 256;

  const int wm = (wave >> 2) * 128;
  const int wn = (wave & 3) * 64;

  // ---- staging: per-lane source (pre-swizzled), wave-uniform LDS dest ----
  const int srow = lane >> 2;                                  // 0..15
  const int csrc = ((lane & 3) ^ ((lane >> 3) & 3)) << 3;      // shorts
  const short* srcA = A  + (size_t)(rt + wave * 32 + srow) * 512 + csrc;
  const short* srcB = Bt + (size_t)(ct + wave * 32 + srow) * 512 + csrc;
  char* dA = lds + wave * 2048;
  char* dB = lds + 32768 + wave * 2048;

  auto stage = [&](int sbb, int isB, int ks, int tt) {
    const short* s = (isB ? srcB : srcA) + tt * 64 + ks * 32;
    char* d = (isB ? dB : dA) + sbb + ks * 16384;
    gld16(s,        d);          // rows w*32 .. +15
    gld16(s + 8192, d + 1024);   // rows w*32+16 .. +31
  };

  // ---- fragment ds_read offsets (swizzled; (row>>1)&3 == (fr>>1)&3) ----
  const int cR   = (((lane >> 4) ^ ((fr >> 1) & 3)) << 4);
  const int offA = (wm + fr) * 64 + cR;
  const int offB = 32768 + (wn + fr) * 64 + cR;

#define READ_A(dst, bufb, ks) do { \
    const char* _p = lds + (bufb) + (ks) * 16384 + offA; \
    _Pragma("unroll") \
    for (int _i = 0; _i < 8; _i++) dst[_i] = *(const bf16x8*)(_p + _i * 1024); \
  } while (0)
#define READ_B2(dst, bufb, ks, j0) do { \
    const char* _p = lds + (bufb) + (ks) * 16384 + offB + (j0) * 1024; \
    dst[0] = *(const bf16x8*)(_p); \
    dst[1] = *(const bf16x8*)(_p + 1024); \
  } while (0)
#define MFMA16(afv, bv, jb) do { \
    __builtin_amdgcn_s_setprio(1); \
    _Pragma("unroll") \
    for (int _i = 0; _i < 8; _i++) { \
      acc[_i][jb]     = __builtin_amdgcn_mfma_f32_16x16x32_bf16(afv[_i], bv[0], acc[_i][jb],     0, 0, 0); \
      acc[_i][jb + 1] = __builtin_amdgcn_mfma_f32_16x16x32_bf16(afv[_i], bv[1], acc[_i][jb + 1], 0, 0, 0); \
    } \
    __builtin_amdgcn_s_setprio(0); \
  } while (0)

  f32x4 zv = {0.f, 0.f, 0.f, 0.f};
  f32x4 acc[8][4];
#pragma unroll
  for (int i = 0; i < 8; i++)
#pragma unroll
    for (int j = 0; j < 4; j++) acc[i][j] = zv;

  bf16x8 afU[8], afV[8], bX[2], bY[2];

  // prologue: tile 0 -> buf 0 (g0..g3), then pre-read P0-set
  stage(0, 0, 0, 0); stage(0, 1, 0, 0); stage(0, 0, 1, 0); stage(0, 1, 1, 0);
  VMC4; BARR; SCHB;               // g0,g1 landed (g2,g3 may fly)
  READ_A(afU, 0, 0);
  READ_B2(bX, 0, 0, 0);

  for (int t = 0; t < 7; ++t) {
    const int bufb = (t & 1) * 65536, sbb = bufb ^ 65536;
    // P0: MFMA(afU,bX ks0c0); read bY(ks0c1); stage g0'(A ks0, t+1)
    stage(sbb, 0, 0, t + 1);
    VMC6; BARR; SCHB;             // g1(t) landed
    READ_B2(bY, bufb, 0, 2);
    LGKM2; SCHB;                  // P0-set (afU,bX) complete
    MFMA16(afU, bX, 0);
    // P1: MFMA(afU,bY ks0c1); read afV,bX(ks1); stage g1'(B ks0)
    stage(sbb, 1, 0, t + 1);
    VMC4; BARR; SCHB;             // g2(t),g3(t) landed
    READ_A(afV, bufb, 1);
    READ_B2(bX, bufb, 1, 0);
    LGKM10; SCHB;                 // bY complete
    MFMA16(afU, bY, 2);
    // P2: MFMA(afV,bX ks1c0); read bY(ks1c1); stage g2'(A ks1)
    stage(sbb, 0, 1, t + 1);
    VMC6; BARR; SCHB;
    READ_B2(bY, bufb, 1, 2);
    LGKM2; SCHB;                  // afV,bX complete
    MFMA16(afV, bX, 0);
    // P3: MFMA(afV,bY ks1c1); read afU,bX(t+1 ks0); stage g3'(B ks1)
    stage(sbb, 1, 1, t + 1);
    VMC4; BARR; SCHB;             // g0',g1' landed
    READ_A(afU, sbb, 0);
    READ_B2(bX, sbb, 0, 0);
    LGKM10; SCHB;                 // bY complete
    MFMA16(afV, bY, 2);
  }
  {
    const int bufb = 65536;       // t = 7, no staging
    // P0
    VMC4; BARR; SCHB;
    READ_B2(bY, bufb, 0, 2);
    LGKM2; SCHB;
    MFMA16(afU, bX, 0);
    // P1
    VMC0; BARR; SCHB;             // g2,g3 of tile 7 landed
    READ_A(afV, bufb, 1);
    READ_B2(bX, bufb, 1, 0);
    LGKM10; SCHB;
    MFMA16(afU, bY, 2);
    // P2 (no barrier needed: data visibility established at P1)
    READ_B2(bY, bufb, 1, 2);
    LGKM2; SCHB;
    MFMA16(afV, bX, 0);
    // P3
    LGKM0; SCHB;
    MFMA16(afV, bY, 2);
  }

  BARR; SCHB;                     // all LDS reads done -> reusable

  // ---- epilogue: quarter-restage (64 rows) through LDS, coalesced stores ----
  const int rb = (lane >> 4) << 2;       // D layout: row=(lane>>4)*4+reg
  if (MODE == 0) {
    short* ov = (short*)lds;             // [64][260] bf16 (33280 B)
    const int sel = ct >> 9;             // 0:Q 1:K 2:V (uniform per block)
    const int cb  = ct - sel * 512;
    short* outp = sel == 0 ? oQ : (sel == 1 ? oK : oV);
#pragma unroll
    for (int q4 = 0; q4 < 4; ++q4) {
      if (q4) __syncthreads();           // protect prev quarter's reads
      if ((wave >> 2) == (q4 >> 1)) {    // waves owning rows q4*64..+63
        const int ib = (q4 & 1) * 4;
#pragma unroll
        for (int ii = 0; ii < 4; ii++)
#pragma unroll
          for (int j = 0; j < 4; j++)
#pragma unroll
            for (int r = 0; r < 4; r++)
              ov[(ii * 16 + rb + r) * 260 + wn + j * 16 + fr] = f2bf(acc[ib + ii][j][r]);
      }
      __syncthreads();
#pragma unroll
      for (int p = 0; p < 4; ++p) {
        int id = tid + 512 * p;
        int row = id >> 5, cc = (id & 31) * 8;
        bf16x8 vv = *(const bf16x8*)&ov[row * 260 + cc];
        int grow = rt + q4 * 64 + row;
        short o[8];
        if (sel == 0) {
#pragma unroll
          for (int e = 0; e < 8; e++) o[e] = f2bf(fmaxf(bf2f(vv[e]), 0.f));
        } else if (sel == 1) {
          int nr = grow % N_;
          const float* pp = posenc + (size_t)nr * 512 + cb + cc;
          f32x4 p0 = *(const f32x4*)pp;
          f32x4 p1 = *(const f32x4*)(pp + 4);
#pragma unroll
          for (int e = 0; e < 4; e++) {
            o[e]     = f2bf(fmaxf(bf2f(vv[e]) + p0[e], 0.f));
            o[e + 4] = f2bf(fmaxf(bf2f(vv[e + 4]) + p1[e], 0.f));
          }
        } else {
#pragma unroll
          for (int e = 0; e < 8; e++) o[e] = vv[e];
        }
        *(bf16x8*)(outp + (size_t)grow * 512 + cb + cc) = *(bf16x8*)o;
      }
    }
  } else {
    float* ovf = (float*)lds;            // [64][260] f32 (66560 B)
#pragma unroll
    for (int q4 = 0; q4 < 4; ++q4) {
      if (q4) __syncthreads();
      if ((wave >> 2) == (q4 >> 1)) {
        const int ib = (q4 & 1) * 4;
#pragma unroll
        for (int ii = 0; ii < 4; ii++)
#pragma unroll
          for (int j = 0; j < 4; j++)
#pragma unroll
            for (int r = 0; r < 4; r++)
              ovf[(ii * 16 + rb + r) * 260 + wn + j * 16 + fr] = acc[ib + ii][j][r];
      }
      __syncthreads();
#pragma unroll
      for (int p = 0; p < 4; ++p) {
        int id = tid + 512 * p;
        int row = id >> 5, cc = (id & 31) * 8;
        f32x4 v0 = *(const f32x4*)&ovf[row * 260 + cc];
        f32x4 v1 = *(const f32x4*)&ovf[row * 260 + cc + 4];
        v0 += *(const f32x4*)&bias[ct + cc];
        v1 += *(const f32x4*)&bias[ct + cc + 4];
        float* op = oF + (size_t)(rt + q4 * 64 + row) * 512 + ct + cc;
        *(f32x4*)op       = v0;
        *(f32x4*)(op + 4) = v1;
      }
    }
  }
#undef READ_A
#undef READ_B2
#undef MFMA16
}

// ------------- per-head KtV (64x64) + ksum, f32 partials, N split 7 ----------
__global__ __launch_bounds__(256)
void kvmat_part(const short* __restrict__ kb, const short* __restrict__ vb,
                float* __restrict__ pKV, float* __restrict__ pKS)
{
  __shared__ __align__(16) float lk[64][64];
  __shared__ __align__(16) float lv[64][64];
  const int chunk = blockIdx.x, bh = blockIdx.y;
  const int b = bh >> 3, h = bh & 7;
  const int t = threadIdx.x;
  const int tc = t >> 4, td = t & 15;
  const int kc = t & 63, kr = (t >> 6) * 16;
  float acc[4][4] = {};
  float ksacc = 0.f;

  for (int tile = 0; tile < 7; ++tile) {
    const int r0 = chunk * 448 + tile * 64;
    __syncthreads();
#pragma unroll
    for (int i = 0; i < 2; i++) {
      int idx = t + i * 256;
      int r = idx >> 3, c8 = (idx & 7) << 3;
      size_t g = (size_t)(b * N_ + r0 + r) * 512 + h * 64 + c8;
      bf16x8 kk = *(const bf16x8*)(kb + g);
      bf16x8 vv = *(const bf16x8*)(vb + g);
#pragma unroll
      for (int e = 0; e < 8; e++) { lk[r][c8 + e] = bf2f(kk[e]); lv[r][c8 + e] = bf2f(vv[e]); }
    }
    __syncthreads();
#pragma unroll 4
    for (int r = 0; r < 64; r++) {
      f32x4 k4 = *(const f32x4*)&lk[r][tc * 4];
      f32x4 v4 = *(const f32x4*)&lv[r][td * 4];
#pragma unroll
      for (int i = 0; i < 4; i++)
#pragma unroll
        for (int j = 0; j < 4; j++) acc[i][j] += k4[i] * v4[j];
    }
#pragma unroll 4
    for (int rr = 0; rr < 16; rr++) ksacc += lk[kr + rr][kc];
  }

  const int pbase = (bh * 7 + chunk) * 4096;
#pragma unroll
  for (int i = 0; i < 4; i++)
#pragma unroll
    for (int j = 0; j < 4; j++)
      pKV[pbase + (tc * 4 + i) * 64 + td * 4 + j] = acc[i][j];
  __syncthreads();
  float* red = &lk[0][0];
  red[t] = ksacc;
  __syncthreads();
  if (t < 64)
    pKS[(bh * 7 + chunk) * 64 + t] = red[t] + red[t + 64] + red[t + 128] + red[t + 192];
}

// ------- reduce partials; emit kvT bf16 [d][c] (B-operand layout) + ksum ----
__global__ __launch_bounds__(256)
void kv_reduce(const float* __restrict__ pKV, const float* __restrict__ pKS,
               short* __restrict__ kvT, float* __restrict__ ksum)
{
  int bh = blockIdx.x, t = threadIdx.x;
#pragma unroll
  for (int i = 0; i < 16; i++) {
    int idx = t + i * 256;
    float s = 0.f;
#pragma unroll
    for (int c = 0; c < 7; c++) s += pKV[(bh * 7 + c) * 4096 + idx];
    int cc = idx >> 6, d = idx & 63;           // pKV layout [c][d]
    kvT[bh * 4096 + d * 64 + cc] = f2bf(s);    // transposed bf16
  }
  if (t < 64) {
    float s = 0.f;
#pragma unroll
    for (int c = 0; c < 7; c++) s += pKS[(bh * 7 + c) * 64 + t];
    ksum[bh * 64 + t] = s;
  }
}

// ------------- depthwise 5x5 conv on v, +bias -> pre (bf16) -------------
__global__ __launch_bounds__(256)
void conv_dw(const short* __restrict__ vb, const float* __restrict__ wT,
             const float* __restrict__ bias, short* __restrict__ pre)
{
  __shared__ __align__(16) short lsv[5 * 56 * 64];   // [row][x][64ch]
  __shared__ __align__(16) float lwT[25 * 64];       // [tap][64ch]
  const int y = blockIdx.x, bh = blockIdx.y;
  const int b = bh >> 3, h = bh & 7;
  const int t = threadIdx.x;
  for (int i = t; i < 1600; i += 256) lwT[i] = wT[i];
  for (int i = t; i < 2240; i += 256) {
    int row = i / 448, rem = i - row * 448;
    int xx = rem >> 3, c8i = rem & 7;
    int gy = y + row - 2;
    bf16x8 val = {0, 0, 0, 0, 0, 0, 0, 0};
    if ((unsigned)gy < 56u)
      val = *(const bf16x8*)(vb + (size_t)(b * N_ + gy * 56 + xx) * 512 + h * 64 + c8i * 8);
    *(bf16x8*)(lsv + i * 8) = val;     // linear: [(row*56+xx)*64 + c8*8]
  }
  __syncthreads();

  const int c8 = t & 7;                // 8-channel chunk within head
  const int x0 = t >> 3;               // 0..31; second pass covers x0+32
  float acc0[8], acc1[8];
  {
    f32x4 b0 = *(const f32x4*)&bias[c8 * 8];
    f32x4 b1 = *(const f32x4*)&bias[c8 * 8 + 4];
#pragma unroll
    for (int e = 0; e < 4; e++) { acc0[e] = b0[e]; acc0[e+4] = b1[e];
                                  acc1[e] = b0[e]; acc1[e+4] = b1[e]; }
  }
#pragma unroll
  for (int dy = 0; dy < 5; ++dy) {
#pragma unroll
    for (int dx = 0; dx < 5; ++dx) {
      float w8[8];
      {
        const float* wp = &lwT[(dy * 5 + dx) * 64 + c8 * 8];
        *(f32x4*)&w8[0] = *(const f32x4*)wp;
        *(f32x4*)&w8[4] = *(const f32x4*)(wp + 4);
      }
      const int base = dy * 56 * 64 + c8 * 8;
      int xxa = x0 + dx - 2;
      if ((unsigned)xxa < 56u) {
        bf16x8 v = *(const bf16x8*)(lsv + base + xxa * 64);
#pragma unroll
        for (int e = 0; e < 8; e++) acc0[e] += bf2f(v[e]) * w8[e];
      }
      int xxb = xxa + 32;
      if (xxb < 56) {
        bf16x8 v = *(const bf16x8*)(lsv + base + xxb * 64);
#pragma unroll
        for (int e = 0; e < 8; e++) acc1[e] += bf2f(v[e]) * w8[e];
      }
    }
  }
  size_t gbase = (size_t)(b * N_ + y * 56 + x0) * 512 + h * 64 + c8 * 8;
  short o[8];
#pragma unroll
  for (int e = 0; e < 8; e++) o[e] = f2bf(acc0[e]);
  *(bf16x8*)(pre + gbase) = *(bf16x8*)o;
  if (x0 + 32 < 56) {
#pragma unroll
    for (int e = 0; e < 8; e++) o[e] = f2bf(acc1[e]);
    *(bf16x8*)(pre + gbase + (size_t)32 * 512) = *(bf16x8*)o;
  }
}

// ---- attn: per-wave MFMA micro-GEMM out = (q @ kvT^T)*z + pre (RMW) ----
// 1 wave per block: 64 pixels x 64 d, K=64 (2 k-slices of 32).
// A frags (q) and B frags (kvT) loaded DIRECTLY from global: each frag set
// tiles full 128B cache lines (lanes 0..63 cover rows fr+16i x 64B per ks;
// both ks cover the line). z computed per-lane f32. Epilogue restaged via
// [64][68] f32 LDS (16B-aligned rows) then vectorized bf16x8 RMW on pre.
__global__ __launch_bounds__(64)
void attn_mfma(const short* __restrict__ qb, const short* __restrict__ kvT,
               const float* __restrict__ ksum, short* __restrict__ pre)
{
  __shared__ __align__(16) float ov[64 * 68];
  __shared__ float lks[64];
  const int pt = blockIdx.x, bh = blockIdx.y;
  const int b = bh >> 3, h = bh & 7;
  const int l = threadIdx.x;
  const int fr = l & 15, kg = l >> 4;
  const int n0 = pt * 64;

  lks[l] = ksum[bh * 64 + l];

  const short* qbase = qb + (size_t)(b * N_ + n0) * 512 + h * 64;
  const short* kvb   = kvT + bh * 4096;
  bf16x8 af[4][2], bm[4][2];
#pragma unroll
  for (int i = 0; i < 4; i++)
#pragma unroll
    for (int s = 0; s < 2; s++) {
      af[i][s] = *(const bf16x8*)(qbase + (size_t)(fr + i * 16) * 512 + s * 32 + kg * 8);
      bm[i][s] = *(const bf16x8*)(kvb + (fr + i * 16) * 64 + s * 32 + kg * 8);
    }

  f32x4 zv4 = {0.f, 0.f, 0.f, 0.f};
  f32x4 acc[4][4];
#pragma unroll
  for (int i = 0; i < 4; i++)
#pragma unroll
    for (int j = 0; j < 4; j++) acc[i][j] = zv4;
#pragma unroll
  for (int s = 0; s < 2; s++)
#pragma unroll
    for (int i = 0; i < 4; i++)
#pragma unroll
      for (int j = 0; j < 4; j++)
        acc[i][j] = __builtin_amdgcn_mfma_f32_16x16x32_bf16(af[i][s], bm[j][s], acc[i][j], 0, 0, 0);

  // z for own row l (f32, q re-read — same cache lines as frags)
  const short* qrow = qb + (size_t)(b * N_ + n0 + l) * 512 + h * 64;
  float zd = 0.f;
#pragma unroll
  for (int g = 0; g < 8; g++) {
    bf16x8 qv = *(const bf16x8*)(qrow + g * 8);
#pragma unroll
    for (int e = 0; e < 8; e++) zd += bf2f(qv[e]) * lks[g * 8 + e];
  }
  const float z = 1.f / (zd + 1e-6f);

  // restage acc: row = i*16 + kg*4 + r, col = j*16 + fr
  const int rb = kg << 2;
#pragma unroll
  for (int i = 0; i < 4; i++)
#pragma unroll
    for (int j = 0; j < 4; j++)
#pragma unroll
      for (int r = 0; r < 4; r++)
        ov[(i * 16 + rb + r) * 68 + j * 16 + fr] = acc[i][j][r];
  __syncthreads();

  // vectorized RMW: lane l owns pixel n0+l
  size_t gb = (size_t)(b * N_ + n0 + l) * 512 + h * 64;
  const float* ovr = &ov[l * 68];
#pragma unroll
  for (int g = 0; g < 8; g++) {
    bf16x8 pv = *(const bf16x8*)(pre + gb + g * 8);
    f32x4 a0 = *(const f32x4*)(ovr + g * 8);
    f32x4 a1 = *(const f32x4*)(ovr + g * 8 + 4);
    short o[8];
#pragma unroll
    for (int e = 0; e < 4; e++) {
      o[e]     = f2bf(a0[e] * z + bf2f(pv[e]));
      o[e + 4] = f2bf(a1[e] * z + bf2f(pv[e + 4]));
    }
    *(bf16x8*)(pre + gb + g * 8) = *(bf16x8*)o;
  }
}

// ---------------------------------------------------------------------------
extern "C" void kernel_launch(void* const* d_in, const int* in_sizes, int n_in,
                              void* d_out, int out_size, void* d_ws, size_t ws_size,
                              hipStream_t stream)
{
  const float* x     = (const float*)d_in[0];
  const float* Wq    = (const float*)d_in[3];
  const float* Wkv   = (const float*)d_in[4];
  const float* pos   = (const float*)d_in[5];
  const float* dwcw  = (const float*)d_in[6];
  const float* dwcb  = (const float*)d_in[7];
  const float* Wproj = (const float*)d_in[8];
  const float* bproj = (const float*)d_in[9];
  float* out = (float*)d_out;

  char* ws = (char*)d_ws;
  size_t off = 0;
  auto alloc = [&](size_t bytes) -> void* {
    void* p = ws + off;
    off = (off + bytes + 255) & ~(size_t)255;
    return p;
  };
  short* xb     = (short*)alloc((size_t)MTOT * 512 * 2);
  short* wqkvT  = (short*)alloc((size_t)1536 * 512 * 2);
  short* wprojT = (short*)alloc((size_t)512 * 512 * 2);
  float* wTc    = (float*)alloc((size_t)25 * 64 * 4);
  short* qb     = (short*)alloc((size_t)MTOT * 512 * 2);
  short* kbuf   = (short*)alloc((size_t)MTOT * 512 * 2);
  short* vbuf   = (short*)alloc((size_t)MTOT * 512 * 2);
  float* pKV    = (float*)alloc((size_t)64 * 7 * 4096 * 4);
  float* pKS    = (float*)alloc((size_t)64 * 7 * 64 * 4);
  short* kvT    = (short*)alloc((size_t)64 * 4096 * 2);
  float* ksumB  = (float*)alloc((size_t)64 * 64 * 4);
  short* pre    = (short*)alloc((size_t)MTOT * 512 * 2);
  if (ws_size < off) return;   // workspace too small: leave output zeroed (visible failure)

  // allow 128KB dynamic LDS for the GEMMs (host-side attr, graph-safe)
  {
    auto k0 = gemm_bf16<0, 6>;
    auto k1 = gemm_bf16<1, 2>;
    hipFuncSetAttribute(reinterpret_cast<const void*>(k0),
                        hipFuncAttributeMaxDynamicSharedMemorySize, 131072);
    hipFuncSetAttribute(reinterpret_cast<const void*>(k1),
                        hipFuncAttributeMaxDynamicSharedMemorySize, 131072);
  }

  // 1. convert x; transpose conv weights
  cvt_x<<<dim3((MTOT * 512 / 8 + 255) / 256), dim3(256), 0, stream>>>(x, xb, MTOT * 512 / 8);
  conv_wT<<<dim3(7), dim3(256), 0, stream>>>(dwcw, wTc);
  // 2. transpose weights -> (N x K) bf16
  tconv<<<dim3(16, 16), dim3(256), 0, stream>>>(Wq,    wqkvT,              512);
  tconv<<<dim3(32, 16), dim3(256), 0, stream>>>(Wkv,   wqkvT + 512 * 512, 1024);
  tconv<<<dim3(16, 16), dim3(256), 0, stream>>>(Wproj, wprojT,             512);
  // 3. QKV GEMM, fused activations (256x256 tiles, 98*6=588 blocks)
  gemm_bf16<0, 6><<<dim3(588), dim3(512), 131072, stream>>>(xb, wqkvT, qb, kbuf, vbuf, pos,
                                                            nullptr, nullptr);
  // 4. per-head KtV + ksum -> bf16 kvT [d][c]
  kvmat_part<<<dim3(7, 64), dim3(256), 0, stream>>>(kbuf, vbuf, pKV, pKS);
  kv_reduce<<<dim3(64), dim3(256), 0, stream>>>(pKV, pKS, kvT, ksumB);
  // 5. depthwise conv -> pre
  conv_dw<<<dim3(56, 64), dim3(256), 0, stream>>>(vbuf, wTc, dwcb, pre);
  // 6. attention output + fmap (in-place on pre), MFMA micro-GEMM
  attn_mfma<<<dim3(49, 64), dim3(64), 0, stream>>>(qb, kvT, ksumB, pre);
  // 7. projection GEMM -> f32 out (256x256 tiles, 98*2=196 blocks)
  gemm_bf16<1, 2><<<dim3(196), dim3(512), 131072, stream>>>(pre, wprojT, nullptr, nullptr, nullptr,
                                                            nullptr, out, bproj);
}

// Round 10
// 216.107 us; speedup vs baseline: 1.2901x; 1.0205x over previous
//
#include <hip/hip_runtime.h>
#include <stdint.h>

// SimplifiedLinearAttention: B=8, N=3136 (56x56), C=512, 8 heads x 64
// Pipeline: cvt -> transpose weights -> GEMM(QKV,fused act) -> kvmat/ksum ->
//           conv_dw -> attn_mfma(z,out,+fmap) -> GEMM(proj,+bias) -> f32 out
// R10: GEMM re-geometried for occupancy: wave-tile 64x64 (acc 64 regs ->
//      ~115 VGPR total, launch_bounds(512,4) => 4 waves/SIMD, 2 blocks/CU).
//      BM=128, BN=256(QKV)/128(proj), BK=32, 3-buffer LDS ring, stage 2
//      tiles ahead, counted vmcnt(3/2), ONE barrier/tile, lgkm fencing.
//      All non-GEMM kernels byte-identical to R9 (passing).
#define B_    8
#define N_    3136
#define C_    512
#define MTOT  25088   // B_*N_

typedef __attribute__((ext_vector_type(8))) short bf16x8;
typedef __attribute__((ext_vector_type(4))) float f32x4;

__device__ __forceinline__ float bf2f(short s){
  union { float f; uint32_t u; } cv; cv.u = ((uint32_t)(uint16_t)s) << 16; return cv.f;
}
__device__ __forceinline__ short f2bf(float f){
  union { float f; uint32_t u; } cv; cv.f = f;
  uint32_t r = cv.u + 0x7FFFu + ((cv.u >> 16) & 1u);
  return (short)(r >> 16);
}

typedef const __attribute__((address_space(1))) void* gas1_t;
typedef __attribute__((address_space(3))) void* las3_t;
__device__ __forceinline__ void gld16(const void* g, void* l){
  __builtin_amdgcn_global_load_lds((gas1_t)g, (las3_t)l, 16, 0, 0);
}

#define BARR  __builtin_amdgcn_s_barrier()
#define SCHB  __builtin_amdgcn_sched_barrier(0)
#define VMC0  asm volatile("s_waitcnt vmcnt(0)" ::: "memory")
#define VMC2  asm volatile("s_waitcnt vmcnt(2)" ::: "memory")
#define VMC3  asm volatile("s_waitcnt vmcnt(3)" ::: "memory")
#define LGKM0 asm volatile("s_waitcnt lgkmcnt(0)" ::: "memory")

// ---------------- convert x to bf16 (vectorized) ----------------
__global__ __launch_bounds__(256) void cvt_x(const float* __restrict__ x,
                                             short* __restrict__ xb, int n8){
  int i = blockIdx.x * 256 + threadIdx.x;
  if (i >= n8) return;
  const float4* p = (const float4*)x;
  float4 a = p[i*2], b = p[i*2+1];
  short o[8] = { f2bf(a.x), f2bf(a.y), f2bf(a.z), f2bf(a.w),
                 f2bf(b.x), f2bf(b.y), f2bf(b.z), f2bf(b.w) };
  *(bf16x8*)(xb + i*8) = *(bf16x8*)o;
}

// -------- transpose+convert weights: dst[j*512 + k] = bf16(src[k*J + j]) ----
__global__ __launch_bounds__(256) void tconv(const float* __restrict__ src,
                                             short* __restrict__ dst, int J){
  __shared__ float tile[32][33];
  int jb = blockIdx.x * 32, kb = blockIdx.y * 32;
  int tx = threadIdx.x & 31, ty = threadIdx.x >> 5;   // ty 0..7
#pragma unroll
  for (int r = 0; r < 32; r += 8)
    tile[ty + r][tx] = src[(size_t)(kb + ty + r) * J + jb + tx];
  __syncthreads();
#pragma unroll
  for (int r = 0; r < 32; r += 8)
    dst[(size_t)(jb + ty + r) * 512 + kb + tx] = f2bf(tile[tx][ty + r]);
}

// -------- conv weight transpose: wt[tap*64 + c] = w[c*25 + tap] ------------
__global__ __launch_bounds__(256) void conv_wT(const float* __restrict__ w,
                                               float* __restrict__ wt){
  int i = blockIdx.x * 256 + threadIdx.x;
  if (i < 1600) { int c = i / 25, tap = i - c * 25; wt[tap * 64 + c] = w[i]; }
}

// ---------------- 128xBN bf16 MFMA GEMM, K=512, Bt is (N x K) ----------------
// 8 waves (2M x 4N), wave-tile 64x(BN/4), acc[4][NJ]. BK=32, 16 K-tiles.
// LDS: 3-buffer ring, buf = [A 8KB | B BN*64B]. Stage 2 tiles ahead
// (LOADS/wave/tile: A 1 gld16 + B 2 (MODE0) / 1 (MODE1)); per tile:
//   vmcnt(LOADS) [tile t landed] ; s_barrier ; stage(t+2) ; ds_read frags(t)
//   ; lgkmcnt(0)+sched_barrier ; setprio{MFMA} ; (next iter's barrier
//   guarantees all reads done before buf reuse at t+3).
// Swizzle (involution both sides): 16B-chunk phys = log ^ ((row>>1)&3).
// MODE 0: QKV epilogue (relu q / relu(k+pos) / v, bf16). MODE 1: +bias, f32.
template<int MODE, int NCT>
__global__ __launch_bounds__(512, 4)
void gemm_bf16(const short* __restrict__ A, const short* __restrict__ Bt,
               short* __restrict__ oQ, short* __restrict__ oK, short* __restrict__ oV,
               const float* __restrict__ posenc,
               float* __restrict__ oF, const float* __restrict__ bias)
{
  constexpr int BN    = MODE ? 128 : 256;
  constexpr int NJ    = MODE ? 2 : 4;          // B frags per wave
  constexpr int WNW   = MODE ? 32 : 64;        // wave N width
  constexpr int BUFSZ = MODE ? 16384 : 24576;  // A 8KB + B 8/16KB
  constexpr int BOFF  = 8192;
  extern __shared__ __align__(16) char lds[];
  const int tid = threadIdx.x;
  const int wave = tid >> 6, lane = tid & 63;
  const int fr = lane & 15;

  // m204 bijective XCD swizzle
  constexpr int nwg = 196 * NCT;
  constexpr int q8 = nwg / 8, r8 = nwg % 8;
  const int orig = blockIdx.x;
  const int xcd = orig & 7, lid = orig >> 3;
  const int swz = (xcd < r8 ? xcd * (q8 + 1) : r8 * (q8 + 1) + (xcd - r8) * q8) + lid;
  const int rt = (swz / NCT) * 128;
  const int ct = (swz % NCT) * BN;

  const int wm = (wave >> 2) * 64;
  const int wn = (wave & 3) * WNW;

  // ---- staging: per-lane source (pre-swizzled), wave-uniform LDS dest ----
  const int srow = lane >> 2;                                  // 0..15
  const int csrc = ((lane & 3) ^ ((lane >> 3) & 3)) << 3;      // shorts
  const short* srcA = A  + (size_t)(rt + wave * 16 + srow) * 512 + csrc;
  const short* srcB = Bt + (size_t)(ct + wave * (MODE ? 16 : 32) + srow) * 512 + csrc;
  char* dA = lds + wave * 1024;
  char* dB = lds + BOFF + wave * (MODE ? 1024 : 2048);

  auto stage = [&](int t) {
    const int b = (t % 3) * BUFSZ;
    const short* a0 = srcA + t * 32;
    gld16(a0, dA + b);
    const short* b0 = srcB + t * 32;
    gld16(b0, dB + b);
    if (MODE == 0) gld16(b0 + 8192, dB + b + 1024);   // B rows +16
  };

  // ---- fragment ds_read offsets (swizzled; (row>>1)&3 == (fr>>1)&3) ----
  const int cR   = (((lane >> 4) ^ ((fr >> 1) & 3)) << 4);
  const int offA = (wm + fr) * 64 + cR;
  const int offB = BOFF + (wn + fr) * 64 + cR;

  f32x4 zv = {0.f, 0.f, 0.f, 0.f};
  f32x4 acc[4][NJ];
#pragma unroll
  for (int i = 0; i < 4; i++)
#pragma unroll
    for (int j = 0; j < NJ; j++) acc[i][j] = zv;

  stage(0); stage(1);        // prologue: 2 tiles in flight

#pragma unroll
  for (int t = 0; t < 16; ++t) {
    if (t < 15) { if (MODE == 0) { VMC3; } else { VMC2; } }
    else       { VMC0; }
    BARR; SCHB;                       // tile t landed chip-wide; all reads
                                      // of buf[t%3] (from iter t-3) retired
    if (t + 2 < 16) stage(t + 2);
    const char* sb = lds + (t % 3) * BUFSZ;
    bf16x8 af[4], bfr[NJ];
#pragma unroll
    for (int i = 0; i < 4; i++) af[i] = *(const bf16x8*)(sb + offA + i * 1024);
#pragma unroll
    for (int j = 0; j < NJ; j++) bfr[j] = *(const bf16x8*)(sb + offB + j * 1024);
    LGKM0; SCHB;                      // rule #18: reads complete HERE
    __builtin_amdgcn_s_setprio(1);
#pragma unroll
    for (int i = 0; i < 4; i++)
#pragma unroll
      for (int j = 0; j < NJ; j++)
        acc[i][j] = __builtin_amdgcn_mfma_f32_16x16x32_bf16(af[i], bfr[j], acc[i][j], 0, 0, 0);
    __builtin_amdgcn_s_setprio(0);
  }

  BARR; SCHB;                         // all LDS reads done -> reusable

  // ---- epilogue: full-tile restage through LDS, coalesced stores ----
  const int rb = (lane >> 4) << 2;    // D layout: row=(lane>>4)*4+reg
  if (MODE == 0) {
    short* ov = (short*)lds;          // [128][264] bf16 (67584 B)
    const int sel = ct >> 9;          // 0:Q 1:K 2:V (uniform per block)
    const int cb  = ct - sel * 512;
    short* outp = sel == 0 ? oQ : (sel == 1 ? oK : oV);
#pragma unroll
    for (int i = 0; i < 4; i++)
#pragma unroll
      for (int j = 0; j < 4; j++)
#pragma unroll
        for (int r = 0; r < 4; r++)
          ov[(wm + i * 16 + rb + r) * 264 + wn + j * 16 + fr] = f2bf(acc[i][j][r]);
    __syncthreads();
#pragma unroll
    for (int p = 0; p < 8; ++p) {
      int id = tid + 512 * p;
      int row = id >> 5, cc = (id & 31) * 8;
      bf16x8 vv = *(const bf16x8*)&ov[row * 264 + cc];
      int grow = rt + row;
      short o[8];
      if (sel == 0) {
#pragma unroll
        for (int e = 0; e < 8; e++) o[e] = f2bf(fmaxf(bf2f(vv[e]), 0.f));
      } else if (sel == 1) {
        int nr = grow % N_;
        const float* pp = posenc + (size_t)nr * 512 + cb + cc;
        f32x4 p0 = *(const f32x4*)pp;
        f32x4 p1 = *(const f32x4*)(pp + 4);
#pragma unroll
        for (int e = 0; e < 4; e++) {
          o[e]     = f2bf(fmaxf(bf2f(vv[e]) + p0[e], 0.f));
          o[e + 4] = f2bf(fmaxf(bf2f(vv[e + 4]) + p1[e], 0.f));
        }
      } else {
#pragma unroll
        for (int e = 0; e < 8; e++) o[e] = vv[e];
      }
      *(bf16x8*)(outp + (size_t)grow * 512 + cb + cc) = *(bf16x8*)o;
    }
  } else {
    float* ovf = (float*)lds;         // [128][132] f32 (67584 B)
#pragma unroll
    for (int i = 0; i < 4; i++)
#pragma unroll
      for (int j = 0; j < 2; j++)
#pragma unroll
        for (int r = 0; r < 4; r++)
          ovf[(wm + i * 16 + rb + r) * 132 + wn + j * 16 + fr] = acc[i][j][r];
    __syncthreads();
#pragma unroll
    for (int p = 0; p < 4; ++p) {
      int id = tid + 512 * p;
      int row = id >> 4, cc = (id & 15) * 8;
      f32x4 v0 = *(const f32x4*)&ovf[row * 132 + cc];
      f32x4 v1 = *(const f32x4*)&ovf[row * 132 + cc + 4];
      v0 += *(const f32x4*)&bias[ct + cc];
      v1 += *(const f32x4*)&bias[ct + cc + 4];
      float* op = oF + (size_t)(rt + row) * 512 + ct + cc;
      *(f32x4*)op       = v0;
      *(f32x4*)(op + 4) = v1;
    }
  }
}

// ------------- per-head KtV (64x64) + ksum, f32 partials, N split 7 ----------
__global__ __launch_bounds__(256)
void kvmat_part(const short* __restrict__ kb, const short* __restrict__ vb,
                float* __restrict__ pKV, float* __restrict__ pKS)
{
  __shared__ __align__(16) float lk[64][64];
  __shared__ __align__(16) float lv[64][64];
  const int chunk = blockIdx.x, bh = blockIdx.y;
  const int b = bh >> 3, h = bh & 7;
  const int t = threadIdx.x;
  const int tc = t >> 4, td = t & 15;
  const int kc = t & 63, kr = (t >> 6) * 16;
  float acc[4][4] = {};
  float ksacc = 0.f;

  for (int tile = 0; tile < 7; ++tile) {
    const int r0 = chunk * 448 + tile * 64;
    __syncthreads();
#pragma unroll
    for (int i = 0; i < 2; i++) {
      int idx = t + i * 256;
      int r = idx >> 3, c8 = (idx & 7) << 3;
      size_t g = (size_t)(b * N_ + r0 + r) * 512 + h * 64 + c8;
      bf16x8 kk = *(const bf16x8*)(kb + g);
      bf16x8 vv = *(const bf16x8*)(vb + g);
#pragma unroll
      for (int e = 0; e < 8; e++) { lk[r][c8 + e] = bf2f(kk[e]); lv[r][c8 + e] = bf2f(vv[e]); }
    }
    __syncthreads();
#pragma unroll 4
    for (int r = 0; r < 64; r++) {
      f32x4 k4 = *(const f32x4*)&lk[r][tc * 4];
      f32x4 v4 = *(const f32x4*)&lv[r][td * 4];
#pragma unroll
      for (int i = 0; i < 4; i++)
#pragma unroll
        for (int j = 0; j < 4; j++) acc[i][j] += k4[i] * v4[j];
    }
#pragma unroll 4
    for (int rr = 0; rr < 16; rr++) ksacc += lk[kr + rr][kc];
  }

  const int pbase = (bh * 7 + chunk) * 4096;
#pragma unroll
  for (int i = 0; i < 4; i++)
#pragma unroll
    for (int j = 0; j < 4; j++)
      pKV[pbase + (tc * 4 + i) * 64 + td * 4 + j] = acc[i][j];
  __syncthreads();
  float* red = &lk[0][0];
  red[t] = ksacc;
  __syncthreads();
  if (t < 64)
    pKS[(bh * 7 + chunk) * 64 + t] = red[t] + red[t + 64] + red[t + 128] + red[t + 192];
}

// ------- reduce partials; emit kvT bf16 [d][c] (B-operand layout) + ksum ----
__global__ __launch_bounds__(256)
void kv_reduce(const float* __restrict__ pKV, const float* __restrict__ pKS,
               short* __restrict__ kvT, float* __restrict__ ksum)
{
  int bh = blockIdx.x, t = threadIdx.x;
#pragma unroll
  for (int i = 0; i < 16; i++) {
    int idx = t + i * 256;
    float s = 0.f;
#pragma unroll
    for (int c = 0; c < 7; c++) s += pKV[(bh * 7 + c) * 4096 + idx];
    int cc = idx >> 6, d = idx & 63;           // pKV layout [c][d]
    kvT[bh * 4096 + d * 64 + cc] = f2bf(s);    // transposed bf16
  }
  if (t < 64) {
    float s = 0.f;
#pragma unroll
    for (int c = 0; c < 7; c++) s += pKS[(bh * 7 + c) * 64 + t];
    ksum[bh * 64 + t] = s;
  }
}

// ------------- depthwise 5x5 conv on v, +bias -> pre (bf16) -------------
__global__ __launch_bounds__(256)
void conv_dw(const short* __restrict__ vb, const float* __restrict__ wT,
             const float* __restrict__ bias, short* __restrict__ pre)
{
  __shared__ __align__(16) short lsv[5 * 56 * 64];   // [row][x][64ch]
  __shared__ __align__(16) float lwT[25 * 64];       // [tap][64ch]
  const int y = blockIdx.x, bh = blockIdx.y;
  const int b = bh >> 3, h = bh & 7;
  const int t = threadIdx.x;
  for (int i = t; i < 1600; i += 256) lwT[i] = wT[i];
  for (int i = t; i < 2240; i += 256) {
    int row = i / 448, rem = i - row * 448;
    int xx = rem >> 3, c8i = rem & 7;
    int gy = y + row - 2;
    bf16x8 val = {0, 0, 0, 0, 0, 0, 0, 0};
    if ((unsigned)gy < 56u)
      val = *(const bf16x8*)(vb + (size_t)(b * N_ + gy * 56 + xx) * 512 + h * 64 + c8i * 8);
    *(bf16x8*)(lsv + i * 8) = val;     // linear: [(row*56+xx)*64 + c8*8]
  }
  __syncthreads();

  const int c8 = t & 7;                // 8-channel chunk within head
  const int x0 = t >> 3;               // 0..31; second pass covers x0+32
  float acc0[8], acc1[8];
  {
    f32x4 b0 = *(const f32x4*)&bias[c8 * 8];
    f32x4 b1 = *(const f32x4*)&bias[c8 * 8 + 4];
#pragma unroll
    for (int e = 0; e < 4; e++) { acc0[e] = b0[e]; acc0[e+4] = b1[e];
                                  acc1[e] = b0[e]; acc1[e+4] = b1[e]; }
  }
#pragma unroll
  for (int dy = 0; dy < 5; ++dy) {
#pragma unroll
    for (int dx = 0; dx < 5; ++dx) {
      float w8[8];
      {
        const float* wp = &lwT[(dy * 5 + dx) * 64 + c8 * 8];
        *(f32x4*)&w8[0] = *(const f32x4*)wp;
        *(f32x4*)&w8[4] = *(const f32x4*)(wp + 4);
      }
      const int base = dy * 56 * 64 + c8 * 8;
      int xxa = x0 + dx - 2;
      if ((unsigned)xxa < 56u) {
        bf16x8 v = *(const bf16x8*)(lsv + base + xxa * 64);
#pragma unroll
        for (int e = 0; e < 8; e++) acc0[e] += bf2f(v[e]) * w8[e];
      }
      int xxb = xxa + 32;
      if (xxb < 56) {
        bf16x8 v = *(const bf16x8*)(lsv + base + xxb * 64);
#pragma unroll
        for (int e = 0; e < 8; e++) acc1[e] += bf2f(v[e]) * w8[e];
      }
    }
  }
  size_t gbase = (size_t)(b * N_ + y * 56 + x0) * 512 + h * 64 + c8 * 8;
  short o[8];
#pragma unroll
  for (int e = 0; e < 8; e++) o[e] = f2bf(acc0[e]);
  *(bf16x8*)(pre + gbase) = *(bf16x8*)o;
  if (x0 + 32 < 56) {
#pragma unroll
    for (int e = 0; e < 8; e++) o[e] = f2bf(acc1[e]);
    *(bf16x8*)(pre + gbase + (size_t)32 * 512) = *(bf16x8*)o;
  }
}

// ---- attn: per-wave MFMA micro-GEMM out = (q @ kvT^T)*z + pre (RMW) ----
__global__ __launch_bounds__(64)
void attn_mfma(const short* __restrict__ qb, const short* __restrict__ kvT,
               const float* __restrict__ ksum, short* __restrict__ pre)
{
  __shared__ __align__(16) float ov[64 * 68];
  __shared__ float lks[64];
  const int pt = blockIdx.x, bh = blockIdx.y;
  const int b = bh >> 3, h = bh & 7;
  const int l = threadIdx.x;
  const int fr = l & 15, kg = l >> 4;
  const int n0 = pt * 64;

  lks[l] = ksum[bh * 64 + l];

  const short* qbase = qb + (size_t)(b * N_ + n0) * 512 + h * 64;
  const short* kvb   = kvT + bh * 4096;
  bf16x8 af[4][2], bm[4][2];
#pragma unroll
  for (int i = 0; i < 4; i++)
#pragma unroll
    for (int s = 0; s < 2; s++) {
      af[i][s] = *(const bf16x8*)(qbase + (size_t)(fr + i * 16) * 512 + s * 32 + kg * 8);
      bm[i][s] = *(const bf16x8*)(kvb + (fr + i * 16) * 64 + s * 32 + kg * 8);
    }

  f32x4 zv4 = {0.f, 0.f, 0.f, 0.f};
  f32x4 acc[4][4];
#pragma unroll
  for (int i = 0; i < 4; i++)
#pragma unroll
    for (int j = 0; j < 4; j++) acc[i][j] = zv4;
#pragma unroll
  for (int s = 0; s < 2; s++)
#pragma unroll
    for (int i = 0; i < 4; i++)
#pragma unroll
      for (int j = 0; j < 4; j++)
        acc[i][j] = __builtin_amdgcn_mfma_f32_16x16x32_bf16(af[i][s], bm[j][s], acc[i][j], 0, 0, 0);

  // z for own row l (f32, q re-read — same cache lines as frags)
  const short* qrow = qb + (size_t)(b * N_ + n0 + l) * 512 + h * 64;
  float zd = 0.f;
#pragma unroll
  for (int g = 0; g < 8; g++) {
    bf16x8 qv = *(const bf16x8*)(qrow + g * 8);
#pragma unroll
    for (int e = 0; e < 8; e++) zd += bf2f(qv[e]) * lks[g * 8 + e];
  }
  const float z = 1.f / (zd + 1e-6f);

  // restage acc: row = i*16 + kg*4 + r, col = j*16 + fr
  const int rb = kg << 2;
#pragma unroll
  for (int i = 0; i < 4; i++)
#pragma unroll
    for (int j = 0; j < 4; j++)
#pragma unroll
      for (int r = 0; r < 4; r++)
        ov[(i * 16 + rb + r) * 68 + j * 16 + fr] = acc[i][j][r];
  __syncthreads();

  // vectorized RMW: lane l owns pixel n0+l
  size_t gb = (size_t)(b * N_ + n0 + l) * 512 + h * 64;
  const float* ovr = &ov[l * 68];
#pragma unroll
  for (int g = 0; g < 8; g++) {
    bf16x8 pv = *(const bf16x8*)(pre + gb + g * 8);
    f32x4 a0 = *(const f32x4*)(ovr + g * 8);
    f32x4 a1 = *(const f32x4*)(ovr + g * 8 + 4);
    short o[8];
#pragma unroll
    for (int e = 0; e < 4; e++) {
      o[e]     = f2bf(a0[e] * z + bf2f(pv[e]));
      o[e + 4] = f2bf(a1[e] * z + bf2f(pv[e + 4]));
    }
    *(bf16x8*)(pre + gb + g * 8) = *(bf16x8*)o;
  }
}

// ---------------------------------------------------------------------------
extern "C" void kernel_launch(void* const* d_in, const int* in_sizes, int n_in,
                              void* d_out, int out_size, void* d_ws, size_t ws_size,
                              hipStream_t stream)
{
  const float* x     = (const float*)d_in[0];
  const float* Wq    = (const float*)d_in[3];
  const float* Wkv   = (const float*)d_in[4];
  const float* pos   = (const float*)d_in[5];
  const float* dwcw  = (const float*)d_in[6];
  const float* dwcb  = (const float*)d_in[7];
  const float* Wproj = (const float*)d_in[8];
  const float* bproj = (const float*)d_in[9];
  float* out = (float*)d_out;

  char* ws = (char*)d_ws;
  size_t off = 0;
  auto alloc = [&](size_t bytes) -> void* {
    void* p = ws + off;
    off = (off + bytes + 255) & ~(size_t)255;
    return p;
  };
  short* xb     = (short*)alloc((size_t)MTOT * 512 * 2);
  short* wqkvT  = (short*)alloc((size_t)1536 * 512 * 2);
  short* wprojT = (short*)alloc((size_t)512 * 512 * 2);
  float* wTc    = (float*)alloc((size_t)25 * 64 * 4);
  short* qb     = (short*)alloc((size_t)MTOT * 512 * 2);
  short* kbuf   = (short*)alloc((size_t)MTOT * 512 * 2);
  short* vbuf   = (short*)alloc((size_t)MTOT * 512 * 2);
  float* pKV    = (float*)alloc((size_t)64 * 7 * 4096 * 4);
  float* pKS    = (float*)alloc((size_t)64 * 7 * 64 * 4);
  short* kvT    = (short*)alloc((size_t)64 * 4096 * 2);
  float* ksumB  = (float*)alloc((size_t)64 * 64 * 4);
  short* pre    = (short*)alloc((size_t)MTOT * 512 * 2);
  if (ws_size < off) return;   // workspace too small: leave output zeroed (visible failure)

  // dynamic LDS for the GEMMs (host-side attr, graph-safe)
  {
    auto k0 = gemm_bf16<0, 6>;
    auto k1 = gemm_bf16<1, 4>;
    hipFuncSetAttribute(reinterpret_cast<const void*>(k0),
                        hipFuncAttributeMaxDynamicSharedMemorySize, 73728);
    hipFuncSetAttribute(reinterpret_cast<const void*>(k1),
                        hipFuncAttributeMaxDynamicSharedMemorySize, 67584);
  }

  // 1. convert x; transpose conv weights
  cvt_x<<<dim3((MTOT * 512 / 8 + 255) / 256), dim3(256), 0, stream>>>(x, xb, MTOT * 512 / 8);
  conv_wT<<<dim3(7), dim3(256), 0, stream>>>(dwcw, wTc);
  // 2. transpose weights -> (N x K) bf16
  tconv<<<dim3(16, 16), dim3(256), 0, stream>>>(Wq,    wqkvT,              512);
  tconv<<<dim3(32, 16), dim3(256), 0, stream>>>(Wkv,   wqkvT + 512 * 512, 1024);
  tconv<<<dim3(16, 16), dim3(256), 0, stream>>>(Wproj, wprojT,             512);
  // 3. QKV GEMM, fused activations (128x256 tiles, 196*6=1176 blocks)
  gemm_bf16<0, 6><<<dim3(1176), dim3(512), 73728, stream>>>(xb, wqkvT, qb, kbuf, vbuf, pos,
                                                            nullptr, nullptr);
  // 4. per-head KtV + ksum -> bf16 kvT [d][c]
  kvmat_part<<<dim3(7, 64), dim3(256), 0, stream>>>(kbuf, vbuf, pKV, pKS);
  kv_reduce<<<dim3(64), dim3(256), 0, stream>>>(pKV, pKS, kvT, ksumB);
  // 5. depthwise conv -> pre
  conv_dw<<<dim3(56, 64), dim3(256), 0, stream>>>(vbuf, wTc, dwcb, pre);
  // 6. attention output + fmap (in-place on pre), MFMA micro-GEMM
  attn_mfma<<<dim3(49, 64), dim3(64), 0, stream>>>(qb, kvT, ksumB, pre);
  // 7. projection GEMM -> f32 out (128x128 tiles, 196*4=784 blocks)
  gemm_bf16<1, 4><<<dim3(784), dim3(512), 67584, stream>>>(pre, wprojT, nullptr, nullptr, nullptr,
                                                           nullptr, out, bproj);
}

// Round 11
// 204.040 us; speedup vs baseline: 1.3664x; 1.0591x over previous
//
#include <hip/hip_runtime.h>
#include <stdint.h>

// SimplifiedLinearAttention: B=8, N=3136 (56x56), C=512, 8 heads x 64
// Pipeline: cvt -> transpose weights -> GEMM(QKV,fused act) -> kvmat/ksum ->
//           conv_dw -> attn_mfma(z,out,+fmap) -> GEMM(proj,+bias) -> f32 out
// R11: kvmat_part (scalar-VALU KtV, ~3.3 GF on f32 pipe) -> kvmat_mfma:
//      bf16 transposed LDS staging ([c][n]/[d][n], 72-short rows), 4 waves x
//      MFMA 16x16x32 (attn_mfma's verified fragment pattern), ksum via
//      ones-B-fragment MFMA. pKV/pKS layouts unchanged. All other kernels
//      byte-identical to R10 (passing).
#define B_    8
#define N_    3136
#define C_    512
#define MTOT  25088   // B_*N_

typedef __attribute__((ext_vector_type(8))) short bf16x8;
typedef __attribute__((ext_vector_type(4))) float f32x4;

__device__ __forceinline__ float bf2f(short s){
  union { float f; uint32_t u; } cv; cv.u = ((uint32_t)(uint16_t)s) << 16; return cv.f;
}
__device__ __forceinline__ short f2bf(float f){
  union { float f; uint32_t u; } cv; cv.f = f;
  uint32_t r = cv.u + 0x7FFFu + ((cv.u >> 16) & 1u);
  return (short)(r >> 16);
}

typedef const __attribute__((address_space(1))) void* gas1_t;
typedef __attribute__((address_space(3))) void* las3_t;
__device__ __forceinline__ void gld16(const void* g, void* l){
  __builtin_amdgcn_global_load_lds((gas1_t)g, (las3_t)l, 16, 0, 0);
}

#define BARR  __builtin_amdgcn_s_barrier()
#define SCHB  __builtin_amdgcn_sched_barrier(0)
#define VMC0  asm volatile("s_waitcnt vmcnt(0)" ::: "memory")
#define VMC2  asm volatile("s_waitcnt vmcnt(2)" ::: "memory")
#define VMC3  asm volatile("s_waitcnt vmcnt(3)" ::: "memory")
#define LGKM0 asm volatile("s_waitcnt lgkmcnt(0)" ::: "memory")

// ---------------- convert x to bf16 (vectorized) ----------------
__global__ __launch_bounds__(256) void cvt_x(const float* __restrict__ x,
                                             short* __restrict__ xb, int n8){
  int i = blockIdx.x * 256 + threadIdx.x;
  if (i >= n8) return;
  const float4* p = (const float4*)x;
  float4 a = p[i*2], b = p[i*2+1];
  short o[8] = { f2bf(a.x), f2bf(a.y), f2bf(a.z), f2bf(a.w),
                 f2bf(b.x), f2bf(b.y), f2bf(b.z), f2bf(b.w) };
  *(bf16x8*)(xb + i*8) = *(bf16x8*)o;
}

// -------- transpose+convert weights: dst[j*512 + k] = bf16(src[k*J + j]) ----
__global__ __launch_bounds__(256) void tconv(const float* __restrict__ src,
                                             short* __restrict__ dst, int J){
  __shared__ float tile[32][33];
  int jb = blockIdx.x * 32, kb = blockIdx.y * 32;
  int tx = threadIdx.x & 31, ty = threadIdx.x >> 5;   // ty 0..7
#pragma unroll
  for (int r = 0; r < 32; r += 8)
    tile[ty + r][tx] = src[(size_t)(kb + ty + r) * J + jb + tx];
  __syncthreads();
#pragma unroll
  for (int r = 0; r < 32; r += 8)
    dst[(size_t)(jb + ty + r) * 512 + kb + tx] = f2bf(tile[tx][ty + r]);
}

// -------- conv weight transpose: wt[tap*64 + c] = w[c*25 + tap] ------------
__global__ __launch_bounds__(256) void conv_wT(const float* __restrict__ w,
                                               float* __restrict__ wt){
  int i = blockIdx.x * 256 + threadIdx.x;
  if (i < 1600) { int c = i / 25, tap = i - c * 25; wt[tap * 64 + c] = w[i]; }
}

// ---------------- 128xBN bf16 MFMA GEMM, K=512, Bt is (N x K) ----------------
// (R10 structure, unchanged — passed; occ 30%, 0 bank conflicts.)
template<int MODE, int NCT>
__global__ __launch_bounds__(512, 4)
void gemm_bf16(const short* __restrict__ A, const short* __restrict__ Bt,
               short* __restrict__ oQ, short* __restrict__ oK, short* __restrict__ oV,
               const float* __restrict__ posenc,
               float* __restrict__ oF, const float* __restrict__ bias)
{
  constexpr int BN    = MODE ? 128 : 256;
  constexpr int NJ    = MODE ? 2 : 4;          // B frags per wave
  constexpr int WNW   = MODE ? 32 : 64;        // wave N width
  constexpr int BUFSZ = MODE ? 16384 : 24576;  // A 8KB + B 8/16KB
  constexpr int BOFF  = 8192;
  extern __shared__ __align__(16) char lds[];
  const int tid = threadIdx.x;
  const int wave = tid >> 6, lane = tid & 63;
  const int fr = lane & 15;

  // m204 bijective XCD swizzle
  constexpr int nwg = 196 * NCT;
  constexpr int q8 = nwg / 8, r8 = nwg % 8;
  const int orig = blockIdx.x;
  const int xcd = orig & 7, lid = orig >> 3;
  const int swz = (xcd < r8 ? xcd * (q8 + 1) : r8 * (q8 + 1) + (xcd - r8) * q8) + lid;
  const int rt = (swz / NCT) * 128;
  const int ct = (swz % NCT) * BN;

  const int wm = (wave >> 2) * 64;
  const int wn = (wave & 3) * WNW;

  // ---- staging: per-lane source (pre-swizzled), wave-uniform LDS dest ----
  const int srow = lane >> 2;                                  // 0..15
  const int csrc = ((lane & 3) ^ ((lane >> 3) & 3)) << 3;      // shorts
  const short* srcA = A  + (size_t)(rt + wave * 16 + srow) * 512 + csrc;
  const short* srcB = Bt + (size_t)(ct + wave * (MODE ? 16 : 32) + srow) * 512 + csrc;
  char* dA = lds + wave * 1024;
  char* dB = lds + BOFF + wave * (MODE ? 1024 : 2048);

  auto stage = [&](int t) {
    const int b = (t % 3) * BUFSZ;
    const short* a0 = srcA + t * 32;
    gld16(a0, dA + b);
    const short* b0 = srcB + t * 32;
    gld16(b0, dB + b);
    if (MODE == 0) gld16(b0 + 8192, dB + b + 1024);   // B rows +16
  };

  // ---- fragment ds_read offsets (swizzled; (row>>1)&3 == (fr>>1)&3) ----
  const int cR   = (((lane >> 4) ^ ((fr >> 1) & 3)) << 4);
  const int offA = (wm + fr) * 64 + cR;
  const int offB = BOFF + (wn + fr) * 64 + cR;

  f32x4 zv = {0.f, 0.f, 0.f, 0.f};
  f32x4 acc[4][NJ];
#pragma unroll
  for (int i = 0; i < 4; i++)
#pragma unroll
    for (int j = 0; j < NJ; j++) acc[i][j] = zv;

  stage(0); stage(1);        // prologue: 2 tiles in flight

#pragma unroll
  for (int t = 0; t < 16; ++t) {
    if (t < 15) { if (MODE == 0) { VMC3; } else { VMC2; } }
    else       { VMC0; }
    BARR; SCHB;                       // tile t landed chip-wide; all reads
                                      // of buf[t%3] (from iter t-3) retired
    if (t + 2 < 16) stage(t + 2);
    const char* sb = lds + (t % 3) * BUFSZ;
    bf16x8 af[4], bfr[NJ];
#pragma unroll
    for (int i = 0; i < 4; i++) af[i] = *(const bf16x8*)(sb + offA + i * 1024);
#pragma unroll
    for (int j = 0; j < NJ; j++) bfr[j] = *(const bf16x8*)(sb + offB + j * 1024);
    LGKM0; SCHB;                      // rule #18: reads complete HERE
    __builtin_amdgcn_s_setprio(1);
#pragma unroll
    for (int i = 0; i < 4; i++)
#pragma unroll
      for (int j = 0; j < NJ; j++)
        acc[i][j] = __builtin_amdgcn_mfma_f32_16x16x32_bf16(af[i], bfr[j], acc[i][j], 0, 0, 0);
    __builtin_amdgcn_s_setprio(0);
  }

  BARR; SCHB;                         // all LDS reads done -> reusable

  // ---- epilogue: full-tile restage through LDS, coalesced stores ----
  const int rb = (lane >> 4) << 2;    // D layout: row=(lane>>4)*4+reg
  if (MODE == 0) {
    short* ov = (short*)lds;          // [128][264] bf16 (67584 B)
    const int sel = ct >> 9;          // 0:Q 1:K 2:V (uniform per block)
    const int cb  = ct - sel * 512;
    short* outp = sel == 0 ? oQ : (sel == 1 ? oK : oV);
#pragma unroll
    for (int i = 0; i < 4; i++)
#pragma unroll
      for (int j = 0; j < 4; j++)
#pragma unroll
        for (int r = 0; r < 4; r++)
          ov[(wm + i * 16 + rb + r) * 264 + wn + j * 16 + fr] = f2bf(acc[i][j][r]);
    __syncthreads();
#pragma unroll
    for (int p = 0; p < 8; ++p) {
      int id = tid + 512 * p;
      int row = id >> 5, cc = (id & 31) * 8;
      bf16x8 vv = *(const bf16x8*)&ov[row * 264 + cc];
      int grow = rt + row;
      short o[8];
      if (sel == 0) {
#pragma unroll
        for (int e = 0; e < 8; e++) o[e] = f2bf(fmaxf(bf2f(vv[e]), 0.f));
      } else if (sel == 1) {
        int nr = grow % N_;
        const float* pp = posenc + (size_t)nr * 512 + cb + cc;
        f32x4 p0 = *(const f32x4*)pp;
        f32x4 p1 = *(const f32x4*)(pp + 4);
#pragma unroll
        for (int e = 0; e < 4; e++) {
          o[e]     = f2bf(fmaxf(bf2f(vv[e]) + p0[e], 0.f));
          o[e + 4] = f2bf(fmaxf(bf2f(vv[e + 4]) + p1[e], 0.f));
        }
      } else {
#pragma unroll
        for (int e = 0; e < 8; e++) o[e] = vv[e];
      }
      *(bf16x8*)(outp + (size_t)grow * 512 + cb + cc) = *(bf16x8*)o;
    }
  } else {
    float* ovf = (float*)lds;         // [128][132] f32 (67584 B)
#pragma unroll
    for (int i = 0; i < 4; i++)
#pragma unroll
      for (int j = 0; j < 2; j++)
#pragma unroll
        for (int r = 0; r < 4; r++)
          ovf[(wm + i * 16 + rb + r) * 132 + wn + j * 16 + fr] = acc[i][j][r];
    __syncthreads();
#pragma unroll
    for (int p = 0; p < 4; ++p) {
      int id = tid + 512 * p;
      int row = id >> 4, cc = (id & 15) * 8;
      f32x4 v0 = *(const f32x4*)&ovf[row * 132 + cc];
      f32x4 v1 = *(const f32x4*)&ovf[row * 132 + cc + 4];
      v0 += *(const f32x4*)&bias[ct + cc];
      v1 += *(const f32x4*)&bias[ct + cc + 4];
      float* op = oF + (size_t)(rt + row) * 512 + ct + cc;
      *(f32x4*)op       = v0;
      *(f32x4*)(op + 4) = v1;
    }
  }
}

// ------- per-head KtV (64x64) + ksum via MFMA, f32 partials, N split 7 ------
// Block = (chunk, bh), 256 threads = 4 waves. Stage k,v transposed to LDS as
// bf16 [c][n] / [d][n] with 72-short rows (frag reads hit all 8 bank-groups
// uniformly). Wave w computes C rows w*16..+15 (c), all 64 cols (d):
//   C[c][d] = sum_n kT[c][n] * vT[d][n]  -> mfma(A=kT rows, B=vT rows)
// (fragment pattern identical to attn_mfma, verified). ksum via extra MFMA
// against ones-B (col 0 holds sum_n k[n][c]).
__global__ __launch_bounds__(256)
void kvmat_mfma(const short* __restrict__ kb, const short* __restrict__ vb,
                float* __restrict__ pKV, float* __restrict__ pKS)
{
  __shared__ __align__(16) short lkT[64 * 72];
  __shared__ __align__(16) short lvT[64 * 72];
  const int chunk = blockIdx.x, bh = blockIdx.y;
  const int b = bh >> 3, h = bh & 7;
  const int t = threadIdx.x;
  const int wave = t >> 6, lane = t & 63;
  const int fr = lane & 15, kg = lane >> 4;

  f32x4 zv = {0.f, 0.f, 0.f, 0.f};
  f32x4 acc[4];
#pragma unroll
  for (int j = 0; j < 4; j++) acc[j] = zv;
  f32x4 accks = zv;

  bf16x8 ones;
#pragma unroll
  for (int e = 0; e < 8; e++) ones[e] = (short)0x3F80;   // bf16 1.0

  const int rr = t >> 3, c8 = t & 7;
  for (int tile = 0; tile < 7; ++tile) {
    const int r0 = chunk * 448 + tile * 64;
    __syncthreads();                       // prev tile's frag reads done
#pragma unroll
    for (int half = 0; half < 2; ++half) {
      int r = rr + half * 32;
      size_t g = (size_t)(b * N_ + r0 + r) * 512 + h * 64 + c8 * 8;
      bf16x8 kk = *(const bf16x8*)(kb + g);
      bf16x8 vv = *(const bf16x8*)(vb + g);
#pragma unroll
      for (int e = 0; e < 8; e++) {
        lkT[(c8 * 8 + e) * 72 + r] = kk[e];
        lvT[(c8 * 8 + e) * 72 + r] = vv[e];
      }
    }
    __syncthreads();
#pragma unroll
    for (int ks = 0; ks < 2; ++ks) {
      const int ko = ks * 32 + kg * 8;
      bf16x8 af = *(const bf16x8*)&lkT[(wave * 16 + fr) * 72 + ko];
      bf16x8 bm[4];
#pragma unroll
      for (int j = 0; j < 4; j++)
        bm[j] = *(const bf16x8*)&lvT[(j * 16 + fr) * 72 + ko];
#pragma unroll
      for (int j = 0; j < 4; j++)
        acc[j] = __builtin_amdgcn_mfma_f32_16x16x32_bf16(af, bm[j], acc[j], 0, 0, 0);
      accks = __builtin_amdgcn_mfma_f32_16x16x32_bf16(af, ones, accks, 0, 0, 0);
    }
  }

  // write partials: D layout row=(lane>>4)*4+reg (c within wave 16), col=fr (d)
  const int pbase = (bh * 7 + chunk) * 4096;
  const int crow = wave * 16 + kg * 4;
#pragma unroll
  for (int j = 0; j < 4; j++)
#pragma unroll
    for (int r_ = 0; r_ < 4; r_++)
      pKV[pbase + (crow + r_) * 64 + j * 16 + fr] = acc[j][r_];
  if (fr == 0) {
#pragma unroll
    for (int r_ = 0; r_ < 4; r_++)
      pKS[(bh * 7 + chunk) * 64 + crow + r_] = accks[r_];
  }
}

// ------- reduce partials; emit kvT bf16 [d][c] (B-operand layout) + ksum ----
__global__ __launch_bounds__(256)
void kv_reduce(const float* __restrict__ pKV, const float* __restrict__ pKS,
               short* __restrict__ kvT, float* __restrict__ ksum)
{
  int bh = blockIdx.x, t = threadIdx.x;
#pragma unroll
  for (int i = 0; i < 16; i++) {
    int idx = t + i * 256;
    float s = 0.f;
#pragma unroll
    for (int c = 0; c < 7; c++) s += pKV[(bh * 7 + c) * 4096 + idx];
    int cc = idx >> 6, d = idx & 63;           // pKV layout [c][d]
    kvT[bh * 4096 + d * 64 + cc] = f2bf(s);    // transposed bf16
  }
  if (t < 64) {
    float s = 0.f;
#pragma unroll
    for (int c = 0; c < 7; c++) s += pKS[(bh * 7 + c) * 64 + t];
    ksum[bh * 64 + t] = s;
  }
}

// ------------- depthwise 5x5 conv on v, +bias -> pre (bf16) -------------
__global__ __launch_bounds__(256)
void conv_dw(const short* __restrict__ vb, const float* __restrict__ wT,
             const float* __restrict__ bias, short* __restrict__ pre)
{
  __shared__ __align__(16) short lsv[5 * 56 * 64];   // [row][x][64ch]
  __shared__ __align__(16) float lwT[25 * 64];       // [tap][64ch]
  const int y = blockIdx.x, bh = blockIdx.y;
  const int b = bh >> 3, h = bh & 7;
  const int t = threadIdx.x;
  for (int i = t; i < 1600; i += 256) lwT[i] = wT[i];
  for (int i = t; i < 2240; i += 256) {
    int row = i / 448, rem = i - row * 448;
    int xx = rem >> 3, c8i = rem & 7;
    int gy = y + row - 2;
    bf16x8 val = {0, 0, 0, 0, 0, 0, 0, 0};
    if ((unsigned)gy < 56u)
      val = *(const bf16x8*)(vb + (size_t)(b * N_ + gy * 56 + xx) * 512 + h * 64 + c8i * 8);
    *(bf16x8*)(lsv + i * 8) = val;     // linear: [(row*56+xx)*64 + c8*8]
  }
  __syncthreads();

  const int c8 = t & 7;                // 8-channel chunk within head
  const int x0 = t >> 3;               // 0..31; second pass covers x0+32
  float acc0[8], acc1[8];
  {
    f32x4 b0 = *(const f32x4*)&bias[c8 * 8];
    f32x4 b1 = *(const f32x4*)&bias[c8 * 8 + 4];
#pragma unroll
    for (int e = 0; e < 4; e++) { acc0[e] = b0[e]; acc0[e+4] = b1[e];
                                  acc1[e] = b0[e]; acc1[e+4] = b1[e]; }
  }
#pragma unroll
  for (int dy = 0; dy < 5; ++dy) {
#pragma unroll
    for (int dx = 0; dx < 5; ++dx) {
      float w8[8];
      {
        const float* wp = &lwT[(dy * 5 + dx) * 64 + c8 * 8];
        *(f32x4*)&w8[0] = *(const f32x4*)wp;
        *(f32x4*)&w8[4] = *(const f32x4*)(wp + 4);
      }
      const int base = dy * 56 * 64 + c8 * 8;
      int xxa = x0 + dx - 2;
      if ((unsigned)xxa < 56u) {
        bf16x8 v = *(const bf16x8*)(lsv + base + xxa * 64);
#pragma unroll
        for (int e = 0; e < 8; e++) acc0[e] += bf2f(v[e]) * w8[e];
      }
      int xxb = xxa + 32;
      if (xxb < 56) {
        bf16x8 v = *(const bf16x8*)(lsv + base + xxb * 64);
#pragma unroll
        for (int e = 0; e < 8; e++) acc1[e] += bf2f(v[e]) * w8[e];
      }
    }
  }
  size_t gbase = (size_t)(b * N_ + y * 56 + x0) * 512 + h * 64 + c8 * 8;
  short o[8];
#pragma unroll
  for (int e = 0; e < 8; e++) o[e] = f2bf(acc0[e]);
  *(bf16x8*)(pre + gbase) = *(bf16x8*)o;
  if (x0 + 32 < 56) {
#pragma unroll
    for (int e = 0; e < 8; e++) o[e] = f2bf(acc1[e]);
    *(bf16x8*)(pre + gbase + (size_t)32 * 512) = *(bf16x8*)o;
  }
}

// ---- attn: per-wave MFMA micro-GEMM out = (q @ kvT^T)*z + pre (RMW) ----
__global__ __launch_bounds__(64)
void attn_mfma(const short* __restrict__ qb, const short* __restrict__ kvT,
               const float* __restrict__ ksum, short* __restrict__ pre)
{
  __shared__ __align__(16) float ov[64 * 68];
  __shared__ float lks[64];
  const int pt = blockIdx.x, bh = blockIdx.y;
  const int b = bh >> 3, h = bh & 7;
  const int l = threadIdx.x;
  const int fr = l & 15, kg = l >> 4;
  const int n0 = pt * 64;

  lks[l] = ksum[bh * 64 + l];

  const short* qbase = qb + (size_t)(b * N_ + n0) * 512 + h * 64;
  const short* kvb   = kvT + bh * 4096;
  bf16x8 af[4][2], bm[4][2];
#pragma unroll
  for (int i = 0; i < 4; i++)
#pragma unroll
    for (int s = 0; s < 2; s++) {
      af[i][s] = *(const bf16x8*)(qbase + (size_t)(fr + i * 16) * 512 + s * 32 + kg * 8);
      bm[i][s] = *(const bf16x8*)(kvb + (fr + i * 16) * 64 + s * 32 + kg * 8);
    }

  f32x4 zv4 = {0.f, 0.f, 0.f, 0.f};
  f32x4 acc[4][4];
#pragma unroll
  for (int i = 0; i < 4; i++)
#pragma unroll
    for (int j = 0; j < 4; j++) acc[i][j] = zv4;
#pragma unroll
  for (int s = 0; s < 2; s++)
#pragma unroll
    for (int i = 0; i < 4; i++)
#pragma unroll
      for (int j = 0; j < 4; j++)
        acc[i][j] = __builtin_amdgcn_mfma_f32_16x16x32_bf16(af[i][s], bm[j][s], acc[i][j], 0, 0, 0);

  // z for own row l (f32, q re-read — same cache lines as frags)
  const short* qrow = qb + (size_t)(b * N_ + n0 + l) * 512 + h * 64;
  float zd = 0.f;
#pragma unroll
  for (int g = 0; g < 8; g++) {
    bf16x8 qv = *(const bf16x8*)(qrow + g * 8);
#pragma unroll
    for (int e = 0; e < 8; e++) zd += bf2f(qv[e]) * lks[g * 8 + e];
  }
  const float z = 1.f / (zd + 1e-6f);

  // restage acc: row = i*16 + kg*4 + r, col = j*16 + fr
  const int rb = kg << 2;
#pragma unroll
  for (int i = 0; i < 4; i++)
#pragma unroll
    for (int j = 0; j < 4; j++)
#pragma unroll
      for (int r = 0; r < 4; r++)
        ov[(i * 16 + rb + r) * 68 + j * 16 + fr] = acc[i][j][r];
  __syncthreads();

  // vectorized RMW: lane l owns pixel n0+l
  size_t gb = (size_t)(b * N_ + n0 + l) * 512 + h * 64;
  const float* ovr = &ov[l * 68];
#pragma unroll
  for (int g = 0; g < 8; g++) {
    bf16x8 pv = *(const bf16x8*)(pre + gb + g * 8);
    f32x4 a0 = *(const f32x4*)(ovr + g * 8);
    f32x4 a1 = *(const f32x4*)(ovr + g * 8 + 4);
    short o[8];
#pragma unroll
    for (int e = 0; e < 4; e++) {
      o[e]     = f2bf(a0[e] * z + bf2f(pv[e]));
      o[e + 4] = f2bf(a1[e] * z + bf2f(pv[e + 4]));
    }
    *(bf16x8*)(pre + gb + g * 8) = *(bf16x8*)o;
  }
}

// ---------------------------------------------------------------------------
extern "C" void kernel_launch(void* const* d_in, const int* in_sizes, int n_in,
                              void* d_out, int out_size, void* d_ws, size_t ws_size,
                              hipStream_t stream)
{
  const float* x     = (const float*)d_in[0];
  const float* Wq    = (const float*)d_in[3];
  const float* Wkv   = (const float*)d_in[4];
  const float* pos   = (const float*)d_in[5];
  const float* dwcw  = (const float*)d_in[6];
  const float* dwcb  = (const float*)d_in[7];
  const float* Wproj = (const float*)d_in[8];
  const float* bproj = (const float*)d_in[9];
  float* out = (float*)d_out;

  char* ws = (char*)d_ws;
  size_t off = 0;
  auto alloc = [&](size_t bytes) -> void* {
    void* p = ws + off;
    off = (off + bytes + 255) & ~(size_t)255;
    return p;
  };
  short* xb     = (short*)alloc((size_t)MTOT * 512 * 2);
  short* wqkvT  = (short*)alloc((size_t)1536 * 512 * 2);
  short* wprojT = (short*)alloc((size_t)512 * 512 * 2);
  float* wTc    = (float*)alloc((size_t)25 * 64 * 4);
  short* qb     = (short*)alloc((size_t)MTOT * 512 * 2);
  short* kbuf   = (short*)alloc((size_t)MTOT * 512 * 2);
  short* vbuf   = (short*)alloc((size_t)MTOT * 512 * 2);
  float* pKV    = (float*)alloc((size_t)64 * 7 * 4096 * 4);
  float* pKS    = (float*)alloc((size_t)64 * 7 * 64 * 4);
  short* kvT    = (short*)alloc((size_t)64 * 4096 * 2);
  float* ksumB  = (float*)alloc((size_t)64 * 64 * 4);
  short* pre    = (short*)alloc((size_t)MTOT * 512 * 2);
  if (ws_size < off) return;   // workspace too small: leave output zeroed (visible failure)

  // dynamic LDS for the GEMMs (host-side attr, graph-safe)
  {
    auto k0 = gemm_bf16<0, 6>;
    auto k1 = gemm_bf16<1, 4>;
    hipFuncSetAttribute(reinterpret_cast<const void*>(k0),
                        hipFuncAttributeMaxDynamicSharedMemorySize, 73728);
    hipFuncSetAttribute(reinterpret_cast<const void*>(k1),
                        hipFuncAttributeMaxDynamicSharedMemorySize, 67584);
  }

  // 1. convert x; transpose conv weights
  cvt_x<<<dim3((MTOT * 512 / 8 + 255) / 256), dim3(256), 0, stream>>>(x, xb, MTOT * 512 / 8);
  conv_wT<<<dim3(7), dim3(256), 0, stream>>>(dwcw, wTc);
  // 2. transpose weights -> (N x K) bf16
  tconv<<<dim3(16, 16), dim3(256), 0, stream>>>(Wq,    wqkvT,              512);
  tconv<<<dim3(32, 16), dim3(256), 0, stream>>>(Wkv,   wqkvT + 512 * 512, 1024);
  tconv<<<dim3(16, 16), dim3(256), 0, stream>>>(Wproj, wprojT,             512);
  // 3. QKV GEMM, fused activations (128x256 tiles, 196*6=1176 blocks)
  gemm_bf16<0, 6><<<dim3(1176), dim3(512), 73728, stream>>>(xb, wqkvT, qb, kbuf, vbuf, pos,
                                                            nullptr, nullptr);
  // 4. per-head KtV + ksum (MFMA) -> bf16 kvT [d][c]
  kvmat_mfma<<<dim3(7, 64), dim3(256), 0, stream>>>(kbuf, vbuf, pKV, pKS);
  kv_reduce<<<dim3(64), dim3(256), 0, stream>>>(pKV, pKS, kvT, ksumB);
  // 5. depthwise conv -> pre
  conv_dw<<<dim3(56, 64), dim3(256), 0, stream>>>(vbuf, wTc, dwcb, pre);
  // 6. attention output + fmap (in-place on pre), MFMA micro-GEMM
  attn_mfma<<<dim3(49, 64), dim3(64), 0, stream>>>(qb, kvT, ksumB, pre);
  // 7. projection GEMM -> f32 out (128x128 tiles, 196*4=784 blocks)
  gemm_bf16<1, 4><<<dim3(784), dim3(512), 67584, stream>>>(pre, wprojT, nullptr, nullptr, nullptr,
                                                           nullptr, out, bproj);
}

// Round 12
// 193.922 us; speedup vs baseline: 1.4377x; 1.0522x over previous
//
#include <hip/hip_runtime.h>
#include <stdint.h>

// SimplifiedLinearAttention: B=8, N=3136 (56x56), C=512, 8 heads x 64
// Pipeline: prep(cvt+transposes) -> GEMM(QKV,fused act) -> kvmat_mfma/reduce
//           -> conv_dw -> attn_mfma -> GEMM(proj,+bias) -> f32 out
// R12: (a) five prep kernels (cvt_x, tconv x3, conv_wT) merged into ONE
//      blockIdx-range-dispatched kernel -> graph nodes 11->7 (gap test).
//      (b) proj epilogue restaged in two 64-row halves (R3 pattern) ->
//      MODE1 dyn LDS 67584->49152. GEMM loops, kvmat, conv, attn unchanged.
#define B_    8
#define N_    3136
#define C_    512
#define MTOT  25088   // B_*N_

typedef __attribute__((ext_vector_type(8))) short bf16x8;
typedef __attribute__((ext_vector_type(4))) float f32x4;

__device__ __forceinline__ float bf2f(short s){
  union { float f; uint32_t u; } cv; cv.u = ((uint32_t)(uint16_t)s) << 16; return cv.f;
}
__device__ __forceinline__ short f2bf(float f){
  union { float f; uint32_t u; } cv; cv.f = f;
  uint32_t r = cv.u + 0x7FFFu + ((cv.u >> 16) & 1u);
  return (short)(r >> 16);
}

typedef const __attribute__((address_space(1))) void* gas1_t;
typedef __attribute__((address_space(3))) void* las3_t;
__device__ __forceinline__ void gld16(const void* g, void* l){
  __builtin_amdgcn_global_load_lds((gas1_t)g, (las3_t)l, 16, 0, 0);
}

#define BARR  __builtin_amdgcn_s_barrier()
#define SCHB  __builtin_amdgcn_sched_barrier(0)
#define VMC0  asm volatile("s_waitcnt vmcnt(0)" ::: "memory")
#define VMC2  asm volatile("s_waitcnt vmcnt(2)" ::: "memory")
#define VMC3  asm volatile("s_waitcnt vmcnt(3)" ::: "memory")
#define LGKM0 asm volatile("s_waitcnt lgkmcnt(0)" ::: "memory")

// ---- prep: cvt_x (blocks 0..6271) | tconv Wq (256) | tconv Wkv (512) |
//      tconv Wproj (256) | conv_wT (7)  -> one kernel, 7303 blocks ----
__global__ __launch_bounds__(256)
void prep(const float* __restrict__ x, short* __restrict__ xb,
          const float* __restrict__ Wq, const float* __restrict__ Wkv,
          const float* __restrict__ Wproj, short* __restrict__ wqkvT,
          short* __restrict__ wprojT,
          const float* __restrict__ dwcw, float* __restrict__ wTc)
{
  __shared__ float tile[32][33];
  int bid = blockIdx.x;
  const int t = threadIdx.x;
  if (bid < 6272) {                       // ---- cvt_x ----
    int i = bid * 256 + t;
    const float4* p = (const float4*)x;
    float4 a = p[i*2], b = p[i*2+1];
    short o[8] = { f2bf(a.x), f2bf(a.y), f2bf(a.z), f2bf(a.w),
                   f2bf(b.x), f2bf(b.y), f2bf(b.z), f2bf(b.w) };
    *(bf16x8*)(xb + i*8) = *(bf16x8*)o;
    return;
  }
  bid -= 6272;
  if (bid >= 1024) {                      // ---- conv_wT (7 blocks) ----
    int i = (bid - 1024) * 256 + t;
    if (i < 1600) { int c = i / 25, tap = i - c * 25; wTc[tap * 64 + c] = dwcw[i]; }
    return;
  }
  // ---- tconv: dst[j*512 + k] = bf16(src[k*J + j]) ----
  const float* src; short* dst; int J, gx;
  if (bid < 256)      {             src = Wq;    dst = wqkvT;             J = 512;  gx = 16; }
  else if (bid < 768) { bid -= 256; src = Wkv;   dst = wqkvT + 512 * 512; J = 1024; gx = 32; }
  else                { bid -= 768; src = Wproj; dst = wprojT;            J = 512;  gx = 16; }
  int jb = (bid % gx) * 32, kb = (bid / gx) * 32;
  int tx = t & 31, ty = t >> 5;
#pragma unroll
  for (int r = 0; r < 32; r += 8)
    tile[ty + r][tx] = src[(size_t)(kb + ty + r) * J + jb + tx];
  __syncthreads();
#pragma unroll
  for (int r = 0; r < 32; r += 8)
    dst[(size_t)(jb + ty + r) * 512 + kb + tx] = f2bf(tile[tx][ty + r]);
}

// ---------------- 128xBN bf16 MFMA GEMM, K=512, Bt is (N x K) ----------------
// (R10/R11 structure, unchanged loop — passed; occ 30%, 0 bank conflicts.)
template<int MODE, int NCT>
__global__ __launch_bounds__(512, 4)
void gemm_bf16(const short* __restrict__ A, const short* __restrict__ Bt,
               short* __restrict__ oQ, short* __restrict__ oK, short* __restrict__ oV,
               const float* __restrict__ posenc,
               float* __restrict__ oF, const float* __restrict__ bias)
{
  constexpr int BN    = MODE ? 128 : 256;
  constexpr int NJ    = MODE ? 2 : 4;          // B frags per wave
  constexpr int WNW   = MODE ? 32 : 64;        // wave N width
  constexpr int BUFSZ = MODE ? 16384 : 24576;  // A 8KB + B 8/16KB
  constexpr int BOFF  = 8192;
  extern __shared__ __align__(16) char lds[];
  const int tid = threadIdx.x;
  const int wave = tid >> 6, lane = tid & 63;
  const int fr = lane & 15;

  // m204 bijective XCD swizzle
  constexpr int nwg = 196 * NCT;
  constexpr int q8 = nwg / 8, r8 = nwg % 8;
  const int orig = blockIdx.x;
  const int xcd = orig & 7, lid = orig >> 3;
  const int swz = (xcd < r8 ? xcd * (q8 + 1) : r8 * (q8 + 1) + (xcd - r8) * q8) + lid;
  const int rt = (swz / NCT) * 128;
  const int ct = (swz % NCT) * BN;

  const int wm = (wave >> 2) * 64;
  const int wn = (wave & 3) * WNW;

  // ---- staging: per-lane source (pre-swizzled), wave-uniform LDS dest ----
  const int srow = lane >> 2;                                  // 0..15
  const int csrc = ((lane & 3) ^ ((lane >> 3) & 3)) << 3;      // shorts
  const short* srcA = A  + (size_t)(rt + wave * 16 + srow) * 512 + csrc;
  const short* srcB = Bt + (size_t)(ct + wave * (MODE ? 16 : 32) + srow) * 512 + csrc;
  char* dA = lds + wave * 1024;
  char* dB = lds + BOFF + wave * (MODE ? 1024 : 2048);

  auto stage = [&](int t) {
    const int b = (t % 3) * BUFSZ;
    const short* a0 = srcA + t * 32;
    gld16(a0, dA + b);
    const short* b0 = srcB + t * 32;
    gld16(b0, dB + b);
    if (MODE == 0) gld16(b0 + 8192, dB + b + 1024);   // B rows +16
  };

  // ---- fragment ds_read offsets (swizzled; (row>>1)&3 == (fr>>1)&3) ----
  const int cR   = (((lane >> 4) ^ ((fr >> 1) & 3)) << 4);
  const int offA = (wm + fr) * 64 + cR;
  const int offB = BOFF + (wn + fr) * 64 + cR;

  f32x4 zv = {0.f, 0.f, 0.f, 0.f};
  f32x4 acc[4][NJ];
#pragma unroll
  for (int i = 0; i < 4; i++)
#pragma unroll
    for (int j = 0; j < NJ; j++) acc[i][j] = zv;

  stage(0); stage(1);        // prologue: 2 tiles in flight

#pragma unroll
  for (int t = 0; t < 16; ++t) {
    if (t < 15) { if (MODE == 0) { VMC3; } else { VMC2; } }
    else       { VMC0; }
    BARR; SCHB;                       // tile t landed chip-wide; all reads
                                      // of buf[t%3] (from iter t-3) retired
    if (t + 2 < 16) stage(t + 2);
    const char* sb = lds + (t % 3) * BUFSZ;
    bf16x8 af[4], bfr[NJ];
#pragma unroll
    for (int i = 0; i < 4; i++) af[i] = *(const bf16x8*)(sb + offA + i * 1024);
#pragma unroll
    for (int j = 0; j < NJ; j++) bfr[j] = *(const bf16x8*)(sb + offB + j * 1024);
    LGKM0; SCHB;                      // rule #18: reads complete HERE
    __builtin_amdgcn_s_setprio(1);
#pragma unroll
    for (int i = 0; i < 4; i++)
#pragma unroll
      for (int j = 0; j < NJ; j++)
        acc[i][j] = __builtin_amdgcn_mfma_f32_16x16x32_bf16(af[i], bfr[j], acc[i][j], 0, 0, 0);
    __builtin_amdgcn_s_setprio(0);
  }

  BARR; SCHB;                         // all LDS reads done -> reusable

  // ---- epilogue: restage through LDS, coalesced stores ----
  const int rb = (lane >> 4) << 2;    // D layout: row=(lane>>4)*4+reg
  if (MODE == 0) {
    short* ov = (short*)lds;          // [128][264] bf16 (67584 B)
    const int sel = ct >> 9;          // 0:Q 1:K 2:V (uniform per block)
    const int cb  = ct - sel * 512;
    short* outp = sel == 0 ? oQ : (sel == 1 ? oK : oV);
#pragma unroll
    for (int i = 0; i < 4; i++)
#pragma unroll
      for (int j = 0; j < 4; j++)
#pragma unroll
        for (int r = 0; r < 4; r++)
          ov[(wm + i * 16 + rb + r) * 264 + wn + j * 16 + fr] = f2bf(acc[i][j][r]);
    __syncthreads();
#pragma unroll
    for (int p = 0; p < 8; ++p) {
      int id = tid + 512 * p;
      int row = id >> 5, cc = (id & 31) * 8;
      bf16x8 vv = *(const bf16x8*)&ov[row * 264 + cc];
      int grow = rt + row;
      short o[8];
      if (sel == 0) {
#pragma unroll
        for (int e = 0; e < 8; e++) o[e] = f2bf(fmaxf(bf2f(vv[e]), 0.f));
      } else if (sel == 1) {
        int nr = grow % N_;
        const float* pp = posenc + (size_t)nr * 512 + cb + cc;
        f32x4 p0 = *(const f32x4*)pp;
        f32x4 p1 = *(const f32x4*)(pp + 4);
#pragma unroll
        for (int e = 0; e < 4; e++) {
          o[e]     = f2bf(fmaxf(bf2f(vv[e]) + p0[e], 0.f));
          o[e + 4] = f2bf(fmaxf(bf2f(vv[e + 4]) + p1[e], 0.f));
        }
      } else {
#pragma unroll
        for (int e = 0; e < 8; e++) o[e] = vv[e];
      }
      *(bf16x8*)(outp + (size_t)grow * 512 + cb + cc) = *(bf16x8*)o;
    }
  } else {
    float* ovf = (float*)lds;         // [64][132] f32 (33792 B), two halves
#pragma unroll
    for (int hf = 0; hf < 2; ++hf) {
      if (hf) __syncthreads();        // protect prev half's reads
      if ((wave >> 2) == hf) {        // waves owning rows hf*64..+63
#pragma unroll
        for (int i = 0; i < 4; i++)
#pragma unroll
          for (int j = 0; j < 2; j++)
#pragma unroll
            for (int r = 0; r < 4; r++)
              ovf[(i * 16 + rb + r) * 132 + wn + j * 16 + fr] = acc[i][j][r];
      }
      __syncthreads();
#pragma unroll
      for (int p = 0; p < 2; ++p) {
        int id = tid + 512 * p;       // 0..1023
        int row = id >> 4, cc = (id & 15) * 8;   // row 0..63
        f32x4 v0 = *(const f32x4*)&ovf[row * 132 + cc];
        f32x4 v1 = *(const f32x4*)&ovf[row * 132 + cc + 4];
        v0 += *(const f32x4*)&bias[ct + cc];
        v1 += *(const f32x4*)&bias[ct + cc + 4];
        float* op = oF + (size_t)(rt + hf * 64 + row) * 512 + ct + cc;
        *(f32x4*)op       = v0;
        *(f32x4*)(op + 4) = v1;
      }
    }
  }
}

// ------- per-head KtV (64x64) + ksum via MFMA, f32 partials, N split 7 ------
__global__ __launch_bounds__(256)
void kvmat_mfma(const short* __restrict__ kb, const short* __restrict__ vb,
                float* __restrict__ pKV, float* __restrict__ pKS)
{
  __shared__ __align__(16) short lkT[64 * 72];
  __shared__ __align__(16) short lvT[64 * 72];
  const int chunk = blockIdx.x, bh = blockIdx.y;
  const int b = bh >> 3, h = bh & 7;
  const int t = threadIdx.x;
  const int wave = t >> 6, lane = t & 63;
  const int fr = lane & 15, kg = lane >> 4;

  f32x4 zv = {0.f, 0.f, 0.f, 0.f};
  f32x4 acc[4];
#pragma unroll
  for (int j = 0; j < 4; j++) acc[j] = zv;
  f32x4 accks = zv;

  bf16x8 ones;
#pragma unroll
  for (int e = 0; e < 8; e++) ones[e] = (short)0x3F80;   // bf16 1.0

  const int rr = t >> 3, c8 = t & 7;
  for (int tile = 0; tile < 7; ++tile) {
    const int r0 = chunk * 448 + tile * 64;
    __syncthreads();                       // prev tile's frag reads done
#pragma unroll
    for (int half = 0; half < 2; ++half) {
      int r = rr + half * 32;
      size_t g = (size_t)(b * N_ + r0 + r) * 512 + h * 64 + c8 * 8;
      bf16x8 kk = *(const bf16x8*)(kb + g);
      bf16x8 vv = *(const bf16x8*)(vb + g);
#pragma unroll
      for (int e = 0; e < 8; e++) {
        lkT[(c8 * 8 + e) * 72 + r] = kk[e];
        lvT[(c8 * 8 + e) * 72 + r] = vv[e];
      }
    }
    __syncthreads();
#pragma unroll
    for (int ks = 0; ks < 2; ++ks) {
      const int ko = ks * 32 + kg * 8;
      bf16x8 af = *(const bf16x8*)&lkT[(wave * 16 + fr) * 72 + ko];
      bf16x8 bm[4];
#pragma unroll
      for (int j = 0; j < 4; j++)
        bm[j] = *(const bf16x8*)&lvT[(j * 16 + fr) * 72 + ko];
#pragma unroll
      for (int j = 0; j < 4; j++)
        acc[j] = __builtin_amdgcn_mfma_f32_16x16x32_bf16(af, bm[j], acc[j], 0, 0, 0);
      accks = __builtin_amdgcn_mfma_f32_16x16x32_bf16(af, ones, accks, 0, 0, 0);
    }
  }

  // write partials: D layout row=(lane>>4)*4+reg (c within wave 16), col=fr (d)
  const int pbase = (bh * 7 + chunk) * 4096;
  const int crow = wave * 16 + kg * 4;
#pragma unroll
  for (int j = 0; j < 4; j++)
#pragma unroll
    for (int r_ = 0; r_ < 4; r_++)
      pKV[pbase + (crow + r_) * 64 + j * 16 + fr] = acc[j][r_];
  if (fr == 0) {
#pragma unroll
    for (int r_ = 0; r_ < 4; r_++)
      pKS[(bh * 7 + chunk) * 64 + crow + r_] = accks[r_];
  }
}

// ------- reduce partials; emit kvT bf16 [d][c] (B-operand layout) + ksum ----
__global__ __launch_bounds__(256)
void kv_reduce(const float* __restrict__ pKV, const float* __restrict__ pKS,
               short* __restrict__ kvT, float* __restrict__ ksum)
{
  int bh = blockIdx.x, t = threadIdx.x;
#pragma unroll
  for (int i = 0; i < 16; i++) {
    int idx = t + i * 256;
    float s = 0.f;
#pragma unroll
    for (int c = 0; c < 7; c++) s += pKV[(bh * 7 + c) * 4096 + idx];
    int cc = idx >> 6, d = idx & 63;           // pKV layout [c][d]
    kvT[bh * 4096 + d * 64 + cc] = f2bf(s);    // transposed bf16
  }
  if (t < 64) {
    float s = 0.f;
#pragma unroll
    for (int c = 0; c < 7; c++) s += pKS[(bh * 7 + c) * 64 + t];
    ksum[bh * 64 + t] = s;
  }
}

// ------------- depthwise 5x5 conv on v, +bias -> pre (bf16) -------------
__global__ __launch_bounds__(256)
void conv_dw(const short* __restrict__ vb, const float* __restrict__ wT,
             const float* __restrict__ bias, short* __restrict__ pre)
{
  __shared__ __align__(16) short lsv[5 * 56 * 64];   // [row][x][64ch]
  __shared__ __align__(16) float lwT[25 * 64];       // [tap][64ch]
  const int y = blockIdx.x, bh = blockIdx.y;
  const int b = bh >> 3, h = bh & 7;
  const int t = threadIdx.x;
  for (int i = t; i < 1600; i += 256) lwT[i] = wT[i];
  for (int i = t; i < 2240; i += 256) {
    int row = i / 448, rem = i - row * 448;
    int xx = rem >> 3, c8i = rem & 7;
    int gy = y + row - 2;
    bf16x8 val = {0, 0, 0, 0, 0, 0, 0, 0};
    if ((unsigned)gy < 56u)
      val = *(const bf16x8*)(vb + (size_t)(b * N_ + gy * 56 + xx) * 512 + h * 64 + c8i * 8);
    *(bf16x8*)(lsv + i * 8) = val;     // linear: [(row*56+xx)*64 + c8*8]
  }
  __syncthreads();

  const int c8 = t & 7;                // 8-channel chunk within head
  const int x0 = t >> 3;               // 0..31; second pass covers x0+32
  float acc0[8], acc1[8];
  {
    f32x4 b0 = *(const f32x4*)&bias[c8 * 8];
    f32x4 b1 = *(const f32x4*)&bias[c8 * 8 + 4];
#pragma unroll
    for (int e = 0; e < 4; e++) { acc0[e] = b0[e]; acc0[e+4] = b1[e];
                                  acc1[e] = b0[e]; acc1[e+4] = b1[e]; }
  }
#pragma unroll
  for (int dy = 0; dy < 5; ++dy) {
#pragma unroll
    for (int dx = 0; dx < 5; ++dx) {
      float w8[8];
      {
        const float* wp = &lwT[(dy * 5 + dx) * 64 + c8 * 8];
        *(f32x4*)&w8[0] = *(const f32x4*)wp;
        *(f32x4*)&w8[4] = *(const f32x4*)(wp + 4);
      }
      const int base = dy * 56 * 64 + c8 * 8;
      int xxa = x0 + dx - 2;
      if ((unsigned)xxa < 56u) {
        bf16x8 v = *(const bf16x8*)(lsv + base + xxa * 64);
#pragma unroll
        for (int e = 0; e < 8; e++) acc0[e] += bf2f(v[e]) * w8[e];
      }
      int xxb = xxa + 32;
      if (xxb < 56) {
        bf16x8 v = *(const bf16x8*)(lsv + base + xxb * 64);
#pragma unroll
        for (int e = 0; e < 8; e++) acc1[e] += bf2f(v[e]) * w8[e];
      }
    }
  }
  size_t gbase = (size_t)(b * N_ + y * 56 + x0) * 512 + h * 64 + c8 * 8;
  short o[8];
#pragma unroll
  for (int e = 0; e < 8; e++) o[e] = f2bf(acc0[e]);
  *(bf16x8*)(pre + gbase) = *(bf16x8*)o;
  if (x0 + 32 < 56) {
#pragma unroll
    for (int e = 0; e < 8; e++) o[e] = f2bf(acc1[e]);
    *(bf16x8*)(pre + gbase + (size_t)32 * 512) = *(bf16x8*)o;
  }
}

// ---- attn: per-wave MFMA micro-GEMM out = (q @ kvT^T)*z + pre (RMW) ----
__global__ __launch_bounds__(64)
void attn_mfma(const short* __restrict__ qb, const short* __restrict__ kvT,
               const float* __restrict__ ksum, short* __restrict__ pre)
{
  __shared__ __align__(16) float ov[64 * 68];
  __shared__ float lks[64];
  const int pt = blockIdx.x, bh = blockIdx.y;
  const int b = bh >> 3, h = bh & 7;
  const int l = threadIdx.x;
  const int fr = l & 15, kg = l >> 4;
  const int n0 = pt * 64;

  lks[l] = ksum[bh * 64 + l];

  const short* qbase = qb + (size_t)(b * N_ + n0) * 512 + h * 64;
  const short* kvb   = kvT + bh * 4096;
  bf16x8 af[4][2], bm[4][2];
#pragma unroll
  for (int i = 0; i < 4; i++)
#pragma unroll
    for (int s = 0; s < 2; s++) {
      af[i][s] = *(const bf16x8*)(qbase + (size_t)(fr + i * 16) * 512 + s * 32 + kg * 8);
      bm[i][s] = *(const bf16x8*)(kvb + (fr + i * 16) * 64 + s * 32 + kg * 8);
    }

  f32x4 zv4 = {0.f, 0.f, 0.f, 0.f};
  f32x4 acc[4][4];
#pragma unroll
  for (int i = 0; i < 4; i++)
#pragma unroll
    for (int j = 0; j < 4; j++) acc[i][j] = zv4;
#pragma unroll
  for (int s = 0; s < 2; s++)
#pragma unroll
    for (int i = 0; i < 4; i++)
#pragma unroll
      for (int j = 0; j < 4; j++)
        acc[i][j] = __builtin_amdgcn_mfma_f32_16x16x32_bf16(af[i][s], bm[j][s], acc[i][j], 0, 0, 0);

  // z for own row l (f32, q re-read — same cache lines as frags)
  const short* qrow = qb + (size_t)(b * N_ + n0 + l) * 512 + h * 64;
  float zd = 0.f;
#pragma unroll
  for (int g = 0; g < 8; g++) {
    bf16x8 qv = *(const bf16x8*)(qrow + g * 8);
#pragma unroll
    for (int e = 0; e < 8; e++) zd += bf2f(qv[e]) * lks[g * 8 + e];
  }
  const float z = 1.f / (zd + 1e-6f);

  // restage acc: row = i*16 + kg*4 + r, col = j*16 + fr
  const int rb = kg << 2;
#pragma unroll
  for (int i = 0; i < 4; i++)
#pragma unroll
    for (int j = 0; j < 4; j++)
#pragma unroll
      for (int r = 0; r < 4; r++)
        ov[(i * 16 + rb + r) * 68 + j * 16 + fr] = acc[i][j][r];
  __syncthreads();

  // vectorized RMW: lane l owns pixel n0+l
  size_t gb = (size_t)(b * N_ + n0 + l) * 512 + h * 64;
  const float* ovr = &ov[l * 68];
#pragma unroll
  for (int g = 0; g < 8; g++) {
    bf16x8 pv = *(const bf16x8*)(pre + gb + g * 8);
    f32x4 a0 = *(const f32x4*)(ovr + g * 8);
    f32x4 a1 = *(const f32x4*)(ovr + g * 8 + 4);
    short o[8];
#pragma unroll
    for (int e = 0; e < 4; e++) {
      o[e]     = f2bf(a0[e] * z + bf2f(pv[e]));
      o[e + 4] = f2bf(a1[e] * z + bf2f(pv[e + 4]));
    }
    *(bf16x8*)(pre + gb + g * 8) = *(bf16x8*)o;
  }
}

// ---------------------------------------------------------------------------
extern "C" void kernel_launch(void* const* d_in, const int* in_sizes, int n_in,
                              void* d_out, int out_size, void* d_ws, size_t ws_size,
                              hipStream_t stream)
{
  const float* x     = (const float*)d_in[0];
  const float* Wq    = (const float*)d_in[3];
  const float* Wkv   = (const float*)d_in[4];
  const float* pos   = (const float*)d_in[5];
  const float* dwcw  = (const float*)d_in[6];
  const float* dwcb  = (const float*)d_in[7];
  const float* Wproj = (const float*)d_in[8];
  const float* bproj = (const float*)d_in[9];
  float* out = (float*)d_out;

  char* ws = (char*)d_ws;
  size_t off = 0;
  auto alloc = [&](size_t bytes) -> void* {
    void* p = ws + off;
    off = (off + bytes + 255) & ~(size_t)255;
    return p;
  };
  short* xb     = (short*)alloc((size_t)MTOT * 512 * 2);
  short* wqkvT  = (short*)alloc((size_t)1536 * 512 * 2);
  short* wprojT = (short*)alloc((size_t)512 * 512 * 2);
  float* wTc    = (float*)alloc((size_t)25 * 64 * 4);
  short* qb     = (short*)alloc((size_t)MTOT * 512 * 2);
  short* kbuf   = (short*)alloc((size_t)MTOT * 512 * 2);
  short* vbuf   = (short*)alloc((size_t)MTOT * 512 * 2);
  float* pKV    = (float*)alloc((size_t)64 * 7 * 4096 * 4);
  float* pKS    = (float*)alloc((size_t)64 * 7 * 64 * 4);
  short* kvT    = (short*)alloc((size_t)64 * 4096 * 2);
  float* ksumB  = (float*)alloc((size_t)64 * 64 * 4);
  short* pre    = (short*)alloc((size_t)MTOT * 512 * 2);
  if (ws_size < off) return;   // workspace too small: leave output zeroed (visible failure)

  // dynamic LDS for the GEMMs (host-side attr, graph-safe)
  {
    auto k0 = gemm_bf16<0, 6>;
    auto k1 = gemm_bf16<1, 4>;
    hipFuncSetAttribute(reinterpret_cast<const void*>(k0),
                        hipFuncAttributeMaxDynamicSharedMemorySize, 73728);
    hipFuncSetAttribute(reinterpret_cast<const void*>(k1),
                        hipFuncAttributeMaxDynamicSharedMemorySize, 49152);
  }

  // 1. prep: cvt x + transpose Wq/Wkv/Wproj + conv-weight transpose (1 node)
  prep<<<dim3(7303), dim3(256), 0, stream>>>(x, xb, Wq, Wkv, Wproj,
                                             wqkvT, wprojT, dwcw, wTc);
  // 2. QKV GEMM, fused activations (128x256 tiles, 196*6=1176 blocks)
  gemm_bf16<0, 6><<<dim3(1176), dim3(512), 73728, stream>>>(xb, wqkvT, qb, kbuf, vbuf, pos,
                                                            nullptr, nullptr);
  // 3. per-head KtV + ksum (MFMA) -> bf16 kvT [d][c]
  kvmat_mfma<<<dim3(7, 64), dim3(256), 0, stream>>>(kbuf, vbuf, pKV, pKS);
  kv_reduce<<<dim3(64), dim3(256), 0, stream>>>(pKV, pKS, kvT, ksumB);
  // 4. depthwise conv -> pre
  conv_dw<<<dim3(56, 64), dim3(256), 0, stream>>>(vbuf, wTc, dwcb, pre);
  // 5. attention output + fmap (in-place on pre), MFMA micro-GEMM
  attn_mfma<<<dim3(49, 64), dim3(64), 0, stream>>>(qb, kvT, ksumB, pre);
  // 6. projection GEMM -> f32 out (128x128 tiles, 196*4=784 blocks)
  gemm_bf16<1, 4><<<dim3(784), dim3(512), 49152, stream>>>(pre, wprojT, nullptr, nullptr, nullptr,
                                                           nullptr, out, bproj);
}